// Round 6
// baseline (4601.889 us; speedup 1.0000x reference)
//
#include <hip/hip_runtime.h>
#include <math.h>
#include <stdint.h>

// ---------------- helpers ----------------
__device__ inline float bf2f(unsigned short u){
  union { unsigned int i; float f; } x; x.i = ((unsigned int)u) << 16; return x.f;
}
__device__ inline unsigned short f2bf(float f){
  union { float f; unsigned int i; } x; x.f = f;
  unsigned int u = x.i;
  return (unsigned short)((u + 0x7FFFu + ((u >> 16) & 1u)) >> 16);
}
// dtype-dispatched input load: f32 flag comes from device-side probe
__device__ inline float ldin(const void* p, size_t i, int f32){
  return f32 ? ((const float*)p)[i] : bf2f(((const unsigned short*)p)[i]);
}

__device__ inline int badf(float v){ return !(fabsf(v) <= 3.0e38f); }
__device__ inline int badd(double v){ return !(fabs(v) <= 1.0e300); }

__device__ inline double wsum_d(double v){
  #pragma unroll
  for (int o = 32; o > 0; o >>= 1) v += __shfl_down(v, o);
  return v;
}
__device__ inline double wmax_d(double v){
  #pragma unroll
  for (int o = 32; o > 0; o >>= 1) v = fmax(v, __shfl_down(v, o));
  return v;
}
__device__ inline void atomicMaxD(double* addr, double v){ // v >= 0
  atomicMax((unsigned long long*)addr, (unsigned long long)__double_as_longlong(v));
}

// MFMA types
typedef __attribute__((ext_vector_type(8))) short short8;
typedef __attribute__((ext_vector_type(4))) float f32x4;
__device__ inline f32x4 mfma16(short8 a, short8 b, f32x4 c){
  return __builtin_amdgcn_mfma_f32_16x16x32_bf16(a, b, c, 0, 0, 0);
}

// ---------------- LAPACK 3x3 eigh port (dsytd2 + dsteqr + dormtr) ----------------
__device__ inline double d_sign(double a, double b){ return (b >= 0.0) ? fabs(a) : -fabs(a); }
__device__ inline double dlapy2_(double x, double y){ return sqrt(x*x + y*y); }

__device__ void dlartg_(double f, double g, double* cs, double* sn, double* r){
  // LAPACK >= 3.10 convention: c >= 0, r = sign(d, f)
  if (g == 0.0){ *cs = 1.0; *sn = 0.0; *r = f; }
  else if (f == 0.0){ *cs = 0.0; *sn = (g >= 0.0) ? 1.0 : -1.0; *r = fabs(g); }
  else {
    double d = sqrt(f*f + g*g);
    *cs = fabs(f)/d;
    *r  = d_sign(d, f);
    *sn = g / (*r);
  }
}

__device__ void dlaev2_(double a, double b, double c, double* rt1, double* rt2,
                        double* cs1, double* sn1){
  double sm = a + c, df = a - c, adf = fabs(df), tb = b + b, ab = fabs(tb);
  double acmx, acmn;
  if (fabs(a) > fabs(c)){ acmx = a; acmn = c; } else { acmx = c; acmn = a; }
  double rt;
  if (adf > ab) rt = adf*sqrt(1.0 + (ab/adf)*(ab/adf));
  else if (adf < ab) rt = ab*sqrt(1.0 + (adf/ab)*(adf/ab));
  else rt = ab*sqrt(2.0);
  int sgn1;
  if (sm < 0.0){ *rt1 = 0.5*(sm - rt); sgn1 = -1; *rt2 = (acmx/(*rt1))*acmn - (b/(*rt1))*b; }
  else if (sm > 0.0){ *rt1 = 0.5*(sm + rt); sgn1 = 1; *rt2 = (acmx/(*rt1))*acmn - (b/(*rt1))*b; }
  else { *rt1 = 0.5*rt; *rt2 = -0.5*rt; sgn1 = 1; }
  int sgn2; double cs;
  if (df >= 0.0){ cs = df + rt; sgn2 = 1; } else { cs = df - rt; sgn2 = -1; }
  double acs = fabs(cs);
  if (acs > ab){ double ct = -tb/cs; *sn1 = 1.0/sqrt(1.0+ct*ct); *cs1 = ct*(*sn1); }
  else {
    if (ab == 0.0){ *cs1 = 1.0; *sn1 = 0.0; }
    else { double tn = -cs/tb; *cs1 = 1.0/sqrt(1.0+tn*tn); *sn1 = tn*(*cs1); }
  }
  if (sgn1 == sgn2){ double tn = *cs1; *cs1 = -(*sn1); *sn1 = tn; }
}

__device__ void dsteqr3_(double* dd, double* ee, double z[3][3]){
  #define D_(i) dd[(i)-1]
  #define E_(i) ee[(i)-1]
  #define Z_(i,j) z[(i)-1][(j)-1]
  #define CW_(i) cw[(i)-1]
  #define SW_(i) sw[(i)-1]
  const int n = 3;
  const double eps = 1.1102230246251565e-16;
  const double eps2 = eps*eps;
  const double safmin = 2.2250738585072014e-308;
  const int nmaxit = n*30;
  double cw[3], sw[3];
  int jtot = 0;
  int l1 = 1, l, m, lsv, lend, lendsv;
  double p, g, r, c, s, f, b, rt1, rt2, anorm, tst;

L10:
  if (l1 > n) goto L160;
  if (l1 > 1) E_(l1-1) = 0.0;
  if (l1 <= n-1){
    for (m = l1; m <= n-1; ++m){
      tst = fabs(E_(m));
      if (tst == 0.0) goto L30;
      if (tst <= (sqrt(fabs(D_(m)))*sqrt(fabs(D_(m+1))))*eps){ E_(m) = 0.0; goto L30; }
    }
  }
  m = n;
L30:
  l = l1; lsv = l; lend = m; lendsv = lend; l1 = m+1;
  if (lend == l) goto L10;
  anorm = 0.0;
  for (int i = l; i <= lend; ++i) anorm = fmax(anorm, fabs(D_(i)));
  for (int i = l; i <= lend-1; ++i) anorm = fmax(anorm, fabs(E_(i)));
  if (anorm == 0.0) goto L10;
  if (fabs(D_(lend)) < fabs(D_(l))){ lend = lsv; l = lendsv; }
  if (lend > l) goto L40; else goto L90;

  // -------- QL iteration --------
L40:
  if (l != lend){
    for (m = l; m <= lend-1; ++m){
      tst = fabs(E_(m)); tst = tst*tst;
      if (tst <= (eps2*fabs(D_(m)))*fabs(D_(m+1)) + safmin) goto L60;
    }
  }
  m = lend;
L60:
  if (m < lend) E_(m) = 0.0;
  p = D_(l);
  if (m == l) goto L80;
  if (m == l+1){
    dlaev2_(D_(l), E_(l), D_(l+1), &rt1, &rt2, &c, &s);
    CW_(l) = c; SW_(l) = s;
    { double ct = CW_(l), st = SW_(l);
      if (ct != 1.0 || st != 0.0)
        for (int i = 1; i <= n; ++i){
          double t = Z_(i, l+1);
          Z_(i, l+1) = ct*t - st*Z_(i, l);
          Z_(i, l)   = st*t + ct*Z_(i, l);
        }
    }
    D_(l) = rt1; D_(l+1) = rt2; E_(l) = 0.0;
    l += 2;
    if (l <= lend) goto L40;
    goto L140;
  }
  if (jtot == nmaxit) goto L140;
  jtot++;
  g = (D_(l+1) - p)/(2.0*E_(l));
  r = dlapy2_(g, 1.0);
  g = D_(m) - p + E_(l)/(g + d_sign(r, g));
  s = 1.0; c = 1.0; p = 0.0;
  for (int i = m-1; i >= l; --i){
    f = s*E_(i); b = c*E_(i);
    dlartg_(g, f, &c, &s, &r);
    if (i != m-1) E_(i+1) = r;
    g = D_(i+1) - p;
    r = (D_(i) - g)*s + 2.0*c*b;
    p = s*r;
    D_(i+1) = g + p;
    g = c*r - b;
    CW_(i) = c; SW_(i) = -s;
  }
  { int mm = m - l + 1;
    for (int j = mm-1; j >= 1; --j){
      double ct = CW_(l+j-1), st = SW_(l+j-1);
      if (ct != 1.0 || st != 0.0)
        for (int i = 1; i <= n; ++i){
          double t = Z_(i, l+j);
          Z_(i, l+j)   = ct*t - st*Z_(i, l+j-1);
          Z_(i, l+j-1) = st*t + ct*Z_(i, l+j-1);
        }
    }
  }
  D_(l) = D_(l) - p;
  E_(l) = g;
  goto L40;
L80:
  D_(l) = p;
  l++;
  if (l <= lend) goto L40;
  goto L140;

  // -------- QR iteration --------
L90:
  if (l != lend){
    for (m = l; m >= lend+1; --m){
      tst = fabs(E_(m-1)); tst = tst*tst;
      if (tst <= (eps2*fabs(D_(m)))*fabs(D_(m-1)) + safmin) goto L110;
    }
  }
  m = lend;
L110:
  if (m > lend) E_(m-1) = 0.0;
  p = D_(l);
  if (m == l) goto L130;
  if (m == l-1){
    dlaev2_(D_(l-1), E_(l-1), D_(l), &rt1, &rt2, &c, &s);
    CW_(m) = c; SW_(m) = s;
    { double ct = CW_(m), st = SW_(m);
      if (ct != 1.0 || st != 0.0)
        for (int i = 1; i <= n; ++i){
          double t = Z_(i, l);
          Z_(i, l)   = ct*t - st*Z_(i, l-1);
          Z_(i, l-1) = st*t + ct*Z_(i, l-1);
        }
    }
    D_(l-1) = rt1; D_(l) = rt2; E_(l-1) = 0.0;
    l -= 2;
    if (l >= lend) goto L90;
    goto L140;
  }
  if (jtot == nmaxit) goto L140;
  jtot++;
  g = (D_(l-1) - p)/(2.0*E_(l-1));
  r = dlapy2_(g, 1.0);
  g = D_(m) - p + E_(l-1)/(g + d_sign(r, g));
  s = 1.0; c = 1.0; p = 0.0;
  for (int i = m; i <= l-1; ++i){
    f = s*E_(i); b = c*E_(i);
    dlartg_(g, f, &c, &s, &r);
    if (i != m) E_(i-1) = r;
    g = D_(i) - p;
    r = (D_(i+1) - g)*s + 2.0*c*b;
    p = s*r;
    D_(i) = g + p;
    g = c*r - b;
    CW_(i) = c; SW_(i) = s;
  }
  { int mm = l - m + 1;
    for (int j = 1; j <= mm-1; ++j){
      double ct = CW_(m+j-1), st = SW_(m+j-1);
      if (ct != 1.0 || st != 0.0)
        for (int i = 1; i <= n; ++i){
          double t = Z_(i, m+j);
          Z_(i, m+j)   = ct*t - st*Z_(i, m+j-1);
          Z_(i, m+j-1) = st*t + ct*Z_(i, m+j-1);
        }
    }
  }
  D_(l) = D_(l) - p;
  E_(l-1) = g;
  goto L90;
L130:
  D_(l) = p;
  l--;
  if (l >= lend) goto L90;
  goto L140;

L140:
  if (jtot < nmaxit) goto L10;
  goto L190;

L160:
  for (int ii = 2; ii <= n; ++ii){
    int i = ii-1, k = i;
    p = D_(i);
    for (int j = ii; j <= n; ++j) if (D_(j) < p){ k = j; p = D_(j); }
    if (k != i){
      D_(k) = D_(i); D_(i) = p;
      for (int rr = 1; rr <= n; ++rr){ double t = Z_(rr,i); Z_(rr,i) = Z_(rr,k); Z_(rr,k) = t; }
    }
  }
L190:
  ;
  #undef D_
  #undef E_
  #undef Z_
  #undef CW_
  #undef SW_
}

__device__ void eigh3_(const double C[3][3], double w[3], double v[3][3]){
  double a00=C[0][0], a10=C[1][0], a20=C[2][0], a11=C[1][1], a21=C[2][1], a22=C[2][2];
  double dd[3], ee[2], tau, v2;
  double alpha = a10, x = a20;
  double xnorm = fabs(x);
  if (xnorm == 0.0){ tau = 0.0; v2 = 0.0; ee[0] = alpha; }
  else {
    double beta = -d_sign(dlapy2_(alpha, xnorm), alpha);
    tau = (beta - alpha)/beta;
    v2 = x/(alpha - beta);
    ee[0] = beta;
  }
  if (tau != 0.0){
    double w0 = tau*(a11 + a21*v2);
    double w1 = tau*(a21 + a22*v2);
    double wv = w0 + w1*v2;
    double ac = -0.5*tau*wv;
    w0 += ac; w1 += ac*v2;
    a11 = a11 - 2.0*w0;
    a21 = a21 - (v2*w0 + w1);
    a22 = a22 - 2.0*v2*w1;
  }
  dd[0]=a00; dd[1]=a11; dd[2]=a22; ee[1]=a21;
  double z[3][3] = {{1,0,0},{0,1,0},{0,0,1}};
  dsteqr3_(dd, ee, z);
  for (int j = 0; j < 3; ++j){
    double t = z[1][j] + v2*z[2][j];
    z[1][j] -= tau*t;
    z[2][j] -= tau*t*v2;
  }
  for (int i=0;i<3;++i){ w[i]=dd[i]; for(int j=0;j<3;++j) v[i][j]=z[i][j]; }
}

// ---------------- kernels ----------------
// PD layout (doubles): 0-2 possum, 3 fsum, 4 fsumsq, 5-10 raw pos moments
// (m00,m10,m20,m11,m21,m22), 12-14 mean, 15 scale, 16-24 V, 25 mu1, 26 rstd1,
// 28: int flag + int isf32, 29-30: int dcnt[4] (last-block counters),
// 32+2l per-layer LN stats, 40-71 pool, 72-74 max(64+p), 75-77 max(64-p)

__global__ void k_dtype(const unsigned short* __restrict__ data, int nus, double* PD){
  int* DF = (int*)(PD + 28);
  int t = threadIdx.x;
  int bad = 0;
  for (int i = t; i < nus; i += 256){
    int e = (data[i] >> 7) & 0xFF;
    if (e > 0x90 || (e && e < 0x60)) bad++;
  }
  #pragma unroll
  for (int o = 32; o > 0; o >>= 1) bad += __shfl_down(bad, o);
  __shared__ int sb[4];
  if ((t & 63) == 0) sb[t >> 6] = bad;
  __syncthreads();
  if (t == 0) DF[1] = ((sb[0]+sb[1]+sb[2]+sb[3]) > nus/16) ? 1 : 0;
}

// single pass: pos sums, raw second moments, min/max (as max(64±p)), feat sums
__global__ void k_red1(const void* __restrict__ data, int N, double* PD){
  int n = blockIdx.x*blockDim.x + threadIdx.x;
  const int* DF = (const int*)(PD + 28);
  int f32 = DF[1];
  double vals[11] = {0,0,0,0,0,0,0,0,0,0,0};
  double mp[3] = {0,0,0}, mn[3] = {0,0,0};
  if (n < N){
    size_t rb = (size_t)n*35;
    double p0 = ldin(data, rb+0, f32);
    double p1 = ldin(data, rb+1, f32);
    double p2 = ldin(data, rb+2, f32);
    vals[0]=p0; vals[1]=p1; vals[2]=p2;
    double fs=0, fss=0;
    for (int k=3;k<35;++k){ double v = ldin(data, rb+k, f32); fs += v; fss += v*v; }
    vals[3]=fs; vals[4]=fss;
    vals[5]=p0*p0; vals[6]=p1*p0; vals[7]=p2*p0; vals[8]=p1*p1; vals[9]=p2*p1; vals[10]=p2*p2;
    mp[0]=64.0+p0; mp[1]=64.0+p1; mp[2]=64.0+p2;
    mn[0]=64.0-p0; mn[1]=64.0-p1; mn[2]=64.0-p2;
  }
  __shared__ double sred[4];
  for (int q=0;q<11;++q){
    double t = wsum_d(vals[q]);
    if ((threadIdx.x&63)==0) sred[threadIdx.x>>6]=t;
    __syncthreads();
    if (threadIdx.x==0) atomicAdd(&PD[q], sred[0]+sred[1]+sred[2]+sred[3]);
    __syncthreads();
  }
  for (int j=0;j<6;++j){
    double t = wmax_d(j<3 ? mp[j] : mn[j-3]);
    if ((threadIdx.x&63)==0) sred[threadIdx.x>>6]=t;
    __syncthreads();
    if (threadIdx.x==0)
      atomicMaxD(&PD[72+j], fmax(fmax(sred[0],sred[1]), fmax(sred[2],sred[3])));
    __syncthreads();
  }
}

__global__ void k_eig(double* PD, int N){
  if (threadIdx.x != 0 || blockIdx.x != 0) return;
  int* DF = (int*)(PD + 28);
  int bad0 = 0;
  for (int i=0;i<11;++i) if (badd(PD[i])) bad0 = 1;
  if (bad0) DF[0] |= 1;
  double dN = (double)N;
  double mu[3] = {PD[0]/dN, PD[1]/dN, PD[2]/dN};
  double amax = 0.0;
  for (int j=0;j<3;++j){
    double mx = (PD[72+j] - 64.0) - mu[j];
    double mnv = mu[j] - (64.0 - PD[75+j]);
    amax = fmax(amax, fmax(mx, mnv));
  }
  double s = 0.999999/amax;
  double s2 = s*s;
  double C[3][3];
  C[0][0]=(PD[5]-dN*mu[0]*mu[0])*s2; C[1][0]=(PD[6]-dN*mu[1]*mu[0])*s2;
  C[2][0]=(PD[7]-dN*mu[2]*mu[0])*s2; C[1][1]=(PD[8]-dN*mu[1]*mu[1])*s2;
  C[2][1]=(PD[9]-dN*mu[2]*mu[1])*s2; C[2][2]=(PD[10]-dN*mu[2]*mu[2])*s2;
  C[0][1]=C[1][0]; C[0][2]=C[2][0]; C[1][2]=C[2][1];
  double w[3], V[3][3];
  eigh3_(C, w, V);
  int bad1 = 0;
  for (int i=0;i<3;++i){ if (badd(w[i])) bad1=1; for (int j=0;j<3;++j) if (badd(V[i][j])) bad1=1; }
  if (bad1){
    DF[0] |= 2;
    for (int i=0;i<3;++i) for (int j=0;j<3;++j) V[i][j] = (i==j) ? 1.0 : 0.0;
  }
  PD[12]=mu[0]; PD[13]=mu[1]; PD[14]=mu[2];
  PD[15]=s;
  for (int i=0;i<3;++i) for (int j=0;j<3;++j) PD[16+i*3+j]=V[i][j];
  double cntf = dN*32.0;
  double mu1 = PD[3]/cntf;
  double var = PD[4]/cntf - mu1*mu1;
  PD[25]=mu1;
  PD[26]=1.0/(sqrt(var>0.0?var:0.0)+1e-5);
}

__global__ void k_buildx(const void* __restrict__ data,
                         const void* __restrict__ ln1w,
                         const void* __restrict__ ln1b,
                         double* __restrict__ PD, float* __restrict__ x, int N){
  int n = blockIdx.x*blockDim.x + threadIdx.x;
  if (n >= N) return;
  int* DF = (int*)(PD + 28);
  int f32 = DF[1];
  size_t rb = (size_t)n*35;
  double s = PD[15];
  double p0 = ((double)ldin(data, rb+0, f32) - PD[12])*s;
  double p1 = ((double)ldin(data, rb+1, f32) - PD[13])*s;
  double p2 = ((double)ldin(data, rb+2, f32) - PD[14])*s;
  float* xr = x + (size_t)n*36;
  int bb = 0;
  for (int j=0;j<3;++j){
    float v = (float)(p0*PD[16+j] + p1*PD[19+j] + p2*PD[22+j]);
    bb |= badf(v);
    xr[j] = v;
  }
  float mu1 = (float)PD[25], rs = (float)PD[26];
  for (int k=0;k<32;++k){
    float v = (ldin(data, rb+3+k, f32) - mu1)*rs*ldin(ln1w, k, f32) + ldin(ln1b, k, f32);
    bb |= badf(v);
    xr[3+k] = v;
  }
  xr[35] = 0.f;
  if (bb) atomicOr(DF, 4);
}

__global__ void k_count(const int* __restrict__ dst, int* __restrict__ cnt, int E){
  int i = blockIdx.x*blockDim.x + threadIdx.x;
  if (i < E) atomicAdd(&cnt[dst[i]], 1);
}

__global__ void k_scan1(const int* __restrict__ cnt, int* __restrict__ bsum, int N){
  int i = blockIdx.x*256 + threadIdx.x;
  int v = (i < N) ? cnt[i] : 0;
  #pragma unroll
  for (int o=32;o>0;o>>=1) v += __shfl_down(v, o);
  __shared__ int s4[4];
  if ((threadIdx.x&63)==0) s4[threadIdx.x>>6]=v;
  __syncthreads();
  if (threadIdx.x==0) bsum[blockIdx.x]=s4[0]+s4[1]+s4[2]+s4[3];
}

__global__ void k_scan2(const int* __restrict__ bsum, int* __restrict__ bpre,
                        int* __restrict__ iptr, int nb, int N){
  if (threadIdx.x != 0 || blockIdx.x != 0) return;
  int run = 0;
  for (int b=0;b<nb;++b){ bpre[b]=run; run += bsum[b]; }
  iptr[N] = run;
}

__global__ void k_scan3(const int* __restrict__ cnt, const int* __restrict__ bpre,
                        int* __restrict__ iptr, int* __restrict__ cur, int N){
  __shared__ int sc[256];
  int i = blockIdx.x*256 + threadIdx.x;
  int t = threadIdx.x;
  int v = (i < N) ? cnt[i] : 0;
  sc[t] = v;
  __syncthreads();
  for (int o=1;o<256;o<<=1){
    int add = (t >= o) ? sc[t-o] : 0;
    __syncthreads();
    sc[t] += add;
    __syncthreads();
  }
  if (i < N){
    int val = bpre[blockIdx.x] + sc[t] - v;
    iptr[i] = val;
    cur[i] = val;
  }
}

__global__ void k_scatter(const int* __restrict__ src, const int* __restrict__ dst,
                          const int* __restrict__ et, int* __restrict__ cur,
                          int* __restrict__ pack, int E){
  int i = blockIdx.x*blockDim.x + threadIdx.x;
  if (i < E){
    int d = dst[i];
    int p = atomicAdd(&cur[d], 1);
    pack[p] = src[i] | (et[i] << 20);
  }
}

// Pack B fragments (bf16, MFMA lane layout) for W (per r, kc, tile) and for
// the yq/yk side (u_r = W_r@q, v_r = W_r@k computed inline, hi/lo split).
__global__ void k_fragpack(const void* __restrict__ W, size_t wofs, int F, int KC,
                           const void* __restrict__ qp, const void* __restrict__ kp,
                           size_t qofs,
                           unsigned short* __restrict__ bfr,
                           unsigned short* __restrict__ qkfr,
                           const int* __restrict__ DF){
  int t = blockIdx.x*blockDim.x + threadIdx.x;
  int nB = 15*KC*2*64*8;
  int nQ = 2*2*KC*64*8;
  int f32 = DF[1];
  if (t < nB){
    int j = t & 7; int lane = (t >> 3) & 63; int tile = (t >> 9) & 1; int idx = t >> 10;
    int kc = idx % KC; int r = idx / KC;
    int f = kc*32 + (lane >> 4)*8 + j;
    int o = tile*16 + (lane & 15);
    bfr[t] = (f < F) ? f2bf(ldin(W, wofs + ((size_t)(r*F+f))*32 + o, f32)) : 0;
  } else if (t < nB + nQ){
    int u = t - nB;
    int j = u & 7; int lane = (u >> 3) & 63; int wpk = u >> 9;
    int kc = wpk % KC; int wp = wpk / KC;
    int part = wp & 1; int which = wp >> 1;
    int f = kc*32 + (lane >> 4)*8 + j;
    int rr = lane & 15;
    unsigned short val = 0;
    if (f < F && rr < 15){
      const void* v = which ? kp : qp;
      float acc = 0.f;
      for (int o = 0; o < 32; ++o)
        acc = fmaf(ldin(W, wofs + ((size_t)(rr*F+f))*32 + o, f32), ldin(v, qofs + o, f32), acc);
      unsigned short hi = f2bf(acc);
      val = (part == 0) ? hi : f2bf(acc - bf2f(hi));
    }
    qkfr[u] = val;
  }
}

// MFMA GEMM: per wave, 16 nodes x (15 r x 32 outs + yq/yk). X split hi/lo bf16.
__global__ void __launch_bounds__(256)
k_mf(const float* __restrict__ x, int str, int KC, int N,
     const unsigned short* __restrict__ bfr,
     const unsigned short* __restrict__ qkfr,
     unsigned short* __restrict__ y, float* __restrict__ yq, float* __restrict__ yk){
  int wave = blockIdx.x*(blockDim.x >> 6) + (threadIdx.x >> 6);
  int node0 = wave*16;
  if (node0 >= N) return;
  int lane = threadIdx.x & 63;
  int col = lane & 15, quad = lane >> 4;

  short8 ah[2], al[2];
  #pragma unroll
  for (int kc = 0; kc < 2; ++kc){
    if (kc >= KC) break;
    float xv[8];
    int node = node0 + col;           // A row m = lane&15
    int kbase = kc*32 + quad*8;
    if (node < N && kbase < str){
      const float* xr = x + (size_t)node*str + kbase;
      if (kbase + 8 <= str){
        float4 a = *(const float4*)xr; float4 b = *(const float4*)(xr + 4);
        xv[0]=a.x; xv[1]=a.y; xv[2]=a.z; xv[3]=a.w; xv[4]=b.x; xv[5]=b.y; xv[6]=b.z; xv[7]=b.w;
      } else if (kbase + 4 <= str){
        float4 a = *(const float4*)xr;
        xv[0]=a.x; xv[1]=a.y; xv[2]=a.z; xv[3]=a.w; xv[4]=0.f; xv[5]=0.f; xv[6]=0.f; xv[7]=0.f;
      } else {
        #pragma unroll
        for (int j=0;j<8;++j) xv[j]=0.f;
      }
    } else {
      #pragma unroll
      for (int j=0;j<8;++j) xv[j]=0.f;
    }
    #pragma unroll
    for (int j=0;j<8;++j){
      unsigned short hi = f2bf(xv[j]);
      ah[kc][j] = (short)hi;
      al[kc][j] = (short)f2bf(xv[j] - bf2f(hi));
    }
  }

  const short8* B  = (const short8*)bfr;
  const short8* QK = (const short8*)qkfr;

  // yq / yk tiles (cols = r), B-side hi/lo split too
  f32x4 aq = {0.f,0.f,0.f,0.f}, ak2 = {0.f,0.f,0.f,0.f};
  for (int kc = 0; kc < KC; ++kc){
    short8 qh = QK[((0*KC) + kc)*64 + lane];        // which=0 part=0
    short8 ql = QK[((1*KC) + kc)*64 + lane];        // which=0 part=1
    short8 kh = QK[((2*KC) + kc)*64 + lane];        // which=1 part=0
    short8 kl = QK[((3*KC) + kc)*64 + lane];        // which=1 part=1
    aq = mfma16(ah[kc], qh, aq);
    aq = mfma16(al[kc], qh, aq);
    aq = mfma16(ah[kc], ql, aq);
    ak2 = mfma16(ah[kc], kh, ak2);
    ak2 = mfma16(al[kc], kh, ak2);
    ak2 = mfma16(ah[kc], kl, ak2);
  }
  #pragma unroll
  for (int j = 0; j < 4; ++j){
    int node = node0 + quad*4 + j;
    if (node < N){
      yq[(size_t)node*16 + col] = aq[j];
      yk[(size_t)node*16 + col] = ak2[j];
    }
  }

  // y tiles per relation
  for (int r = 0; r < 15; ++r){
    f32x4 a0 = {0.f,0.f,0.f,0.f}, a1 = {0.f,0.f,0.f,0.f};
    for (int kc = 0; kc < KC; ++kc){
      short8 b0 = B[(((size_t)(r*KC + kc))*2 + 0)*64 + lane];
      short8 b1 = B[(((size_t)(r*KC + kc))*2 + 1)*64 + lane];
      a0 = mfma16(ah[kc], b0, a0);
      a0 = mfma16(al[kc], b0, a0);
      a1 = mfma16(ah[kc], b1, a1);
      a1 = mfma16(al[kc], b1, a1);
    }
    #pragma unroll
    for (int j = 0; j < 4; ++j){
      int node = node0 + quad*4 + j;
      if (node < N){
        unsigned short* yp = &y[(((size_t)r*N + node))*32 + col];
        yp[0]  = f2bf(a0[j]);
        yp[16] = f2bf(a1[j]);
      }
    }
  }
}

// softmax + aggregation; register-cached logits, 4x-unrolled gather,
// per-block LDS stat reduction -> partials, last block finalizes LN stats.
__global__ void k_main(const int* __restrict__ iptr, const int* __restrict__ pack,
                       const float* __restrict__ yq, const float* __restrict__ yk,
                       const unsigned short* __restrict__ y,
                       const void* __restrict__ biasp, size_t bofs,
                       const float* __restrict__ xres, float* __restrict__ hpre,
                       double* __restrict__ partials, double* __restrict__ PD,
                       int l, int* __restrict__ dcnt, int N){
  __shared__ double sdb[4][2];
  __shared__ int slast;
  int* DF = (int*)(PD + 28);
  int gt = blockIdx.x*blockDim.x + threadIdx.x;
  int node = gt >> 6, lane = gt & 63;
  int wid = threadIdx.x >> 6;
  int f32 = DF[1];
  int o = lane & 31;
  bool active = (node < N);
  float hp = 0.f;

  if (active){
    int start = iptr[node];
    int deg = iptr[node+1] - start;
    const float* yqn = yq + (size_t)node*16;
    int nc = (deg + 63) >> 6;

    // pass 1: segment max of leaky_relu(qi+kj), cache logits for <=4 chunks
    float av[4]; int pv[4];
    float amax = -INFINITY;
    for (int c = 0; c < nc; ++c){
      int k = c*64 + lane;
      float a = -INFINITY; int pe = 0;
      if (k < deg){
        pe = pack[start+k];
        int sr = pe & 0xFFFFF, et = pe >> 20;
        a = yqn[et] + yk[(size_t)sr*16+et];
        a = (a >= 0.f) ? a : 0.2f*a;
      }
      if (c < 4){ av[c] = a; pv[c] = pe; }
      amax = fmaxf(amax, a);
    }
    #pragma unroll
    for (int o2=32;o2>0;o2>>=1) amax = fmaxf(amax, __shfl_xor(amax, o2));

    // pass 2: exp weights from cached logits; 4x-unrolled weighted gather
    float ssum = 0.f;
    float acc = 0.f;
    for (int c = 0; c < nc; ++c){
      int k = c*64 + lane;
      float ev = 0.f; int pe = 0;
      if (c < 4){
        pe = pv[c];
        if (k < deg){ ev = expf(av[c] - amax); ssum += ev; }
      } else if (k < deg){
        pe = pack[start+k];
        int sr = pe & 0xFFFFF, et = pe >> 20;
        float a = yqn[et] + yk[(size_t)sr*16+et];
        a = (a >= 0.f) ? a : 0.2f*a;
        ev = expf(a - amax);
        ssum += ev;
      }
      int lim = min(64, deg - c*64);
      int sub = lane >> 5;
      for (; sub + 6 < lim; sub += 8){
        float w0 = __shfl(ev, sub),   w1 = __shfl(ev, sub+2);
        float w2 = __shfl(ev, sub+4), w3 = __shfl(ev, sub+6);
        int   p0 = __shfl(pe, sub),   p1 = __shfl(pe, sub+2);
        int   p2 = __shfl(pe, sub+4), p3 = __shfl(pe, sub+6);
        float v0 = bf2f(y[((size_t)(p0 >> 20)*N + (p0 & 0xFFFFF))*32 + o]);
        float v1 = bf2f(y[((size_t)(p1 >> 20)*N + (p1 & 0xFFFFF))*32 + o]);
        float v2 = bf2f(y[((size_t)(p2 >> 20)*N + (p2 & 0xFFFFF))*32 + o]);
        float v3 = bf2f(y[((size_t)(p3 >> 20)*N + (p3 & 0xFFFFF))*32 + o]);
        acc = fmaf(w0, v0, acc);
        acc = fmaf(w1, v1, acc);
        acc = fmaf(w2, v2, acc);
        acc = fmaf(w3, v3, acc);
      }
      for (; sub < lim; sub += 2){
        float wgt = __shfl(ev, sub);
        int pb = __shfl(pe, sub);
        acc = fmaf(wgt, bf2f(y[((size_t)(pb >> 20)*N + (pb & 0xFFFFF))*32 + o]), acc);
      }
    }
    #pragma unroll
    for (int o2=32;o2>0;o2>>=1) ssum += __shfl_xor(ssum, o2);
    float inv = 1.f/(ssum + 1e-16f);
    acc *= inv;
    acc += __shfl_xor(acc, 32);

    if (lane < 32){
      hp = acc + ldin(biasp, bofs + o, f32);
      if (xres) hp += xres[(size_t)node*32 + o];
      if (badf(hp)) atomicOr(DF, 32);
      hpre[(size_t)node*32 + o] = hp;
    }
  }

  // block-level LN stats (no global atomics)
  float s1 = (active && lane < 32) ? hp : 0.f;
  float s2 = s1*s1;
  #pragma unroll
  for (int o2=32;o2>0;o2>>=1){ s1 += __shfl_xor(s1,o2); s2 += __shfl_xor(s2,o2); }
  if (lane == 0){ sdb[wid][0] = (double)s1; sdb[wid][1] = (double)s2; }
  __syncthreads();
  if (threadIdx.x == 0){
    partials[(size_t)blockIdx.x*2]   = sdb[0][0]+sdb[1][0]+sdb[2][0]+sdb[3][0];
    partials[(size_t)blockIdx.x*2+1] = sdb[0][1]+sdb[1][1]+sdb[2][1]+sdb[3][1];
    __threadfence();
    int v = atomicAdd(&dcnt[l], 1);
    slast = (v == (int)gridDim.x - 1) ? 1 : 0;
  }
  __syncthreads();
  if (slast){
    // last block reduces all partials -> LN stats for this layer
    double t1 = 0.0, t2 = 0.0;
    for (int i = threadIdx.x; i < (int)gridDim.x; i += 256){
      t1 += partials[(size_t)i*2];
      t2 += partials[(size_t)i*2+1];
    }
    t1 = wsum_d(t1); t2 = wsum_d(t2);
    __shared__ double sd[8];
    int w = threadIdx.x >> 6;
    if ((threadIdx.x & 63) == 0){ sd[w*2] = t1; sd[w*2+1] = t2; }
    __syncthreads();
    if (threadIdx.x == 0){
      PD[32+2*l]   = sd[0]+sd[2]+sd[4]+sd[6];
      PD[32+2*l+1] = sd[1]+sd[3]+sd[5]+sd[7];
    }
  }
}

__global__ void k_ln(float* __restrict__ h, const void* __restrict__ lnw,
                     const void* __restrict__ lnb, size_t lofs,
                     double* __restrict__ PD, int l, int N){
  int idx = blockIdx.x*blockDim.x + threadIdx.x;
  if (idx >= N*32) return;
  int* DF = (int*)(PD + 28);
  int f32 = DF[1];
  const double* stats = PD + 32 + 2*l;
  int o = idx & 31;
  double cntf = (double)N*32.0;
  double mu = stats[0]/cntf;
  double var = stats[1]/cntf - mu*mu;
  float rstd = (float)(1.0/(sqrt(var>0.0?var:0.0) + 1e-5));
  float v = (h[idx] - (float)mu)*rstd*ldin(lnw, lofs + o, f32) + ldin(lnb, lofs + o, f32);
  v = v / (1.f + expf(-v));
  if (badf(v)) atomicOr(DF, 64);
  h[idx] = v;
}

__global__ void k_pool(const float* __restrict__ h, double* __restrict__ PD, int N){
  __shared__ float sp[8][33];
  int t = threadIdx.x, o = t & 31, g = t >> 5;
  int r0 = blockIdx.x*256;
  float s = 0.f;
  for (int r = r0 + g; r < N && r < r0 + 256; r += 8) s += h[(size_t)r*32 + o];
  sp[g][o] = s;
  __syncthreads();
  if (t < 32){
    float tot = 0.f;
    #pragma unroll
    for (int g2=0; g2<8; ++g2) tot += sp[g2][t];
    atomicAdd(&PD[40 + t], (double)tot);
  }
}

__global__ void k_out(double* __restrict__ PD, const void* __restrict__ Wl,
                      const void* __restrict__ bl, void* __restrict__ out, int N, int H2){
  int j = blockIdx.x*blockDim.x + threadIdx.x;
  if (j >= H2) return;
  int* DF = (int*)(PD + 28);
  int f32 = DF[1];
  int flag = DF[0];
  const double* pool = PD + 40;
  float acc = ldin(bl, j, f32);
  for (int o=0;o<32;++o)
    acc = fmaf((float)(pool[o]/(double)N), ldin(Wl, (size_t)j*32+o, f32), acc);
  if (badf(acc)) flag |= 128;
  float v = acc / (1.f + expf(-acc));
  if (flag) v = (float)flag;   // diagnostic: absmax == stage bitmask
  if (f32) ((float*)out)[j] = v;
  else     ((unsigned short*)out)[j] = f2bf(v);
}

__global__ void k_diag(unsigned short* out, float val, int H2){
  int j = blockIdx.x*blockDim.x + threadIdx.x;
  if (j < H2) out[j] = f2bf(val);
}

// ---------------- entry ----------------
extern "C" void kernel_launch(void* const* d_in, const int* in_sizes, int n_in,
                              void* d_out, int out_size, void* d_ws, size_t ws_size,
                              hipStream_t stream)
{
  const int N  = in_sizes[0] / 35;
  const int E  = in_sizes[3];
  const int R  = 15;
  const int H2 = in_sizes[19];

  const void* data = d_in[0];
  const int* ei  = (const int*)d_in[2];
  const int* etp = (const int*)d_in[3];
  const void* W0  = d_in[6];
  const void* q0  = d_in[7];
  const void* k0  = d_in[8];
  const void* b0  = d_in[9];
  const void* Wsp = d_in[10];
  const void* qsp = d_in[11];
  const void* ksp = d_in[12];
  const void* bsp = d_in[13];
  const void* lnw = d_in[14];
  const void* lnb = d_in[15];
  const void* ln1w= d_in[16];
  const void* ln1b= d_in[17];
  const void* l1W = d_in[18];
  const void* l1b = d_in[19];

  char* base = (char*)d_ws;
  size_t off = 0;
  auto A = [&](size_t nb)->size_t { size_t c = off; off += (nb + 255) & ~(size_t)255; return c; };
  size_t oPD  = A(1024);
  size_t oCnt = A((size_t)N*4);
  size_t oPtr = A(((size_t)N+1)*4);
  size_t oCur = A((size_t)N*4);
  size_t oBs  = A(4096);
  size_t oBp  = A(4096);
  size_t oPk  = A((size_t)E*4);
  size_t oX   = A((size_t)N*36*4);
  size_t oH0  = A((size_t)N*32*4);
  size_t oH1  = A((size_t)N*32*4);
  size_t oYq  = A((size_t)N*16*4);
  size_t oYk  = A((size_t)N*16*4);
  size_t oBf  = A((size_t)15*2*2*64*8*2);
  size_t oQk  = A((size_t)2*2*2*64*8*2);
  int nbMain  = (int)(((size_t)N*64 + 255)/256);
  size_t oPt  = A((size_t)nbMain*2*8);
  size_t oY   = off;
  size_t needB = oY + (size_t)R*N*32*2;

  double* PD  = (double*)(base + oPD);
  int* DF     = (int*)(PD + 28);
  int* dcnt   = (int*)(PD + 29);   // 4 ints, zeroed by memset
  int* cnt    = (int*)(base + oCnt);
  int* iptr   = (int*)(base + oPtr);
  int* cur    = (int*)(base + oCur);
  int* bsum   = (int*)(base + oBs);
  int* bpre   = (int*)(base + oBp);
  int* pack   = (int*)(base + oPk);
  float* xb   = (float*)(base + oX);
  float* h0   = (float*)(base + oH0);
  float* h1   = (float*)(base + oH1);
  float* yqb  = (float*)(base + oYq);
  float* ykb  = (float*)(base + oYk);
  unsigned short* bfr  = (unsigned short*)(base + oBf);
  unsigned short* qkfr = (unsigned short*)(base + oQk);
  double* partials = (double*)(base + oPt);
  unsigned short* y = (unsigned short*)(base + oY);

  if (ws_size < needB){
    k_diag<<<1, 256, 0, stream>>>((unsigned short*)d_out, (float)(ws_size >> 20), H2);
    return;
  }

  // zero PD + cnt ( [0, oPtr) covers both exactly )
  hipMemsetAsync(base, 0, oPtr, stream);

  int nbN = (N + 255)/256;
  int nbE = (E + 255)/256;
  int nus = (in_sizes[0] < 1024) ? in_sizes[0] : 1024;

  k_dtype<<<1, 256, 0, stream>>>((const unsigned short*)data, nus, PD);
  k_red1<<<nbN, 256, 0, stream>>>(data, N, PD);
  k_eig<<<1, 1, 0, stream>>>(PD, N);
  k_buildx<<<nbN, 256, 0, stream>>>(data, ln1w, ln1b, PD, xb, N);

  k_count<<<nbE, 256, 0, stream>>>(ei + E, cnt, E);
  k_scan1<<<nbN, 256, 0, stream>>>(cnt, bsum, N);
  k_scan2<<<1, 1, 0, stream>>>(bsum, bpre, iptr, nbN, N);
  k_scan3<<<nbN, 256, 0, stream>>>(cnt, bpre, iptr, cur, N);
  k_scatter<<<nbE, 256, 0, stream>>>(ei, ei + E, etp, cur, pack, E);

  int nbMf = (int)(((N + 15)/16 + 3)/4);
  for (int l=0; l<4; ++l){
    const void* W  = (l==0)? W0 : Wsp;  size_t wofs = (l==0)? 0 : (size_t)(l-1)*R*32*32;
    const void* qp = (l==0)? q0 : qsp;  size_t qofs = (l==0)? 0 : (size_t)(l-1)*32;
    const void* kp = (l==0)? k0 : ksp;
    const void* bp = (l==0)? b0 : bsp;  size_t bofs = qofs;
    int str = (l==0)? 36 : 32;
    int KC = (l==0)? 2 : 1;
    int F = (l==0)? 35 : 32;
    const float* xin = (l==0)? xb : ((l%2==0)? h1 : h0);
    float* hout = (l%2==0)? h0 : h1;
    int nFrag = 15*KC*2*64*8 + 2*2*KC*64*8;
    k_fragpack<<<(nFrag+255)/256, 256, 0, stream>>>(W, wofs, F, KC, qp, kp, qofs, bfr, qkfr, DF);
    k_mf<<<nbMf, 256, 0, stream>>>(xin, str, KC, N, bfr, qkfr, y, yqb, ykb);
    k_main<<<nbMain, 256, 0, stream>>>(iptr, pack, yqb, ykb, y, bp, bofs,
                 (l==0)? (const float*)nullptr : xin, hout, partials, PD, l, dcnt, N);
    k_ln<<<(N*32+255)/256, 256, 0, stream>>>(hout, lnw, lnb, (size_t)l*32, PD, l, N);
  }

  k_pool<<<nbN, 256, 0, stream>>>(h1, PD, N);
  k_out<<<(H2+255)/256, 256, 0, stream>>>(PD, l1W, l1b, d_out, N, H2);
}

// Round 7
// 4562.626 us; speedup vs baseline: 1.0086x; 1.0086x over previous
//
#include <hip/hip_runtime.h>
#include <math.h>
#include <stdint.h>

// ---------------- helpers ----------------
__device__ inline float bf2f(unsigned short u){
  union { unsigned int i; float f; } x; x.i = ((unsigned int)u) << 16; return x.f;
}
__device__ inline unsigned short f2bf(float f){
  union { float f; unsigned int i; } x; x.f = f;
  unsigned int u = x.i;
  return (unsigned short)((u + 0x7FFFu + ((u >> 16) & 1u)) >> 16);
}
// dtype-dispatched input load: f32 flag comes from device-side probe
__device__ inline float ldin(const void* p, size_t i, int f32){
  return f32 ? ((const float*)p)[i] : bf2f(((const unsigned short*)p)[i]);
}

__device__ inline int badf(float v){ return !(fabsf(v) <= 3.0e38f); }
__device__ inline int badd(double v){ return !(fabs(v) <= 1.0e300); }

__device__ inline double wsum_d(double v){
  #pragma unroll
  for (int o = 32; o > 0; o >>= 1) v += __shfl_down(v, o);
  return v;
}
__device__ inline double wmax_d(double v){
  #pragma unroll
  for (int o = 32; o > 0; o >>= 1) v = fmax(v, __shfl_down(v, o));
  return v;
}
__device__ inline void atomicMaxD(double* addr, double v){ // v >= 0
  atomicMax((unsigned long long*)addr, (unsigned long long)__double_as_longlong(v));
}

// MFMA types
typedef __attribute__((ext_vector_type(8))) short short8;
typedef __attribute__((ext_vector_type(4))) float f32x4;
__device__ inline f32x4 mfma16(short8 a, short8 b, f32x4 c){
  return __builtin_amdgcn_mfma_f32_16x16x32_bf16(a, b, c, 0, 0, 0);
}

// ---------------- LAPACK 3x3 eigh port (dsytd2 + dsteqr + dormtr) ----------------
__device__ inline double d_sign(double a, double b){ return (b >= 0.0) ? fabs(a) : -fabs(a); }
__device__ inline double dlapy2_(double x, double y){ return sqrt(x*x + y*y); }

__device__ void dlartg_(double f, double g, double* cs, double* sn, double* r){
  // LAPACK >= 3.10 convention: c >= 0, r = sign(d, f)
  if (g == 0.0){ *cs = 1.0; *sn = 0.0; *r = f; }
  else if (f == 0.0){ *cs = 0.0; *sn = (g >= 0.0) ? 1.0 : -1.0; *r = fabs(g); }
  else {
    double d = sqrt(f*f + g*g);
    *cs = fabs(f)/d;
    *r  = d_sign(d, f);
    *sn = g / (*r);
  }
}

__device__ void dlaev2_(double a, double b, double c, double* rt1, double* rt2,
                        double* cs1, double* sn1){
  double sm = a + c, df = a - c, adf = fabs(df), tb = b + b, ab = fabs(tb);
  double acmx, acmn;
  if (fabs(a) > fabs(c)){ acmx = a; acmn = c; } else { acmx = c; acmn = a; }
  double rt;
  if (adf > ab) rt = adf*sqrt(1.0 + (ab/adf)*(ab/adf));
  else if (adf < ab) rt = ab*sqrt(1.0 + (adf/ab)*(adf/ab));
  else rt = ab*sqrt(2.0);
  int sgn1;
  if (sm < 0.0){ *rt1 = 0.5*(sm - rt); sgn1 = -1; *rt2 = (acmx/(*rt1))*acmn - (b/(*rt1))*b; }
  else if (sm > 0.0){ *rt1 = 0.5*(sm + rt); sgn1 = 1; *rt2 = (acmx/(*rt1))*acmn - (b/(*rt1))*b; }
  else { *rt1 = 0.5*rt; *rt2 = -0.5*rt; sgn1 = 1; }
  int sgn2; double cs;
  if (df >= 0.0){ cs = df + rt; sgn2 = 1; } else { cs = df - rt; sgn2 = -1; }
  double acs = fabs(cs);
  if (acs > ab){ double ct = -tb/cs; *sn1 = 1.0/sqrt(1.0+ct*ct); *cs1 = ct*(*sn1); }
  else {
    if (ab == 0.0){ *cs1 = 1.0; *sn1 = 0.0; }
    else { double tn = -cs/tb; *cs1 = 1.0/sqrt(1.0+tn*tn); *sn1 = tn*(*cs1); }
  }
  if (sgn1 == sgn2){ double tn = *cs1; *cs1 = -(*sn1); *sn1 = tn; }
}

__device__ void dsteqr3_(double* dd, double* ee, double z[3][3]){
  #define D_(i) dd[(i)-1]
  #define E_(i) ee[(i)-1]
  #define Z_(i,j) z[(i)-1][(j)-1]
  #define CW_(i) cw[(i)-1]
  #define SW_(i) sw[(i)-1]
  const int n = 3;
  const double eps = 1.1102230246251565e-16;
  const double eps2 = eps*eps;
  const double safmin = 2.2250738585072014e-308;
  const int nmaxit = n*30;
  double cw[3], sw[3];
  int jtot = 0;
  int l1 = 1, l, m, lsv, lend, lendsv;
  double p, g, r, c, s, f, b, rt1, rt2, anorm, tst;

L10:
  if (l1 > n) goto L160;
  if (l1 > 1) E_(l1-1) = 0.0;
  if (l1 <= n-1){
    for (m = l1; m <= n-1; ++m){
      tst = fabs(E_(m));
      if (tst == 0.0) goto L30;
      if (tst <= (sqrt(fabs(D_(m)))*sqrt(fabs(D_(m+1))))*eps){ E_(m) = 0.0; goto L30; }
    }
  }
  m = n;
L30:
  l = l1; lsv = l; lend = m; lendsv = lend; l1 = m+1;
  if (lend == l) goto L10;
  anorm = 0.0;
  for (int i = l; i <= lend; ++i) anorm = fmax(anorm, fabs(D_(i)));
  for (int i = l; i <= lend-1; ++i) anorm = fmax(anorm, fabs(E_(i)));
  if (anorm == 0.0) goto L10;
  if (fabs(D_(lend)) < fabs(D_(l))){ lend = lsv; l = lendsv; }
  if (lend > l) goto L40; else goto L90;

  // -------- QL iteration --------
L40:
  if (l != lend){
    for (m = l; m <= lend-1; ++m){
      tst = fabs(E_(m)); tst = tst*tst;
      if (tst <= (eps2*fabs(D_(m)))*fabs(D_(m+1)) + safmin) goto L60;
    }
  }
  m = lend;
L60:
  if (m < lend) E_(m) = 0.0;
  p = D_(l);
  if (m == l) goto L80;
  if (m == l+1){
    dlaev2_(D_(l), E_(l), D_(l+1), &rt1, &rt2, &c, &s);
    CW_(l) = c; SW_(l) = s;
    { double ct = CW_(l), st = SW_(l);
      if (ct != 1.0 || st != 0.0)
        for (int i = 1; i <= n; ++i){
          double t = Z_(i, l+1);
          Z_(i, l+1) = ct*t - st*Z_(i, l);
          Z_(i, l)   = st*t + ct*Z_(i, l);
        }
    }
    D_(l) = rt1; D_(l+1) = rt2; E_(l) = 0.0;
    l += 2;
    if (l <= lend) goto L40;
    goto L140;
  }
  if (jtot == nmaxit) goto L140;
  jtot++;
  g = (D_(l+1) - p)/(2.0*E_(l));
  r = dlapy2_(g, 1.0);
  g = D_(m) - p + E_(l)/(g + d_sign(r, g));
  s = 1.0; c = 1.0; p = 0.0;
  for (int i = m-1; i >= l; --i){
    f = s*E_(i); b = c*E_(i);
    dlartg_(g, f, &c, &s, &r);
    if (i != m-1) E_(i+1) = r;
    g = D_(i+1) - p;
    r = (D_(i) - g)*s + 2.0*c*b;
    p = s*r;
    D_(i+1) = g + p;
    g = c*r - b;
    CW_(i) = c; SW_(i) = -s;
  }
  { int mm = m - l + 1;
    for (int j = mm-1; j >= 1; --j){
      double ct = CW_(l+j-1), st = SW_(l+j-1);
      if (ct != 1.0 || st != 0.0)
        for (int i = 1; i <= n; ++i){
          double t = Z_(i, l+j);
          Z_(i, l+j)   = ct*t - st*Z_(i, l+j-1);
          Z_(i, l+j-1) = st*t + ct*Z_(i, l+j-1);
        }
    }
  }
  D_(l) = D_(l) - p;
  E_(l) = g;
  goto L40;
L80:
  D_(l) = p;
  l++;
  if (l <= lend) goto L40;
  goto L140;

  // -------- QR iteration --------
L90:
  if (l != lend){
    for (m = l; m >= lend+1; --m){
      tst = fabs(E_(m-1)); tst = tst*tst;
      if (tst <= (eps2*fabs(D_(m)))*fabs(D_(m-1)) + safmin) goto L110;
    }
  }
  m = lend;
L110:
  if (m > lend) E_(m-1) = 0.0;
  p = D_(l);
  if (m == l) goto L130;
  if (m == l-1){
    dlaev2_(D_(l-1), E_(l-1), D_(l), &rt1, &rt2, &c, &s);
    CW_(m) = c; SW_(m) = s;
    { double ct = CW_(m), st = SW_(m);
      if (ct != 1.0 || st != 0.0)
        for (int i = 1; i <= n; ++i){
          double t = Z_(i, l);
          Z_(i, l)   = ct*t - st*Z_(i, l-1);
          Z_(i, l-1) = st*t + ct*Z_(i, l-1);
        }
    }
    D_(l-1) = rt1; D_(l) = rt2; E_(l-1) = 0.0;
    l -= 2;
    if (l >= lend) goto L90;
    goto L140;
  }
  if (jtot == nmaxit) goto L140;
  jtot++;
  g = (D_(l-1) - p)/(2.0*E_(l-1));
  r = dlapy2_(g, 1.0);
  g = D_(m) - p + E_(l-1)/(g + d_sign(r, g));
  s = 1.0; c = 1.0; p = 0.0;
  for (int i = m; i <= l-1; ++i){
    f = s*E_(i); b = c*E_(i);
    dlartg_(g, f, &c, &s, &r);
    if (i != m) E_(i-1) = r;
    g = D_(i) - p;
    r = (D_(i+1) - g)*s + 2.0*c*b;
    p = s*r;
    D_(i) = g + p;
    g = c*r - b;
    CW_(i) = c; SW_(i) = s;
  }
  { int mm = l - m + 1;
    for (int j = 1; j <= mm-1; ++j){
      double ct = CW_(m+j-1), st = SW_(m+j-1);
      if (ct != 1.0 || st != 0.0)
        for (int i = 1; i <= n; ++i){
          double t = Z_(i, m+j);
          Z_(i, m+j)   = ct*t - st*Z_(i, m+j-1);
          Z_(i, m+j-1) = st*t + ct*Z_(i, m+j-1);
        }
    }
  }
  D_(l) = D_(l) - p;
  E_(l-1) = g;
  goto L90;
L130:
  D_(l) = p;
  l--;
  if (l >= lend) goto L90;
  goto L140;

L140:
  if (jtot < nmaxit) goto L10;
  goto L190;

L160:
  for (int ii = 2; ii <= n; ++ii){
    int i = ii-1, k = i;
    p = D_(i);
    for (int j = ii; j <= n; ++j) if (D_(j) < p){ k = j; p = D_(j); }
    if (k != i){
      D_(k) = D_(i); D_(i) = p;
      for (int rr = 1; rr <= n; ++rr){ double t = Z_(rr,i); Z_(rr,i) = Z_(rr,k); Z_(rr,k) = t; }
    }
  }
L190:
  ;
  #undef D_
  #undef E_
  #undef Z_
  #undef CW_
  #undef SW_
}

__device__ void eigh3_(const double C[3][3], double w[3], double v[3][3]){
  double a00=C[0][0], a10=C[1][0], a20=C[2][0], a11=C[1][1], a21=C[2][1], a22=C[2][2];
  double dd[3], ee[2], tau, v2;
  double alpha = a10, x = a20;
  double xnorm = fabs(x);
  if (xnorm == 0.0){ tau = 0.0; v2 = 0.0; ee[0] = alpha; }
  else {
    double beta = -d_sign(dlapy2_(alpha, xnorm), alpha);
    tau = (beta - alpha)/beta;
    v2 = x/(alpha - beta);
    ee[0] = beta;
  }
  if (tau != 0.0){
    double w0 = tau*(a11 + a21*v2);
    double w1 = tau*(a21 + a22*v2);
    double wv = w0 + w1*v2;
    double ac = -0.5*tau*wv;
    w0 += ac; w1 += ac*v2;
    a11 = a11 - 2.0*w0;
    a21 = a21 - (v2*w0 + w1);
    a22 = a22 - 2.0*v2*w1;
  }
  dd[0]=a00; dd[1]=a11; dd[2]=a22; ee[1]=a21;
  double z[3][3] = {{1,0,0},{0,1,0},{0,0,1}};
  dsteqr3_(dd, ee, z);
  for (int j = 0; j < 3; ++j){
    double t = z[1][j] + v2*z[2][j];
    z[1][j] -= tau*t;
    z[2][j] -= tau*t*v2;
  }
  for (int i=0;i<3;++i){ w[i]=dd[i]; for(int j=0;j<3;++j) v[i][j]=z[i][j]; }
}

// ---------------- kernels ----------------
// PD layout (doubles): 0-2 possum, 3 fsum, 4 fsumsq, 5-10 raw pos moments
// (m00,m10,m20,m11,m21,m22), 12-14 mean, 15 scale, 16-24 V, 25 mu1, 26 rstd1,
// 28: int flag + int isf32, 29-30: int dcnt[4] (last-block counters),
// 32+2l per-layer LN stats, 40-71 pool, 72-74 max(64+p), 75-77 max(64-p)

__global__ void k_dtype(const unsigned short* __restrict__ data, int nus, double* PD){
  int* DF = (int*)(PD + 28);
  int t = threadIdx.x;
  int bad = 0;
  for (int i = t; i < nus; i += 256){
    int e = (data[i] >> 7) & 0xFF;
    if (e > 0x90 || (e && e < 0x60)) bad++;
  }
  #pragma unroll
  for (int o = 32; o > 0; o >>= 1) bad += __shfl_down(bad, o);
  __shared__ int sb[4];
  if ((t & 63) == 0) sb[t >> 6] = bad;
  __syncthreads();
  if (t == 0) DF[1] = ((sb[0]+sb[1]+sb[2]+sb[3]) > nus/16) ? 1 : 0;
}

// single pass: pos sums, raw second moments, min/max (as max(64±p)), feat sums
__global__ void k_red1(const void* __restrict__ data, int N, double* PD){
  int n = blockIdx.x*blockDim.x + threadIdx.x;
  const int* DF = (const int*)(PD + 28);
  int f32 = DF[1];
  double vals[11] = {0,0,0,0,0,0,0,0,0,0,0};
  double mp[3] = {0,0,0}, mn[3] = {0,0,0};
  if (n < N){
    size_t rb = (size_t)n*35;
    double p0 = ldin(data, rb+0, f32);
    double p1 = ldin(data, rb+1, f32);
    double p2 = ldin(data, rb+2, f32);
    vals[0]=p0; vals[1]=p1; vals[2]=p2;
    double fs=0, fss=0;
    for (int k=3;k<35;++k){ double v = ldin(data, rb+k, f32); fs += v; fss += v*v; }
    vals[3]=fs; vals[4]=fss;
    vals[5]=p0*p0; vals[6]=p1*p0; vals[7]=p2*p0; vals[8]=p1*p1; vals[9]=p2*p1; vals[10]=p2*p2;
    mp[0]=64.0+p0; mp[1]=64.0+p1; mp[2]=64.0+p2;
    mn[0]=64.0-p0; mn[1]=64.0-p1; mn[2]=64.0-p2;
  }
  __shared__ double sred[4];
  for (int q=0;q<11;++q){
    double t = wsum_d(vals[q]);
    if ((threadIdx.x&63)==0) sred[threadIdx.x>>6]=t;
    __syncthreads();
    if (threadIdx.x==0) atomicAdd(&PD[q], sred[0]+sred[1]+sred[2]+sred[3]);
    __syncthreads();
  }
  for (int j=0;j<6;++j){
    double t = wmax_d(j<3 ? mp[j] : mn[j-3]);
    if ((threadIdx.x&63)==0) sred[threadIdx.x>>6]=t;
    __syncthreads();
    if (threadIdx.x==0)
      atomicMaxD(&PD[72+j], fmax(fmax(sred[0],sred[1]), fmax(sred[2],sred[3])));
    __syncthreads();
  }
}

__global__ void k_eig(double* PD, int N){
  if (threadIdx.x != 0 || blockIdx.x != 0) return;
  int* DF = (int*)(PD + 28);
  int bad0 = 0;
  for (int i=0;i<11;++i) if (badd(PD[i])) bad0 = 1;
  if (bad0) DF[0] |= 1;
  double dN = (double)N;
  double mu[3] = {PD[0]/dN, PD[1]/dN, PD[2]/dN};
  double amax = 0.0;
  for (int j=0;j<3;++j){
    double mx = (PD[72+j] - 64.0) - mu[j];
    double mnv = mu[j] - (64.0 - PD[75+j]);
    amax = fmax(amax, fmax(mx, mnv));
  }
  double s = 0.999999/amax;
  double s2 = s*s;
  double C[3][3];
  C[0][0]=(PD[5]-dN*mu[0]*mu[0])*s2; C[1][0]=(PD[6]-dN*mu[1]*mu[0])*s2;
  C[2][0]=(PD[7]-dN*mu[2]*mu[0])*s2; C[1][1]=(PD[8]-dN*mu[1]*mu[1])*s2;
  C[2][1]=(PD[9]-dN*mu[2]*mu[1])*s2; C[2][2]=(PD[10]-dN*mu[2]*mu[2])*s2;
  C[0][1]=C[1][0]; C[0][2]=C[2][0]; C[1][2]=C[2][1];
  double w[3], V[3][3];
  eigh3_(C, w, V);
  int bad1 = 0;
  for (int i=0;i<3;++i){ if (badd(w[i])) bad1=1; for (int j=0;j<3;++j) if (badd(V[i][j])) bad1=1; }
  if (bad1){
    DF[0] |= 2;
    for (int i=0;i<3;++i) for (int j=0;j<3;++j) V[i][j] = (i==j) ? 1.0 : 0.0;
  }
  PD[12]=mu[0]; PD[13]=mu[1]; PD[14]=mu[2];
  PD[15]=s;
  for (int i=0;i<3;++i) for (int j=0;j<3;++j) PD[16+i*3+j]=V[i][j];
  double cntf = dN*32.0;
  double mu1 = PD[3]/cntf;
  double var = PD[4]/cntf - mu1*mu1;
  PD[25]=mu1;
  PD[26]=1.0/(sqrt(var>0.0?var:0.0)+1e-5);
}

__global__ void k_buildx(const void* __restrict__ data,
                         const void* __restrict__ ln1w,
                         const void* __restrict__ ln1b,
                         double* __restrict__ PD, float* __restrict__ x, int N){
  int n = blockIdx.x*blockDim.x + threadIdx.x;
  if (n >= N) return;
  int* DF = (int*)(PD + 28);
  int f32 = DF[1];
  size_t rb = (size_t)n*35;
  double s = PD[15];
  double p0 = ((double)ldin(data, rb+0, f32) - PD[12])*s;
  double p1 = ((double)ldin(data, rb+1, f32) - PD[13])*s;
  double p2 = ((double)ldin(data, rb+2, f32) - PD[14])*s;
  float* xr = x + (size_t)n*36;
  int bb = 0;
  for (int j=0;j<3;++j){
    float v = (float)(p0*PD[16+j] + p1*PD[19+j] + p2*PD[22+j]);
    bb |= badf(v);
    xr[j] = v;
  }
  float mu1 = (float)PD[25], rs = (float)PD[26];
  for (int k=0;k<32;++k){
    float v = (ldin(data, rb+3+k, f32) - mu1)*rs*ldin(ln1w, k, f32) + ldin(ln1b, k, f32);
    bb |= badf(v);
    xr[3+k] = v;
  }
  xr[35] = 0.f;
  if (bb) atomicOr(DF, 4);
}

__global__ void k_count(const int* __restrict__ dst, int* __restrict__ cnt, int E){
  int i = blockIdx.x*blockDim.x + threadIdx.x;
  if (i < E) atomicAdd(&cnt[dst[i]], 1);
}

__global__ void k_scan1(const int* __restrict__ cnt, int* __restrict__ bsum, int N){
  int i = blockIdx.x*256 + threadIdx.x;
  int v = (i < N) ? cnt[i] : 0;
  #pragma unroll
  for (int o=32;o>0;o>>=1) v += __shfl_down(v, o);
  __shared__ int s4[4];
  if ((threadIdx.x&63)==0) s4[threadIdx.x>>6]=v;
  __syncthreads();
  if (threadIdx.x==0) bsum[blockIdx.x]=s4[0]+s4[1]+s4[2]+s4[3];
}

__global__ void k_scan2(const int* __restrict__ bsum, int* __restrict__ bpre,
                        int* __restrict__ iptr, int nb, int N){
  if (threadIdx.x != 0 || blockIdx.x != 0) return;
  int run = 0;
  for (int b=0;b<nb;++b){ bpre[b]=run; run += bsum[b]; }
  iptr[N] = run;
}

__global__ void k_scan3(const int* __restrict__ cnt, const int* __restrict__ bpre,
                        int* __restrict__ iptr, int* __restrict__ cur, int N){
  __shared__ int sc[256];
  int i = blockIdx.x*256 + threadIdx.x;
  int t = threadIdx.x;
  int v = (i < N) ? cnt[i] : 0;
  sc[t] = v;
  __syncthreads();
  for (int o=1;o<256;o<<=1){
    int add = (t >= o) ? sc[t-o] : 0;
    __syncthreads();
    sc[t] += add;
    __syncthreads();
  }
  if (i < N){
    int val = bpre[blockIdx.x] + sc[t] - v;
    iptr[i] = val;
    cur[i] = val;
  }
}

__global__ void k_scatter(const int* __restrict__ src, const int* __restrict__ dst,
                          const int* __restrict__ et, int* __restrict__ cur,
                          int* __restrict__ pack, int E){
  int i = blockIdx.x*blockDim.x + threadIdx.x;
  if (i < E){
    int d = dst[i];
    int p = atomicAdd(&cur[d], 1);
    pack[p] = src[i] | (et[i] << 20);
  }
}

// Pack B fragments (bf16, MFMA lane layout) for W (per r, kc, tile) and for
// the yq/yk side (u_r = W_r@q, v_r = W_r@k computed inline, hi/lo split).
__global__ void k_fragpack(const void* __restrict__ W, size_t wofs, int F, int KC,
                           const void* __restrict__ qp, const void* __restrict__ kp,
                           size_t qofs,
                           unsigned short* __restrict__ bfr,
                           unsigned short* __restrict__ qkfr,
                           const int* __restrict__ DF){
  int t = blockIdx.x*blockDim.x + threadIdx.x;
  int nB = 15*KC*2*64*8;
  int nQ = 2*2*KC*64*8;
  int f32 = DF[1];
  if (t < nB){
    int j = t & 7; int lane = (t >> 3) & 63; int tile = (t >> 9) & 1; int idx = t >> 10;
    int kc = idx % KC; int r = idx / KC;
    int f = kc*32 + (lane >> 4)*8 + j;
    int o = tile*16 + (lane & 15);
    bfr[t] = (f < F) ? f2bf(ldin(W, wofs + ((size_t)(r*F+f))*32 + o, f32)) : 0;
  } else if (t < nB + nQ){
    int u = t - nB;
    int j = u & 7; int lane = (u >> 3) & 63; int wpk = u >> 9;
    int kc = wpk % KC; int wp = wpk / KC;
    int part = wp & 1; int which = wp >> 1;
    int f = kc*32 + (lane >> 4)*8 + j;
    int rr = lane & 15;
    unsigned short val = 0;
    if (f < F && rr < 15){
      const void* v = which ? kp : qp;
      float acc = 0.f;
      for (int o = 0; o < 32; ++o)
        acc = fmaf(ldin(W, wofs + ((size_t)(rr*F+f))*32 + o, f32), ldin(v, qofs + o, f32), acc);
      unsigned short hi = f2bf(acc);
      val = (part == 0) ? hi : f2bf(acc - bf2f(hi));
    }
    qkfr[u] = val;
  }
}

// MFMA GEMM: per wave, 16 nodes x (15 r x 32 outs + yq/yk). X split hi/lo bf16.
__global__ void __launch_bounds__(256)
k_mf(const float* __restrict__ x, int str, int KC, int N,
     const unsigned short* __restrict__ bfr,
     const unsigned short* __restrict__ qkfr,
     unsigned short* __restrict__ y, float* __restrict__ yq, float* __restrict__ yk){
  int wave = blockIdx.x*(blockDim.x >> 6) + (threadIdx.x >> 6);
  int node0 = wave*16;
  if (node0 >= N) return;
  int lane = threadIdx.x & 63;
  int col = lane & 15, quad = lane >> 4;

  short8 ah[2], al[2];
  #pragma unroll
  for (int kc = 0; kc < 2; ++kc){
    if (kc >= KC) break;
    float xv[8];
    int node = node0 + col;           // A row m = lane&15
    int kbase = kc*32 + quad*8;
    if (node < N && kbase < str){
      const float* xr = x + (size_t)node*str + kbase;
      if (kbase + 8 <= str){
        float4 a = *(const float4*)xr; float4 b = *(const float4*)(xr + 4);
        xv[0]=a.x; xv[1]=a.y; xv[2]=a.z; xv[3]=a.w; xv[4]=b.x; xv[5]=b.y; xv[6]=b.z; xv[7]=b.w;
      } else if (kbase + 4 <= str){
        float4 a = *(const float4*)xr;
        xv[0]=a.x; xv[1]=a.y; xv[2]=a.z; xv[3]=a.w; xv[4]=0.f; xv[5]=0.f; xv[6]=0.f; xv[7]=0.f;
      } else {
        #pragma unroll
        for (int j=0;j<8;++j) xv[j]=0.f;
      }
    } else {
      #pragma unroll
      for (int j=0;j<8;++j) xv[j]=0.f;
    }
    #pragma unroll
    for (int j=0;j<8;++j){
      unsigned short hi = f2bf(xv[j]);
      ah[kc][j] = (short)hi;
      al[kc][j] = (short)f2bf(xv[j] - bf2f(hi));
    }
  }

  const short8* B  = (const short8*)bfr;
  const short8* QK = (const short8*)qkfr;

  // yq / yk tiles (cols = r), B-side hi/lo split too
  f32x4 aq = {0.f,0.f,0.f,0.f}, ak2 = {0.f,0.f,0.f,0.f};
  for (int kc = 0; kc < KC; ++kc){
    short8 qh = QK[((0*KC) + kc)*64 + lane];        // which=0 part=0
    short8 ql = QK[((1*KC) + kc)*64 + lane];        // which=0 part=1
    short8 kh = QK[((2*KC) + kc)*64 + lane];        // which=1 part=0
    short8 kl = QK[((3*KC) + kc)*64 + lane];        // which=1 part=1
    aq = mfma16(ah[kc], qh, aq);
    aq = mfma16(al[kc], qh, aq);
    aq = mfma16(ah[kc], ql, aq);
    ak2 = mfma16(ah[kc], kh, ak2);
    ak2 = mfma16(al[kc], kh, ak2);
    ak2 = mfma16(ah[kc], kl, ak2);
  }
  #pragma unroll
  for (int j = 0; j < 4; ++j){
    int node = node0 + quad*4 + j;
    if (node < N){
      yq[(size_t)node*16 + col] = aq[j];
      yk[(size_t)node*16 + col] = ak2[j];
    }
  }

  // y tiles per relation
  for (int r = 0; r < 15; ++r){
    f32x4 a0 = {0.f,0.f,0.f,0.f}, a1 = {0.f,0.f,0.f,0.f};
    for (int kc = 0; kc < KC; ++kc){
      short8 b0 = B[(((size_t)(r*KC + kc))*2 + 0)*64 + lane];
      short8 b1 = B[(((size_t)(r*KC + kc))*2 + 1)*64 + lane];
      a0 = mfma16(ah[kc], b0, a0);
      a0 = mfma16(al[kc], b0, a0);
      a1 = mfma16(ah[kc], b1, a1);
      a1 = mfma16(al[kc], b1, a1);
    }
    #pragma unroll
    for (int j = 0; j < 4; ++j){
      int node = node0 + quad*4 + j;
      if (node < N){
        unsigned short* yp = &y[(((size_t)r*N + node))*32 + col];
        yp[0]  = f2bf(a0[j]);
        yp[16] = f2bf(a1[j]);
      }
    }
  }
}

// softmax + aggregation. deg<=64 fast path: logits held in SCALARS (no
// dynamically-indexed arrays -> no scratch spill). 4x-unrolled gather.
// Per-block LDS stat reduction -> partials; last block finalizes LN stats.
__global__ void k_main(const int* __restrict__ iptr, const int* __restrict__ pack,
                       const float* __restrict__ yq, const float* __restrict__ yk,
                       const unsigned short* __restrict__ y,
                       const void* __restrict__ biasp, size_t bofs,
                       const float* __restrict__ xres, float* __restrict__ hpre,
                       double* __restrict__ partials, double* __restrict__ PD,
                       int l, int* __restrict__ dcnt, int N){
  __shared__ double sdb[4][2];
  __shared__ int slast;
  int* DF = (int*)(PD + 28);
  int gt = blockIdx.x*blockDim.x + threadIdx.x;
  int node = gt >> 6, lane = gt & 63;
  int wid = threadIdx.x >> 6;
  int f32 = DF[1];
  int o = lane & 31;
  bool active = (node < N);
  float hp = 0.f;

  if (active){
    int start = iptr[node];
    int deg = iptr[node+1] - start;
    const float* yqn = yq + (size_t)node*16;
    float acc = 0.f;
    float ssum = 0.f;

    if (deg <= 64){
      // ---- fast path: one chunk in scalars ----
      int pe = 0; float a = -INFINITY;
      if (lane < deg){
        pe = pack[start+lane];
        int sr = pe & 0xFFFFF, et = pe >> 20;
        a = yqn[et] + yk[(size_t)sr*16+et];
        a = (a >= 0.f) ? a : 0.2f*a;
      }
      float amax = a;
      #pragma unroll
      for (int o2=32;o2>0;o2>>=1) amax = fmaxf(amax, __shfl_xor(amax, o2));
      float ev = (lane < deg) ? expf(a - amax) : 0.f;
      ssum = ev;
      int sub = lane >> 5;
      for (; sub + 6 < deg; sub += 8){
        float w0 = __shfl(ev, sub),   w1 = __shfl(ev, sub+2);
        float w2 = __shfl(ev, sub+4), w3 = __shfl(ev, sub+6);
        int   p0 = __shfl(pe, sub),   p1 = __shfl(pe, sub+2);
        int   p2 = __shfl(pe, sub+4), p3 = __shfl(pe, sub+6);
        float v0 = bf2f(y[((size_t)(p0 >> 20)*N + (p0 & 0xFFFFF))*32 + o]);
        float v1 = bf2f(y[((size_t)(p1 >> 20)*N + (p1 & 0xFFFFF))*32 + o]);
        float v2 = bf2f(y[((size_t)(p2 >> 20)*N + (p2 & 0xFFFFF))*32 + o]);
        float v3 = bf2f(y[((size_t)(p3 >> 20)*N + (p3 & 0xFFFFF))*32 + o]);
        acc = fmaf(w0, v0, acc);
        acc = fmaf(w1, v1, acc);
        acc = fmaf(w2, v2, acc);
        acc = fmaf(w3, v3, acc);
      }
      for (; sub < deg; sub += 2){
        float wgt = __shfl(ev, sub);
        int pb = __shfl(pe, sub);
        acc = fmaf(wgt, bf2f(y[((size_t)(pb >> 20)*N + (pb & 0xFFFFF))*32 + o]), acc);
      }
    } else {
      // ---- slow path: two-pass recompute (rare: deg>64) ----
      float amax = -INFINITY;
      for (int k = lane; k < deg; k += 64){
        int pe = pack[start+k];
        int sr = pe & 0xFFFFF, et = pe >> 20;
        float a = yqn[et] + yk[(size_t)sr*16+et];
        a = (a >= 0.f) ? a : 0.2f*a;
        amax = fmaxf(amax, a);
      }
      #pragma unroll
      for (int o2=32;o2>0;o2>>=1) amax = fmaxf(amax, __shfl_xor(amax, o2));
      for (int c = 0; c < deg; c += 64){
        int k = c + lane;
        float ev = 0.f; int pe = 0;
        if (k < deg){
          pe = pack[start+k];
          int sr = pe & 0xFFFFF, et = pe >> 20;
          float a = yqn[et] + yk[(size_t)sr*16+et];
          a = (a >= 0.f) ? a : 0.2f*a;
          ev = expf(a - amax);
          ssum += ev;
        }
        int lim = min(64, deg - c);
        int sub = lane >> 5;
        for (; sub + 6 < lim; sub += 8){
          float w0 = __shfl(ev, sub),   w1 = __shfl(ev, sub+2);
          float w2 = __shfl(ev, sub+4), w3 = __shfl(ev, sub+6);
          int   p0 = __shfl(pe, sub),   p1 = __shfl(pe, sub+2);
          int   p2 = __shfl(pe, sub+4), p3 = __shfl(pe, sub+6);
          float v0 = bf2f(y[((size_t)(p0 >> 20)*N + (p0 & 0xFFFFF))*32 + o]);
          float v1 = bf2f(y[((size_t)(p1 >> 20)*N + (p1 & 0xFFFFF))*32 + o]);
          float v2 = bf2f(y[((size_t)(p2 >> 20)*N + (p2 & 0xFFFFF))*32 + o]);
          float v3 = bf2f(y[((size_t)(p3 >> 20)*N + (p3 & 0xFFFFF))*32 + o]);
          acc = fmaf(w0, v0, acc);
          acc = fmaf(w1, v1, acc);
          acc = fmaf(w2, v2, acc);
          acc = fmaf(w3, v3, acc);
        }
        for (; sub < lim; sub += 2){
          float wgt = __shfl(ev, sub);
          int pb = __shfl(pe, sub);
          acc = fmaf(wgt, bf2f(y[((size_t)(pb >> 20)*N + (pb & 0xFFFFF))*32 + o]), acc);
        }
      }
    }
    #pragma unroll
    for (int o2=32;o2>0;o2>>=1) ssum += __shfl_xor(ssum, o2);
    float inv = 1.f/(ssum + 1e-16f);
    acc *= inv;
    acc += __shfl_xor(acc, 32);

    if (lane < 32){
      hp = acc + ldin(biasp, bofs + o, f32);
      if (xres) hp += xres[(size_t)node*32 + o];
      if (badf(hp)) atomicOr(DF, 32);
      hpre[(size_t)node*32 + o] = hp;
    }
  }

  // block-level LN stats (no global atomics)
  float s1 = (active && lane < 32) ? hp : 0.f;
  float s2 = s1*s1;
  #pragma unroll
  for (int o2=32;o2>0;o2>>=1){ s1 += __shfl_xor(s1,o2); s2 += __shfl_xor(s2,o2); }
  if (lane == 0){ sdb[wid][0] = (double)s1; sdb[wid][1] = (double)s2; }
  __syncthreads();
  if (threadIdx.x == 0){
    partials[(size_t)blockIdx.x*2]   = sdb[0][0]+sdb[1][0]+sdb[2][0]+sdb[3][0];
    partials[(size_t)blockIdx.x*2+1] = sdb[0][1]+sdb[1][1]+sdb[2][1]+sdb[3][1];
    __threadfence();
    int v = atomicAdd(&dcnt[l], 1);
    slast = (v == (int)gridDim.x - 1) ? 1 : 0;
  }
  __syncthreads();
  if (slast){
    double t1 = 0.0, t2 = 0.0;
    for (int i = threadIdx.x; i < (int)gridDim.x; i += 256){
      t1 += partials[(size_t)i*2];
      t2 += partials[(size_t)i*2+1];
    }
    t1 = wsum_d(t1); t2 = wsum_d(t2);
    __shared__ double sd[8];
    int w = threadIdx.x >> 6;
    if ((threadIdx.x & 63) == 0){ sd[w*2] = t1; sd[w*2+1] = t2; }
    __syncthreads();
    if (threadIdx.x == 0){
      PD[32+2*l]   = sd[0]+sd[2]+sd[4]+sd[6];
      PD[32+2*l+1] = sd[1]+sd[3]+sd[5]+sd[7];
    }
  }
}

__global__ void k_ln(float* __restrict__ h, const void* __restrict__ lnw,
                     const void* __restrict__ lnb, size_t lofs,
                     double* __restrict__ PD, int l, int N){
  int idx = blockIdx.x*blockDim.x + threadIdx.x;
  if (idx >= N*32) return;
  int* DF = (int*)(PD + 28);
  int f32 = DF[1];
  const double* stats = PD + 32 + 2*l;
  int o = idx & 31;
  double cntf = (double)N*32.0;
  double mu = stats[0]/cntf;
  double var = stats[1]/cntf - mu*mu;
  float rstd = (float)(1.0/(sqrt(var>0.0?var:0.0) + 1e-5));
  float v = (h[idx] - (float)mu)*rstd*ldin(lnw, lofs + o, f32) + ldin(lnb, lofs + o, f32);
  v = v / (1.f + expf(-v));
  if (badf(v)) atomicOr(DF, 64);
  h[idx] = v;
}

__global__ void k_pool(const float* __restrict__ h, double* __restrict__ PD, int N){
  __shared__ float sp[8][33];
  int t = threadIdx.x, o = t & 31, g = t >> 5;
  int r0 = blockIdx.x*256;
  float s = 0.f;
  for (int r = r0 + g; r < N && r < r0 + 256; r += 8) s += h[(size_t)r*32 + o];
  sp[g][o] = s;
  __syncthreads();
  if (t < 32){
    float tot = 0.f;
    #pragma unroll
    for (int g2=0; g2<8; ++g2) tot += sp[g2][t];
    atomicAdd(&PD[40 + t], (double)tot);
  }
}

__global__ void k_out(double* __restrict__ PD, const void* __restrict__ Wl,
                      const void* __restrict__ bl, void* __restrict__ out, int N, int H2){
  int j = blockIdx.x*blockDim.x + threadIdx.x;
  if (j >= H2) return;
  int* DF = (int*)(PD + 28);
  int f32 = DF[1];
  int flag = DF[0];
  const double* pool = PD + 40;
  float acc = ldin(bl, j, f32);
  for (int o=0;o<32;++o)
    acc = fmaf((float)(pool[o]/(double)N), ldin(Wl, (size_t)j*32+o, f32), acc);
  if (badf(acc)) flag |= 128;
  float v = acc / (1.f + expf(-acc));
  if (flag) v = (float)flag;   // diagnostic: absmax == stage bitmask
  if (f32) ((float*)out)[j] = v;
  else     ((unsigned short*)out)[j] = f2bf(v);
}

__global__ void k_diag(unsigned short* out, float val, int H2){
  int j = blockIdx.x*blockDim.x + threadIdx.x;
  if (j < H2) out[j] = f2bf(val);
}

// ---------------- entry ----------------
extern "C" void kernel_launch(void* const* d_in, const int* in_sizes, int n_in,
                              void* d_out, int out_size, void* d_ws, size_t ws_size,
                              hipStream_t stream)
{
  const int N  = in_sizes[0] / 35;
  const int E  = in_sizes[3];
  const int R  = 15;
  const int H2 = in_sizes[19];

  const void* data = d_in[0];
  const int* ei  = (const int*)d_in[2];
  const int* etp = (const int*)d_in[3];
  const void* W0  = d_in[6];
  const void* q0  = d_in[7];
  const void* k0  = d_in[8];
  const void* b0  = d_in[9];
  const void* Wsp = d_in[10];
  const void* qsp = d_in[11];
  const void* ksp = d_in[12];
  const void* bsp = d_in[13];
  const void* lnw = d_in[14];
  const void* lnb = d_in[15];
  const void* ln1w= d_in[16];
  const void* ln1b= d_in[17];
  const void* l1W = d_in[18];
  const void* l1b = d_in[19];

  char* base = (char*)d_ws;
  size_t off = 0;
  auto A = [&](size_t nb)->size_t { size_t c = off; off += (nb + 255) & ~(size_t)255; return c; };
  size_t oPD  = A(1024);
  size_t oCnt = A((size_t)N*4);
  size_t oPtr = A(((size_t)N+1)*4);
  size_t oCur = A((size_t)N*4);
  size_t oBs  = A(4096);
  size_t oBp  = A(4096);
  size_t oPk  = A((size_t)E*4);
  size_t oX   = A((size_t)N*36*4);
  size_t oH0  = A((size_t)N*32*4);
  size_t oH1  = A((size_t)N*32*4);
  size_t oYq  = A((size_t)N*16*4);
  size_t oYk  = A((size_t)N*16*4);
  size_t oBf  = A((size_t)15*2*2*64*8*2);
  size_t oQk  = A((size_t)2*2*2*64*8*2);
  int nbMain  = (int)(((size_t)N*64 + 255)/256);
  size_t oPt  = A((size_t)nbMain*2*8);
  size_t oY   = off;
  size_t needB = oY + (size_t)R*N*32*2;

  double* PD  = (double*)(base + oPD);
  int* DF     = (int*)(PD + 28);
  int* dcnt   = (int*)(PD + 29);   // 4 ints, zeroed by memset
  int* cnt    = (int*)(base + oCnt);
  int* iptr   = (int*)(base + oPtr);
  int* cur    = (int*)(base + oCur);
  int* bsum   = (int*)(base + oBs);
  int* bpre   = (int*)(base + oBp);
  int* pack   = (int*)(base + oPk);
  float* xb   = (float*)(base + oX);
  float* h0   = (float*)(base + oH0);
  float* h1   = (float*)(base + oH1);
  float* yqb  = (float*)(base + oYq);
  float* ykb  = (float*)(base + oYk);
  unsigned short* bfr  = (unsigned short*)(base + oBf);
  unsigned short* qkfr = (unsigned short*)(base + oQk);
  double* partials = (double*)(base + oPt);
  unsigned short* y = (unsigned short*)(base + oY);

  if (ws_size < needB){
    k_diag<<<1, 256, 0, stream>>>((unsigned short*)d_out, (float)(ws_size >> 20), H2);
    return;
  }

  // zero PD + cnt ( [0, oPtr) covers both exactly )
  hipMemsetAsync(base, 0, oPtr, stream);

  int nbN = (N + 255)/256;
  int nbE = (E + 255)/256;
  int nus = (in_sizes[0] < 1024) ? in_sizes[0] : 1024;

  k_dtype<<<1, 256, 0, stream>>>((const unsigned short*)data, nus, PD);
  k_red1<<<nbN, 256, 0, stream>>>(data, N, PD);
  k_eig<<<1, 1, 0, stream>>>(PD, N);
  k_buildx<<<nbN, 256, 0, stream>>>(data, ln1w, ln1b, PD, xb, N);

  k_count<<<nbE, 256, 0, stream>>>(ei + E, cnt, E);
  k_scan1<<<nbN, 256, 0, stream>>>(cnt, bsum, N);
  k_scan2<<<1, 1, 0, stream>>>(bsum, bpre, iptr, nbN, N);
  k_scan3<<<nbN, 256, 0, stream>>>(cnt, bpre, iptr, cur, N);
  k_scatter<<<nbE, 256, 0, stream>>>(ei, ei + E, etp, cur, pack, E);

  int nbMf = (int)(((N + 15)/16 + 3)/4);
  for (int l=0; l<4; ++l){
    const void* W  = (l==0)? W0 : Wsp;  size_t wofs = (l==0)? 0 : (size_t)(l-1)*R*32*32;
    const void* qp = (l==0)? q0 : qsp;  size_t qofs = (l==0)? 0 : (size_t)(l-1)*32;
    const void* kp = (l==0)? k0 : ksp;
    const void* bp = (l==0)? b0 : bsp;  size_t bofs = qofs;
    int str = (l==0)? 36 : 32;
    int KC = (l==0)? 2 : 1;
    int F = (l==0)? 35 : 32;
    const float* xin = (l==0)? xb : ((l%2==0)? h1 : h0);
    float* hout = (l%2==0)? h0 : h1;
    int nFrag = 15*KC*2*64*8 + 2*2*KC*64*8;
    k_fragpack<<<(nFrag+255)/256, 256, 0, stream>>>(W, wofs, F, KC, qp, kp, qofs, bfr, qkfr, DF);
    k_mf<<<nbMf, 256, 0, stream>>>(xin, str, KC, N, bfr, qkfr, y, yqb, ykb);
    k_main<<<nbMain, 256, 0, stream>>>(iptr, pack, yqb, ykb, y, bp, bofs,
                 (l==0)? (const float*)nullptr : xin, hout, partials, PD, l, dcnt, N);
    k_ln<<<(N*32+255)/256, 256, 0, stream>>>(hout, lnw, lnb, (size_t)l*32, PD, l, N);
  }

  k_pool<<<nbN, 256, 0, stream>>>(h1, PD, N);
  k_out<<<(H2+255)/256, 256, 0, stream>>>(PD, l1W, l1b, d_out, N, H2);
}

// Round 8
// 1561.346 us; speedup vs baseline: 2.9474x; 2.9222x over previous
//
#include <hip/hip_runtime.h>
#include <math.h>
#include <stdint.h>

// ---------------- helpers ----------------
__device__ inline float bf2f(unsigned short u){
  union { unsigned int i; float f; } x; x.i = ((unsigned int)u) << 16; return x.f;
}
__device__ inline unsigned short f2bf(float f){
  union { float f; unsigned int i; } x; x.f = f;
  unsigned int u = x.i;
  return (unsigned short)((u + 0x7FFFu + ((u >> 16) & 1u)) >> 16);
}
// dtype-dispatched input load: f32 flag comes from device-side probe
__device__ inline float ldin(const void* p, size_t i, int f32){
  return f32 ? ((const float*)p)[i] : bf2f(((const unsigned short*)p)[i]);
}

__device__ inline int badf(float v){ return !(fabsf(v) <= 3.0e38f); }
__device__ inline int badd(double v){ return !(fabs(v) <= 1.0e300); }

__device__ inline double wsum_d(double v){
  #pragma unroll
  for (int o = 32; o > 0; o >>= 1) v += __shfl_down(v, o);
  return v;
}
__device__ inline double wmax_d(double v){
  #pragma unroll
  for (int o = 32; o > 0; o >>= 1) v = fmax(v, __shfl_down(v, o));
  return v;
}
__device__ inline void atomicMaxD(double* addr, double v){ // v >= 0
  atomicMax((unsigned long long*)addr, (unsigned long long)__double_as_longlong(v));
}

// MFMA types
typedef __attribute__((ext_vector_type(8))) short short8;
typedef __attribute__((ext_vector_type(4))) float f32x4;
__device__ inline f32x4 mfma16(short8 a, short8 b, f32x4 c){
  return __builtin_amdgcn_mfma_f32_16x16x32_bf16(a, b, c, 0, 0, 0);
}

// ---------------- LAPACK 3x3 eigh port (dsytd2 + dsteqr + dormtr) ----------------
__device__ inline double d_sign(double a, double b){ return (b >= 0.0) ? fabs(a) : -fabs(a); }
__device__ inline double dlapy2_(double x, double y){ return sqrt(x*x + y*y); }

__device__ void dlartg_(double f, double g, double* cs, double* sn, double* r){
  // LAPACK >= 3.10 convention: c >= 0, r = sign(d, f)
  if (g == 0.0){ *cs = 1.0; *sn = 0.0; *r = f; }
  else if (f == 0.0){ *cs = 0.0; *sn = (g >= 0.0) ? 1.0 : -1.0; *r = fabs(g); }
  else {
    double d = sqrt(f*f + g*g);
    *cs = fabs(f)/d;
    *r  = d_sign(d, f);
    *sn = g / (*r);
  }
}

__device__ void dlaev2_(double a, double b, double c, double* rt1, double* rt2,
                        double* cs1, double* sn1){
  double sm = a + c, df = a - c, adf = fabs(df), tb = b + b, ab = fabs(tb);
  double acmx, acmn;
  if (fabs(a) > fabs(c)){ acmx = a; acmn = c; } else { acmx = c; acmn = a; }
  double rt;
  if (adf > ab) rt = adf*sqrt(1.0 + (ab/adf)*(ab/adf));
  else if (adf < ab) rt = ab*sqrt(1.0 + (adf/ab)*(adf/ab));
  else rt = ab*sqrt(2.0);
  int sgn1;
  if (sm < 0.0){ *rt1 = 0.5*(sm - rt); sgn1 = -1; *rt2 = (acmx/(*rt1))*acmn - (b/(*rt1))*b; }
  else if (sm > 0.0){ *rt1 = 0.5*(sm + rt); sgn1 = 1; *rt2 = (acmx/(*rt1))*acmn - (b/(*rt1))*b; }
  else { *rt1 = 0.5*rt; *rt2 = -0.5*rt; sgn1 = 1; }
  int sgn2; double cs;
  if (df >= 0.0){ cs = df + rt; sgn2 = 1; } else { cs = df - rt; sgn2 = -1; }
  double acs = fabs(cs);
  if (acs > ab){ double ct = -tb/cs; *sn1 = 1.0/sqrt(1.0+ct*ct); *cs1 = ct*(*sn1); }
  else {
    if (ab == 0.0){ *cs1 = 1.0; *sn1 = 0.0; }
    else { double tn = -cs/tb; *cs1 = 1.0/sqrt(1.0+tn*tn); *sn1 = tn*(*cs1); }
  }
  if (sgn1 == sgn2){ double tn = *cs1; *cs1 = -(*sn1); *sn1 = tn; }
}

__device__ void dsteqr3_(double* dd, double* ee, double z[3][3]){
  #define D_(i) dd[(i)-1]
  #define E_(i) ee[(i)-1]
  #define Z_(i,j) z[(i)-1][(j)-1]
  #define CW_(i) cw[(i)-1]
  #define SW_(i) sw[(i)-1]
  const int n = 3;
  const double eps = 1.1102230246251565e-16;
  const double eps2 = eps*eps;
  const double safmin = 2.2250738585072014e-308;
  const int nmaxit = n*30;
  double cw[3], sw[3];
  int jtot = 0;
  int l1 = 1, l, m, lsv, lend, lendsv;
  double p, g, r, c, s, f, b, rt1, rt2, anorm, tst;

L10:
  if (l1 > n) goto L160;
  if (l1 > 1) E_(l1-1) = 0.0;
  if (l1 <= n-1){
    for (m = l1; m <= n-1; ++m){
      tst = fabs(E_(m));
      if (tst == 0.0) goto L30;
      if (tst <= (sqrt(fabs(D_(m)))*sqrt(fabs(D_(m+1))))*eps){ E_(m) = 0.0; goto L30; }
    }
  }
  m = n;
L30:
  l = l1; lsv = l; lend = m; lendsv = lend; l1 = m+1;
  if (lend == l) goto L10;
  anorm = 0.0;
  for (int i = l; i <= lend; ++i) anorm = fmax(anorm, fabs(D_(i)));
  for (int i = l; i <= lend-1; ++i) anorm = fmax(anorm, fabs(E_(i)));
  if (anorm == 0.0) goto L10;
  if (fabs(D_(lend)) < fabs(D_(l))){ lend = lsv; l = lendsv; }
  if (lend > l) goto L40; else goto L90;

  // -------- QL iteration --------
L40:
  if (l != lend){
    for (m = l; m <= lend-1; ++m){
      tst = fabs(E_(m)); tst = tst*tst;
      if (tst <= (eps2*fabs(D_(m)))*fabs(D_(m+1)) + safmin) goto L60;
    }
  }
  m = lend;
L60:
  if (m < lend) E_(m) = 0.0;
  p = D_(l);
  if (m == l) goto L80;
  if (m == l+1){
    dlaev2_(D_(l), E_(l), D_(l+1), &rt1, &rt2, &c, &s);
    CW_(l) = c; SW_(l) = s;
    { double ct = CW_(l), st = SW_(l);
      if (ct != 1.0 || st != 0.0)
        for (int i = 1; i <= n; ++i){
          double t = Z_(i, l+1);
          Z_(i, l+1) = ct*t - st*Z_(i, l);
          Z_(i, l)   = st*t + ct*Z_(i, l);
        }
    }
    D_(l) = rt1; D_(l+1) = rt2; E_(l) = 0.0;
    l += 2;
    if (l <= lend) goto L40;
    goto L140;
  }
  if (jtot == nmaxit) goto L140;
  jtot++;
  g = (D_(l+1) - p)/(2.0*E_(l));
  r = dlapy2_(g, 1.0);
  g = D_(m) - p + E_(l)/(g + d_sign(r, g));
  s = 1.0; c = 1.0; p = 0.0;
  for (int i = m-1; i >= l; --i){
    f = s*E_(i); b = c*E_(i);
    dlartg_(g, f, &c, &s, &r);
    if (i != m-1) E_(i+1) = r;
    g = D_(i+1) - p;
    r = (D_(i) - g)*s + 2.0*c*b;
    p = s*r;
    D_(i+1) = g + p;
    g = c*r - b;
    CW_(i) = c; SW_(i) = -s;
  }
  { int mm = m - l + 1;
    for (int j = mm-1; j >= 1; --j){
      double ct = CW_(l+j-1), st = SW_(l+j-1);
      if (ct != 1.0 || st != 0.0)
        for (int i = 1; i <= n; ++i){
          double t = Z_(i, l+j);
          Z_(i, l+j)   = ct*t - st*Z_(i, l+j-1);
          Z_(i, l+j-1) = st*t + ct*Z_(i, l+j-1);
        }
    }
  }
  D_(l) = D_(l) - p;
  E_(l) = g;
  goto L40;
L80:
  D_(l) = p;
  l++;
  if (l <= lend) goto L40;
  goto L140;

  // -------- QR iteration --------
L90:
  if (l != lend){
    for (m = l; m >= lend+1; --m){
      tst = fabs(E_(m-1)); tst = tst*tst;
      if (tst <= (eps2*fabs(D_(m)))*fabs(D_(m-1)) + safmin) goto L110;
    }
  }
  m = lend;
L110:
  if (m > lend) E_(m-1) = 0.0;
  p = D_(l);
  if (m == l) goto L130;
  if (m == l-1){
    dlaev2_(D_(l-1), E_(l-1), D_(l), &rt1, &rt2, &c, &s);
    CW_(m) = c; SW_(m) = s;
    { double ct = CW_(m), st = SW_(m);
      if (ct != 1.0 || st != 0.0)
        for (int i = 1; i <= n; ++i){
          double t = Z_(i, l);
          Z_(i, l)   = ct*t - st*Z_(i, l-1);
          Z_(i, l-1) = st*t + ct*Z_(i, l-1);
        }
    }
    D_(l-1) = rt1; D_(l) = rt2; E_(l-1) = 0.0;
    l -= 2;
    if (l >= lend) goto L90;
    goto L140;
  }
  if (jtot == nmaxit) goto L140;
  jtot++;
  g = (D_(l-1) - p)/(2.0*E_(l-1));
  r = dlapy2_(g, 1.0);
  g = D_(m) - p + E_(l-1)/(g + d_sign(r, g));
  s = 1.0; c = 1.0; p = 0.0;
  for (int i = m; i <= l-1; ++i){
    f = s*E_(i); b = c*E_(i);
    dlartg_(g, f, &c, &s, &r);
    if (i != m) E_(i-1) = r;
    g = D_(i) - p;
    r = (D_(i+1) - g)*s + 2.0*c*b;
    p = s*r;
    D_(i) = g + p;
    g = c*r - b;
    CW_(i) = c; SW_(i) = s;
  }
  { int mm = l - m + 1;
    for (int j = 1; j <= mm-1; ++j){
      double ct = CW_(m+j-1), st = SW_(m+j-1);
      if (ct != 1.0 || st != 0.0)
        for (int i = 1; i <= n; ++i){
          double t = Z_(i, m+j);
          Z_(i, m+j)   = ct*t - st*Z_(i, m+j-1);
          Z_(i, m+j-1) = st*t + ct*Z_(i, m+j-1);
        }
    }
  }
  D_(l) = D_(l) - p;
  E_(l-1) = g;
  goto L90;
L130:
  D_(l) = p;
  l--;
  if (l >= lend) goto L90;
  goto L140;

L140:
  if (jtot < nmaxit) goto L10;
  goto L190;

L160:
  for (int ii = 2; ii <= n; ++ii){
    int i = ii-1, k = i;
    p = D_(i);
    for (int j = ii; j <= n; ++j) if (D_(j) < p){ k = j; p = D_(j); }
    if (k != i){
      D_(k) = D_(i); D_(i) = p;
      for (int rr = 1; rr <= n; ++rr){ double t = Z_(rr,i); Z_(rr,i) = Z_(rr,k); Z_(rr,k) = t; }
    }
  }
L190:
  ;
  #undef D_
  #undef E_
  #undef Z_
  #undef CW_
  #undef SW_
}

__device__ void eigh3_(const double C[3][3], double w[3], double v[3][3]){
  double a00=C[0][0], a10=C[1][0], a20=C[2][0], a11=C[1][1], a21=C[2][1], a22=C[2][2];
  double dd[3], ee[2], tau, v2;
  double alpha = a10, x = a20;
  double xnorm = fabs(x);
  if (xnorm == 0.0){ tau = 0.0; v2 = 0.0; ee[0] = alpha; }
  else {
    double beta = -d_sign(dlapy2_(alpha, xnorm), alpha);
    tau = (beta - alpha)/beta;
    v2 = x/(alpha - beta);
    ee[0] = beta;
  }
  if (tau != 0.0){
    double w0 = tau*(a11 + a21*v2);
    double w1 = tau*(a21 + a22*v2);
    double wv = w0 + w1*v2;
    double ac = -0.5*tau*wv;
    w0 += ac; w1 += ac*v2;
    a11 = a11 - 2.0*w0;
    a21 = a21 - (v2*w0 + w1);
    a22 = a22 - 2.0*v2*w1;
  }
  dd[0]=a00; dd[1]=a11; dd[2]=a22; ee[1]=a21;
  double z[3][3] = {{1,0,0},{0,1,0},{0,0,1}};
  dsteqr3_(dd, ee, z);
  for (int j = 0; j < 3; ++j){
    double t = z[1][j] + v2*z[2][j];
    z[1][j] -= tau*t;
    z[2][j] -= tau*t*v2;
  }
  for (int i=0;i<3;++i){ w[i]=dd[i]; for(int j=0;j<3;++j) v[i][j]=z[i][j]; }
}

// ---------------- kernels ----------------
// PD layout (doubles): 0-2 possum, 3 fsum, 4 fsumsq, 5-10 raw pos moments
// (m00,m10,m20,m11,m21,m22), 12-14 mean, 15 scale, 16-24 V, 25 mu1, 26 rstd1,
// 28: int flag + int isf32, 32+2l per-layer LN stats, 40-71 pool,
// 72-74 max(64+p), 75-77 max(64-p)

__global__ void k_dtype(const unsigned short* __restrict__ data, int nus, double* PD){
  int* DF = (int*)(PD + 28);
  int t = threadIdx.x;
  int bad = 0;
  for (int i = t; i < nus; i += 256){
    int e = (data[i] >> 7) & 0xFF;
    if (e > 0x90 || (e && e < 0x60)) bad++;
  }
  #pragma unroll
  for (int o = 32; o > 0; o >>= 1) bad += __shfl_down(bad, o);
  __shared__ int sb[4];
  if ((t & 63) == 0) sb[t >> 6] = bad;
  __syncthreads();
  if (t == 0) DF[1] = ((sb[0]+sb[1]+sb[2]+sb[3]) > nus/16) ? 1 : 0;
}

// single pass: pos sums, raw second moments, min/max (as max(64±p)), feat sums
__global__ void k_red1(const void* __restrict__ data, int N, double* PD){
  int n = blockIdx.x*blockDim.x + threadIdx.x;
  const int* DF = (const int*)(PD + 28);
  int f32 = DF[1];
  double vals[11] = {0,0,0,0,0,0,0,0,0,0,0};
  double mp[3] = {0,0,0}, mn[3] = {0,0,0};
  if (n < N){
    size_t rb = (size_t)n*35;
    double p0 = ldin(data, rb+0, f32);
    double p1 = ldin(data, rb+1, f32);
    double p2 = ldin(data, rb+2, f32);
    vals[0]=p0; vals[1]=p1; vals[2]=p2;
    double fs=0, fss=0;
    for (int k=3;k<35;++k){ double v = ldin(data, rb+k, f32); fs += v; fss += v*v; }
    vals[3]=fs; vals[4]=fss;
    vals[5]=p0*p0; vals[6]=p1*p0; vals[7]=p2*p0; vals[8]=p1*p1; vals[9]=p2*p1; vals[10]=p2*p2;
    mp[0]=64.0+p0; mp[1]=64.0+p1; mp[2]=64.0+p2;
    mn[0]=64.0-p0; mn[1]=64.0-p1; mn[2]=64.0-p2;
  }
  __shared__ double sred[4];
  for (int q=0;q<11;++q){
    double t = wsum_d(vals[q]);
    if ((threadIdx.x&63)==0) sred[threadIdx.x>>6]=t;
    __syncthreads();
    if (threadIdx.x==0) atomicAdd(&PD[q], sred[0]+sred[1]+sred[2]+sred[3]);
    __syncthreads();
  }
  for (int j=0;j<6;++j){
    double t = wmax_d(j<3 ? mp[j] : mn[j-3]);
    if ((threadIdx.x&63)==0) sred[threadIdx.x>>6]=t;
    __syncthreads();
    if (threadIdx.x==0)
      atomicMaxD(&PD[72+j], fmax(fmax(sred[0],sred[1]), fmax(sred[2],sred[3])));
    __syncthreads();
  }
}

__global__ void k_eig(double* PD, int N){
  if (threadIdx.x != 0 || blockIdx.x != 0) return;
  int* DF = (int*)(PD + 28);
  int bad0 = 0;
  for (int i=0;i<11;++i) if (badd(PD[i])) bad0 = 1;
  if (bad0) DF[0] |= 1;
  double dN = (double)N;
  double mu[3] = {PD[0]/dN, PD[1]/dN, PD[2]/dN};
  double amax = 0.0;
  for (int j=0;j<3;++j){
    double mx = (PD[72+j] - 64.0) - mu[j];
    double mnv = mu[j] - (64.0 - PD[75+j]);
    amax = fmax(amax, fmax(mx, mnv));
  }
  double s = 0.999999/amax;
  double s2 = s*s;
  double C[3][3];
  C[0][0]=(PD[5]-dN*mu[0]*mu[0])*s2; C[1][0]=(PD[6]-dN*mu[1]*mu[0])*s2;
  C[2][0]=(PD[7]-dN*mu[2]*mu[0])*s2; C[1][1]=(PD[8]-dN*mu[1]*mu[1])*s2;
  C[2][1]=(PD[9]-dN*mu[2]*mu[1])*s2; C[2][2]=(PD[10]-dN*mu[2]*mu[2])*s2;
  C[0][1]=C[1][0]; C[0][2]=C[2][0]; C[1][2]=C[2][1];
  double w[3], V[3][3];
  eigh3_(C, w, V);
  int bad1 = 0;
  for (int i=0;i<3;++i){ if (badd(w[i])) bad1=1; for (int j=0;j<3;++j) if (badd(V[i][j])) bad1=1; }
  if (bad1){
    DF[0] |= 2;
    for (int i=0;i<3;++i) for (int j=0;j<3;++j) V[i][j] = (i==j) ? 1.0 : 0.0;
  }
  PD[12]=mu[0]; PD[13]=mu[1]; PD[14]=mu[2];
  PD[15]=s;
  for (int i=0;i<3;++i) for (int j=0;j<3;++j) PD[16+i*3+j]=V[i][j];
  double cntf = dN*32.0;
  double mu1 = PD[3]/cntf;
  double var = PD[4]/cntf - mu1*mu1;
  PD[25]=mu1;
  PD[26]=1.0/(sqrt(var>0.0?var:0.0)+1e-5);
}

__global__ void k_buildx(const void* __restrict__ data,
                         const void* __restrict__ ln1w,
                         const void* __restrict__ ln1b,
                         double* __restrict__ PD, float* __restrict__ x, int N){
  int n = blockIdx.x*blockDim.x + threadIdx.x;
  if (n >= N) return;
  int* DF = (int*)(PD + 28);
  int f32 = DF[1];
  size_t rb = (size_t)n*35;
  double s = PD[15];
  double p0 = ((double)ldin(data, rb+0, f32) - PD[12])*s;
  double p1 = ((double)ldin(data, rb+1, f32) - PD[13])*s;
  double p2 = ((double)ldin(data, rb+2, f32) - PD[14])*s;
  float* xr = x + (size_t)n*36;
  int bb = 0;
  for (int j=0;j<3;++j){
    float v = (float)(p0*PD[16+j] + p1*PD[19+j] + p2*PD[22+j]);
    bb |= badf(v);
    xr[j] = v;
  }
  float mu1 = (float)PD[25], rs = (float)PD[26];
  for (int k=0;k<32;++k){
    float v = (ldin(data, rb+3+k, f32) - mu1)*rs*ldin(ln1w, k, f32) + ldin(ln1b, k, f32);
    bb |= badf(v);
    xr[3+k] = v;
  }
  xr[35] = 0.f;
  if (bb) atomicOr(DF, 4);
}

__global__ void k_count(const int* __restrict__ dst, int* __restrict__ cnt, int E){
  int i = blockIdx.x*blockDim.x + threadIdx.x;
  if (i < E) atomicAdd(&cnt[dst[i]], 1);
}

__global__ void k_scan1(const int* __restrict__ cnt, int* __restrict__ bsum, int N){
  int i = blockIdx.x*256 + threadIdx.x;
  int v = (i < N) ? cnt[i] : 0;
  #pragma unroll
  for (int o=32;o>0;o>>=1) v += __shfl_down(v, o);
  __shared__ int s4[4];
  if ((threadIdx.x&63)==0) s4[threadIdx.x>>6]=v;
  __syncthreads();
  if (threadIdx.x==0) bsum[blockIdx.x]=s4[0]+s4[1]+s4[2]+s4[3];
}

__global__ void k_scan2(const int* __restrict__ bsum, int* __restrict__ bpre,
                        int* __restrict__ iptr, int nb, int N){
  if (threadIdx.x != 0 || blockIdx.x != 0) return;
  int run = 0;
  for (int b=0;b<nb;++b){ bpre[b]=run; run += bsum[b]; }
  iptr[N] = run;
}

__global__ void k_scan3(const int* __restrict__ cnt, const int* __restrict__ bpre,
                        int* __restrict__ iptr, int* __restrict__ cur, int N){
  __shared__ int sc[256];
  int i = blockIdx.x*256 + threadIdx.x;
  int t = threadIdx.x;
  int v = (i < N) ? cnt[i] : 0;
  sc[t] = v;
  __syncthreads();
  for (int o=1;o<256;o<<=1){
    int add = (t >= o) ? sc[t-o] : 0;
    __syncthreads();
    sc[t] += add;
    __syncthreads();
  }
  if (i < N){
    int val = bpre[blockIdx.x] + sc[t] - v;
    iptr[i] = val;
    cur[i] = val;
  }
}

__global__ void k_scatter(const int* __restrict__ src, const int* __restrict__ dst,
                          const int* __restrict__ et, int* __restrict__ cur,
                          int* __restrict__ pack, int E){
  int i = blockIdx.x*blockDim.x + threadIdx.x;
  if (i < E){
    int d = dst[i];
    int p = atomicAdd(&cur[d], 1);
    pack[p] = src[i] | (et[i] << 20);
  }
}

// Pack B fragments (bf16, MFMA lane layout) for W (per r, kc, tile) and for
// the yq/yk side (u_r = W_r@q, v_r = W_r@k computed inline, hi/lo split).
__global__ void k_fragpack(const void* __restrict__ W, size_t wofs, int F, int KC,
                           const void* __restrict__ qp, const void* __restrict__ kp,
                           size_t qofs,
                           unsigned short* __restrict__ bfr,
                           unsigned short* __restrict__ qkfr,
                           const int* __restrict__ DF){
  int t = blockIdx.x*blockDim.x + threadIdx.x;
  int nB = 15*KC*2*64*8;
  int nQ = 2*2*KC*64*8;
  int f32 = DF[1];
  if (t < nB){
    int j = t & 7; int lane = (t >> 3) & 63; int tile = (t >> 9) & 1; int idx = t >> 10;
    int kc = idx % KC; int r = idx / KC;
    int f = kc*32 + (lane >> 4)*8 + j;
    int o = tile*16 + (lane & 15);
    bfr[t] = (f < F) ? f2bf(ldin(W, wofs + ((size_t)(r*F+f))*32 + o, f32)) : 0;
  } else if (t < nB + nQ){
    int u = t - nB;
    int j = u & 7; int lane = (u >> 3) & 63; int wpk = u >> 9;
    int kc = wpk % KC; int wp = wpk / KC;
    int part = wp & 1; int which = wp >> 1;
    int f = kc*32 + (lane >> 4)*8 + j;
    int rr = lane & 15;
    unsigned short val = 0;
    if (f < F && rr < 15){
      const void* v = which ? kp : qp;
      float acc = 0.f;
      for (int o = 0; o < 32; ++o)
        acc = fmaf(ldin(W, wofs + ((size_t)(rr*F+f))*32 + o, f32), ldin(v, qofs + o, f32), acc);
      unsigned short hi = f2bf(acc);
      val = (part == 0) ? hi : f2bf(acc - bf2f(hi));
    }
    qkfr[u] = val;
  }
}

// MFMA GEMM: per wave, 16 nodes x (15 r x 32 outs + yq/yk). X split hi/lo bf16.
__global__ void __launch_bounds__(256)
k_mf(const float* __restrict__ x, int str, int KC, int N,
     const unsigned short* __restrict__ bfr,
     const unsigned short* __restrict__ qkfr,
     unsigned short* __restrict__ y, float* __restrict__ yq, float* __restrict__ yk){
  int wave = blockIdx.x*(blockDim.x >> 6) + (threadIdx.x >> 6);
  int node0 = wave*16;
  if (node0 >= N) return;
  int lane = threadIdx.x & 63;
  int col = lane & 15, quad = lane >> 4;

  short8 ah[2], al[2];
  #pragma unroll
  for (int kc = 0; kc < 2; ++kc){
    if (kc >= KC) break;
    float xv[8];
    int node = node0 + col;           // A row m = lane&15
    int kbase = kc*32 + quad*8;
    if (node < N && kbase < str){
      const float* xr = x + (size_t)node*str + kbase;
      if (kbase + 8 <= str){
        float4 a = *(const float4*)xr; float4 b = *(const float4*)(xr + 4);
        xv[0]=a.x; xv[1]=a.y; xv[2]=a.z; xv[3]=a.w; xv[4]=b.x; xv[5]=b.y; xv[6]=b.z; xv[7]=b.w;
      } else if (kbase + 4 <= str){
        float4 a = *(const float4*)xr;
        xv[0]=a.x; xv[1]=a.y; xv[2]=a.z; xv[3]=a.w; xv[4]=0.f; xv[5]=0.f; xv[6]=0.f; xv[7]=0.f;
      } else {
        #pragma unroll
        for (int j=0;j<8;++j) xv[j]=0.f;
      }
    } else {
      #pragma unroll
      for (int j=0;j<8;++j) xv[j]=0.f;
    }
    #pragma unroll
    for (int j=0;j<8;++j){
      unsigned short hi = f2bf(xv[j]);
      ah[kc][j] = (short)hi;
      al[kc][j] = (short)f2bf(xv[j] - bf2f(hi));
    }
  }

  const short8* B  = (const short8*)bfr;
  const short8* QK = (const short8*)qkfr;

  // yq / yk tiles (cols = r), B-side hi/lo split too
  f32x4 aq = {0.f,0.f,0.f,0.f}, ak2 = {0.f,0.f,0.f,0.f};
  for (int kc = 0; kc < KC; ++kc){
    short8 qh = QK[((0*KC) + kc)*64 + lane];        // which=0 part=0
    short8 ql = QK[((1*KC) + kc)*64 + lane];        // which=0 part=1
    short8 kh = QK[((2*KC) + kc)*64 + lane];        // which=1 part=0
    short8 kl = QK[((3*KC) + kc)*64 + lane];        // which=1 part=1
    aq = mfma16(ah[kc], qh, aq);
    aq = mfma16(al[kc], qh, aq);
    aq = mfma16(ah[kc], ql, aq);
    ak2 = mfma16(ah[kc], kh, ak2);
    ak2 = mfma16(al[kc], kh, ak2);
    ak2 = mfma16(ah[kc], kl, ak2);
  }
  #pragma unroll
  for (int j = 0; j < 4; ++j){
    int node = node0 + quad*4 + j;
    if (node < N){
      yq[(size_t)node*16 + col] = aq[j];
      yk[(size_t)node*16 + col] = ak2[j];
    }
  }

  // y tiles per relation
  for (int r = 0; r < 15; ++r){
    f32x4 a0 = {0.f,0.f,0.f,0.f}, a1 = {0.f,0.f,0.f,0.f};
    for (int kc = 0; kc < KC; ++kc){
      short8 b0 = B[(((size_t)(r*KC + kc))*2 + 0)*64 + lane];
      short8 b1 = B[(((size_t)(r*KC + kc))*2 + 1)*64 + lane];
      a0 = mfma16(ah[kc], b0, a0);
      a0 = mfma16(al[kc], b0, a0);
      a1 = mfma16(ah[kc], b1, a1);
      a1 = mfma16(al[kc], b1, a1);
    }
    #pragma unroll
    for (int j = 0; j < 4; ++j){
      int node = node0 + quad*4 + j;
      if (node < N){
        unsigned short* yp = &y[(((size_t)r*N + node))*32 + col];
        yp[0]  = f2bf(a0[j]);
        yp[16] = f2bf(a1[j]);
      }
    }
  }
}

// softmax + aggregation. deg<=64 fast path (scalars, no spill), 4x-unrolled
// gather. Per-block stats -> partials[] (plain store); k_stat reduces them.
// NO per-block device fence / same-address atomic (that cost 750us in r6/r7).
__global__ void k_main(const int* __restrict__ iptr, const int* __restrict__ pack,
                       const float* __restrict__ yq, const float* __restrict__ yk,
                       const unsigned short* __restrict__ y,
                       const void* __restrict__ biasp, size_t bofs,
                       const float* __restrict__ xres, float* __restrict__ hpre,
                       double* __restrict__ partials, int* __restrict__ DF, int N){
  __shared__ double sdb[4][2];
  int gt = blockIdx.x*blockDim.x + threadIdx.x;
  int node = gt >> 6, lane = gt & 63;
  int wid = threadIdx.x >> 6;
  int f32 = DF[1];
  int o = lane & 31;
  bool active = (node < N);
  float hp = 0.f;

  if (active){
    int start = iptr[node];
    int deg = iptr[node+1] - start;
    const float* yqn = yq + (size_t)node*16;
    float acc = 0.f;
    float ssum = 0.f;

    if (deg <= 64){
      // ---- fast path: one chunk in scalars ----
      int pe = 0; float a = -INFINITY;
      if (lane < deg){
        pe = pack[start+lane];
        int sr = pe & 0xFFFFF, et = pe >> 20;
        a = yqn[et] + yk[(size_t)sr*16+et];
        a = (a >= 0.f) ? a : 0.2f*a;
      }
      float amax = a;
      #pragma unroll
      for (int o2=32;o2>0;o2>>=1) amax = fmaxf(amax, __shfl_xor(amax, o2));
      float ev = (lane < deg) ? expf(a - amax) : 0.f;
      ssum = ev;
      int sub = lane >> 5;
      for (; sub + 6 < deg; sub += 8){
        float w0 = __shfl(ev, sub),   w1 = __shfl(ev, sub+2);
        float w2 = __shfl(ev, sub+4), w3 = __shfl(ev, sub+6);
        int   p0 = __shfl(pe, sub),   p1 = __shfl(pe, sub+2);
        int   p2 = __shfl(pe, sub+4), p3 = __shfl(pe, sub+6);
        float v0 = bf2f(y[((size_t)(p0 >> 20)*N + (p0 & 0xFFFFF))*32 + o]);
        float v1 = bf2f(y[((size_t)(p1 >> 20)*N + (p1 & 0xFFFFF))*32 + o]);
        float v2 = bf2f(y[((size_t)(p2 >> 20)*N + (p2 & 0xFFFFF))*32 + o]);
        float v3 = bf2f(y[((size_t)(p3 >> 20)*N + (p3 & 0xFFFFF))*32 + o]);
        acc = fmaf(w0, v0, acc);
        acc = fmaf(w1, v1, acc);
        acc = fmaf(w2, v2, acc);
        acc = fmaf(w3, v3, acc);
      }
      for (; sub < deg; sub += 2){
        float wgt = __shfl(ev, sub);
        int pb = __shfl(pe, sub);
        acc = fmaf(wgt, bf2f(y[((size_t)(pb >> 20)*N + (pb & 0xFFFFF))*32 + o]), acc);
      }
    } else {
      // ---- slow path: two-pass recompute (rare: deg>64) ----
      float amax = -INFINITY;
      for (int k = lane; k < deg; k += 64){
        int pe = pack[start+k];
        int sr = pe & 0xFFFFF, et = pe >> 20;
        float a = yqn[et] + yk[(size_t)sr*16+et];
        a = (a >= 0.f) ? a : 0.2f*a;
        amax = fmaxf(amax, a);
      }
      #pragma unroll
      for (int o2=32;o2>0;o2>>=1) amax = fmaxf(amax, __shfl_xor(amax, o2));
      for (int c = 0; c < deg; c += 64){
        int k = c + lane;
        float ev = 0.f; int pe = 0;
        if (k < deg){
          pe = pack[start+k];
          int sr = pe & 0xFFFFF, et = pe >> 20;
          float a = yqn[et] + yk[(size_t)sr*16+et];
          a = (a >= 0.f) ? a : 0.2f*a;
          ev = expf(a - amax);
          ssum += ev;
        }
        int lim = min(64, deg - c);
        int sub = lane >> 5;
        for (; sub + 6 < lim; sub += 8){
          float w0 = __shfl(ev, sub),   w1 = __shfl(ev, sub+2);
          float w2 = __shfl(ev, sub+4), w3 = __shfl(ev, sub+6);
          int   p0 = __shfl(pe, sub),   p1 = __shfl(pe, sub+2);
          int   p2 = __shfl(pe, sub+4), p3 = __shfl(pe, sub+6);
          float v0 = bf2f(y[((size_t)(p0 >> 20)*N + (p0 & 0xFFFFF))*32 + o]);
          float v1 = bf2f(y[((size_t)(p1 >> 20)*N + (p1 & 0xFFFFF))*32 + o]);
          float v2 = bf2f(y[((size_t)(p2 >> 20)*N + (p2 & 0xFFFFF))*32 + o]);
          float v3 = bf2f(y[((size_t)(p3 >> 20)*N + (p3 & 0xFFFFF))*32 + o]);
          acc = fmaf(w0, v0, acc);
          acc = fmaf(w1, v1, acc);
          acc = fmaf(w2, v2, acc);
          acc = fmaf(w3, v3, acc);
        }
        for (; sub < lim; sub += 2){
          float wgt = __shfl(ev, sub);
          int pb = __shfl(pe, sub);
          acc = fmaf(wgt, bf2f(y[((size_t)(pb >> 20)*N + (pb & 0xFFFFF))*32 + o]), acc);
        }
      }
    }
    #pragma unroll
    for (int o2=32;o2>0;o2>>=1) ssum += __shfl_xor(ssum, o2);
    float inv = 1.f/(ssum + 1e-16f);
    acc *= inv;
    acc += __shfl_xor(acc, 32);

    if (lane < 32){
      hp = acc + ldin(biasp, bofs + o, f32);
      if (xres) hp += xres[(size_t)node*32 + o];
      if (badf(hp)) atomicOr(DF, 32);
      hpre[(size_t)node*32 + o] = hp;
    }
  }

  // block-level LN stats -> plain store to partials (no fence, no atomics)
  float s1 = (active && lane < 32) ? hp : 0.f;
  float s2 = s1*s1;
  #pragma unroll
  for (int o2=32;o2>0;o2>>=1){ s1 += __shfl_xor(s1,o2); s2 += __shfl_xor(s2,o2); }
  if (lane == 0){ sdb[wid][0] = (double)s1; sdb[wid][1] = (double)s2; }
  __syncthreads();
  if (threadIdx.x == 0){
    partials[(size_t)blockIdx.x*2]   = sdb[0][0]+sdb[1][0]+sdb[2][0]+sdb[3][0];
    partials[(size_t)blockIdx.x*2+1] = sdb[0][1]+sdb[1][1]+sdb[2][1]+sdb[3][1];
  }
}

__global__ void k_stat(const double* __restrict__ partials, int nb,
                       double* __restrict__ PD, int l){
  double t1 = 0.0, t2 = 0.0;
  for (int i = threadIdx.x; i < nb; i += 256){
    t1 += partials[(size_t)i*2];
    t2 += partials[(size_t)i*2+1];
  }
  t1 = wsum_d(t1); t2 = wsum_d(t2);
  __shared__ double sd[8];
  int w = threadIdx.x >> 6;
  if ((threadIdx.x & 63) == 0){ sd[w*2] = t1; sd[w*2+1] = t2; }
  __syncthreads();
  if (threadIdx.x == 0){
    PD[32+2*l]   = sd[0]+sd[2]+sd[4]+sd[6];
    PD[32+2*l+1] = sd[1]+sd[3]+sd[5]+sd[7];
  }
}

__global__ void k_ln(float* __restrict__ h, const void* __restrict__ lnw,
                     const void* __restrict__ lnb, size_t lofs,
                     double* __restrict__ PD, int l, int N){
  int idx = blockIdx.x*blockDim.x + threadIdx.x;
  if (idx >= N*32) return;
  int* DF = (int*)(PD + 28);
  int f32 = DF[1];
  const double* stats = PD + 32 + 2*l;
  int o = idx & 31;
  double cntf = (double)N*32.0;
  double mu = stats[0]/cntf;
  double var = stats[1]/cntf - mu*mu;
  float rstd = (float)(1.0/(sqrt(var>0.0?var:0.0) + 1e-5));
  float v = (h[idx] - (float)mu)*rstd*ldin(lnw, lofs + o, f32) + ldin(lnb, lofs + o, f32);
  v = v / (1.f + expf(-v));
  if (badf(v)) atomicOr(DF, 64);
  h[idx] = v;
}

__global__ void k_pool(const float* __restrict__ h, double* __restrict__ PD, int N){
  __shared__ float sp[8][33];
  int t = threadIdx.x, o = t & 31, g = t >> 5;
  int r0 = blockIdx.x*256;
  float s = 0.f;
  for (int r = r0 + g; r < N && r < r0 + 256; r += 8) s += h[(size_t)r*32 + o];
  sp[g][o] = s;
  __syncthreads();
  if (t < 32){
    float tot = 0.f;
    #pragma unroll
    for (int g2=0; g2<8; ++g2) tot += sp[g2][t];
    atomicAdd(&PD[40 + t], (double)tot);
  }
}

__global__ void k_out(double* __restrict__ PD, const void* __restrict__ Wl,
                      const void* __restrict__ bl, void* __restrict__ out, int N, int H2){
  int j = blockIdx.x*blockDim.x + threadIdx.x;
  if (j >= H2) return;
  int* DF = (int*)(PD + 28);
  int f32 = DF[1];
  int flag = DF[0];
  const double* pool = PD + 40;
  float acc = ldin(bl, j, f32);
  for (int o=0;o<32;++o)
    acc = fmaf((float)(pool[o]/(double)N), ldin(Wl, (size_t)j*32+o, f32), acc);
  if (badf(acc)) flag |= 128;
  float v = acc / (1.f + expf(-acc));
  if (flag) v = (float)flag;   // diagnostic: absmax == stage bitmask
  if (f32) ((float*)out)[j] = v;
  else     ((unsigned short*)out)[j] = f2bf(v);
}

__global__ void k_diag(unsigned short* out, float val, int H2){
  int j = blockIdx.x*blockDim.x + threadIdx.x;
  if (j < H2) out[j] = f2bf(val);
}

// ---------------- entry ----------------
extern "C" void kernel_launch(void* const* d_in, const int* in_sizes, int n_in,
                              void* d_out, int out_size, void* d_ws, size_t ws_size,
                              hipStream_t stream)
{
  const int N  = in_sizes[0] / 35;
  const int E  = in_sizes[3];
  const int R  = 15;
  const int H2 = in_sizes[19];

  const void* data = d_in[0];
  const int* ei  = (const int*)d_in[2];
  const int* etp = (const int*)d_in[3];
  const void* W0  = d_in[6];
  const void* q0  = d_in[7];
  const void* k0  = d_in[8];
  const void* b0  = d_in[9];
  const void* Wsp = d_in[10];
  const void* qsp = d_in[11];
  const void* ksp = d_in[12];
  const void* bsp = d_in[13];
  const void* lnw = d_in[14];
  const void* lnb = d_in[15];
  const void* ln1w= d_in[16];
  const void* ln1b= d_in[17];
  const void* l1W = d_in[18];
  const void* l1b = d_in[19];

  char* base = (char*)d_ws;
  size_t off = 0;
  auto A = [&](size_t nb)->size_t { size_t c = off; off += (nb + 255) & ~(size_t)255; return c; };
  size_t oPD  = A(1024);
  size_t oCnt = A((size_t)N*4);
  size_t oPtr = A(((size_t)N+1)*4);
  size_t oCur = A((size_t)N*4);
  size_t oBs  = A(4096);
  size_t oBp  = A(4096);
  size_t oPk  = A((size_t)E*4);
  size_t oX   = A((size_t)N*36*4);
  size_t oH0  = A((size_t)N*32*4);
  size_t oH1  = A((size_t)N*32*4);
  size_t oYq  = A((size_t)N*16*4);
  size_t oYk  = A((size_t)N*16*4);
  size_t oBf  = A((size_t)15*2*2*64*8*2);
  size_t oQk  = A((size_t)2*2*2*64*8*2);
  int nbMain  = (int)(((size_t)N*64 + 255)/256);
  size_t oPt  = A((size_t)nbMain*2*8);
  size_t oY   = off;
  size_t needB = oY + (size_t)R*N*32*2;

  double* PD  = (double*)(base + oPD);
  int* DF     = (int*)(PD + 28);
  int* cnt    = (int*)(base + oCnt);
  int* iptr   = (int*)(base + oPtr);
  int* cur    = (int*)(base + oCur);
  int* bsum   = (int*)(base + oBs);
  int* bpre   = (int*)(base + oBp);
  int* pack   = (int*)(base + oPk);
  float* xb   = (float*)(base + oX);
  float* h0   = (float*)(base + oH0);
  float* h1   = (float*)(base + oH1);
  float* yqb  = (float*)(base + oYq);
  float* ykb  = (float*)(base + oYk);
  unsigned short* bfr  = (unsigned short*)(base + oBf);
  unsigned short* qkfr = (unsigned short*)(base + oQk);
  double* partials = (double*)(base + oPt);
  unsigned short* y = (unsigned short*)(base + oY);

  if (ws_size < needB){
    k_diag<<<1, 256, 0, stream>>>((unsigned short*)d_out, (float)(ws_size >> 20), H2);
    return;
  }

  // zero PD + cnt ( [0, oPtr) covers both exactly )
  hipMemsetAsync(base, 0, oPtr, stream);

  int nbN = (N + 255)/256;
  int nbE = (E + 255)/256;
  int nus = (in_sizes[0] < 1024) ? in_sizes[0] : 1024;

  k_dtype<<<1, 256, 0, stream>>>((const unsigned short*)data, nus, PD);
  k_red1<<<nbN, 256, 0, stream>>>(data, N, PD);
  k_eig<<<1, 1, 0, stream>>>(PD, N);
  k_buildx<<<nbN, 256, 0, stream>>>(data, ln1w, ln1b, PD, xb, N);

  k_count<<<nbE, 256, 0, stream>>>(ei + E, cnt, E);
  k_scan1<<<nbN, 256, 0, stream>>>(cnt, bsum, N);
  k_scan2<<<1, 1, 0, stream>>>(bsum, bpre, iptr, nbN, N);
  k_scan3<<<nbN, 256, 0, stream>>>(cnt, bpre, iptr, cur, N);
  k_scatter<<<nbE, 256, 0, stream>>>(ei, ei + E, etp, cur, pack, E);

  int nbMf = (int)(((N + 15)/16 + 3)/4);
  for (int l=0; l<4; ++l){
    const void* W  = (l==0)? W0 : Wsp;  size_t wofs = (l==0)? 0 : (size_t)(l-1)*R*32*32;
    const void* qp = (l==0)? q0 : qsp;  size_t qofs = (l==0)? 0 : (size_t)(l-1)*32;
    const void* kp = (l==0)? k0 : ksp;
    const void* bp = (l==0)? b0 : bsp;  size_t bofs = qofs;
    int str = (l==0)? 36 : 32;
    int KC = (l==0)? 2 : 1;
    int F = (l==0)? 35 : 32;
    const float* xin = (l==0)? xb : ((l%2==0)? h1 : h0);
    float* hout = (l%2==0)? h0 : h1;
    int nFrag = 15*KC*2*64*8 + 2*2*KC*64*8;
    k_fragpack<<<(nFrag+255)/256, 256, 0, stream>>>(W, wofs, F, KC, qp, kp, qofs, bfr, qkfr, DF);
    k_mf<<<nbMf, 256, 0, stream>>>(xin, str, KC, N, bfr, qkfr, y, yqb, ykb);
    k_main<<<nbMain, 256, 0, stream>>>(iptr, pack, yqb, ykb, y, bp, bofs,
                 (l==0)? (const float*)nullptr : xin, hout, partials, DF, N);
    k_stat<<<1, 256, 0, stream>>>(partials, nbMain, PD, l);
    k_ln<<<(N*32+255)/256, 256, 0, stream>>>(hout, lnw, lnb, (size_t)l*32, PD, l, N);
  }

  k_pool<<<nbN, 256, 0, stream>>>(h1, PD, N);
  k_out<<<(H2+255)/256, 256, 0, stream>>>(PD, l1W, l1b, d_out, N, H2);
}

// Round 9
// 1508.845 us; speedup vs baseline: 3.0499x; 1.0348x over previous
//
#include <hip/hip_runtime.h>
#include <math.h>
#include <stdint.h>

// ---------------- helpers ----------------
__device__ inline float bf2f(unsigned short u){
  union { unsigned int i; float f; } x; x.i = ((unsigned int)u) << 16; return x.f;
}
__device__ inline unsigned short f2bf(float f){
  union { float f; unsigned int i; } x; x.f = f;
  unsigned int u = x.i;
  return (unsigned short)((u + 0x7FFFu + ((u >> 16) & 1u)) >> 16);
}
// dtype-dispatched input load: f32 flag comes from device-side probe
__device__ inline float ldin(const void* p, size_t i, int f32){
  return f32 ? ((const float*)p)[i] : bf2f(((const unsigned short*)p)[i]);
}

__device__ inline int badf(float v){ return !(fabsf(v) <= 3.0e38f); }
__device__ inline int badd(double v){ return !(fabs(v) <= 1.0e300); }

__device__ inline double wsum_d(double v){
  #pragma unroll
  for (int o = 32; o > 0; o >>= 1) v += __shfl_down(v, o);
  return v;
}
__device__ inline double wmax_d(double v){
  #pragma unroll
  for (int o = 32; o > 0; o >>= 1) v = fmax(v, __shfl_down(v, o));
  return v;
}
__device__ inline void atomicMaxD(double* addr, double v){ // v >= 0
  atomicMax((unsigned long long*)addr, (unsigned long long)__double_as_longlong(v));
}

// MFMA types
typedef __attribute__((ext_vector_type(8))) short short8;
typedef __attribute__((ext_vector_type(4))) float f32x4;
__device__ inline f32x4 mfma16(short8 a, short8 b, f32x4 c){
  return __builtin_amdgcn_mfma_f32_16x16x32_bf16(a, b, c, 0, 0, 0);
}

// ---------------- LAPACK 3x3 eigh port (dsytd2 + dsteqr + dormtr) ----------------
__device__ inline double d_sign(double a, double b){ return (b >= 0.0) ? fabs(a) : -fabs(a); }
__device__ inline double dlapy2_(double x, double y){ return sqrt(x*x + y*y); }

__device__ void dlartg_(double f, double g, double* cs, double* sn, double* r){
  // LAPACK >= 3.10 convention: c >= 0, r = sign(d, f)
  if (g == 0.0){ *cs = 1.0; *sn = 0.0; *r = f; }
  else if (f == 0.0){ *cs = 0.0; *sn = (g >= 0.0) ? 1.0 : -1.0; *r = fabs(g); }
  else {
    double d = sqrt(f*f + g*g);
    *cs = fabs(f)/d;
    *r  = d_sign(d, f);
    *sn = g / (*r);
  }
}

__device__ void dlaev2_(double a, double b, double c, double* rt1, double* rt2,
                        double* cs1, double* sn1){
  double sm = a + c, df = a - c, adf = fabs(df), tb = b + b, ab = fabs(tb);
  double acmx, acmn;
  if (fabs(a) > fabs(c)){ acmx = a; acmn = c; } else { acmx = c; acmn = a; }
  double rt;
  if (adf > ab) rt = adf*sqrt(1.0 + (ab/adf)*(ab/adf));
  else if (adf < ab) rt = ab*sqrt(1.0 + (adf/ab)*(adf/ab));
  else rt = ab*sqrt(2.0);
  int sgn1;
  if (sm < 0.0){ *rt1 = 0.5*(sm - rt); sgn1 = -1; *rt2 = (acmx/(*rt1))*acmn - (b/(*rt1))*b; }
  else if (sm > 0.0){ *rt1 = 0.5*(sm + rt); sgn1 = 1; *rt2 = (acmx/(*rt1))*acmn - (b/(*rt1))*b; }
  else { *rt1 = 0.5*rt; *rt2 = -0.5*rt; sgn1 = 1; }
  int sgn2; double cs;
  if (df >= 0.0){ cs = df + rt; sgn2 = 1; } else { cs = df - rt; sgn2 = -1; }
  double acs = fabs(cs);
  if (acs > ab){ double ct = -tb/cs; *sn1 = 1.0/sqrt(1.0+ct*ct); *cs1 = ct*(*sn1); }
  else {
    if (ab == 0.0){ *cs1 = 1.0; *sn1 = 0.0; }
    else { double tn = -cs/tb; *cs1 = 1.0/sqrt(1.0+tn*tn); *sn1 = tn*(*cs1); }
  }
  if (sgn1 == sgn2){ double tn = *cs1; *cs1 = -(*sn1); *sn1 = tn; }
}

__device__ void dsteqr3_(double* dd, double* ee, double z[3][3]){
  #define D_(i) dd[(i)-1]
  #define E_(i) ee[(i)-1]
  #define Z_(i,j) z[(i)-1][(j)-1]
  #define CW_(i) cw[(i)-1]
  #define SW_(i) sw[(i)-1]
  const int n = 3;
  const double eps = 1.1102230246251565e-16;
  const double eps2 = eps*eps;
  const double safmin = 2.2250738585072014e-308;
  const int nmaxit = n*30;
  double cw[3], sw[3];
  int jtot = 0;
  int l1 = 1, l, m, lsv, lend, lendsv;
  double p, g, r, c, s, f, b, rt1, rt2, anorm, tst;

L10:
  if (l1 > n) goto L160;
  if (l1 > 1) E_(l1-1) = 0.0;
  if (l1 <= n-1){
    for (m = l1; m <= n-1; ++m){
      tst = fabs(E_(m));
      if (tst == 0.0) goto L30;
      if (tst <= (sqrt(fabs(D_(m)))*sqrt(fabs(D_(m+1))))*eps){ E_(m) = 0.0; goto L30; }
    }
  }
  m = n;
L30:
  l = l1; lsv = l; lend = m; lendsv = lend; l1 = m+1;
  if (lend == l) goto L10;
  anorm = 0.0;
  for (int i = l; i <= lend; ++i) anorm = fmax(anorm, fabs(D_(i)));
  for (int i = l; i <= lend-1; ++i) anorm = fmax(anorm, fabs(E_(i)));
  if (anorm == 0.0) goto L10;
  if (fabs(D_(lend)) < fabs(D_(l))){ lend = lsv; l = lendsv; }
  if (lend > l) goto L40; else goto L90;

  // -------- QL iteration --------
L40:
  if (l != lend){
    for (m = l; m <= lend-1; ++m){
      tst = fabs(E_(m)); tst = tst*tst;
      if (tst <= (eps2*fabs(D_(m)))*fabs(D_(m+1)) + safmin) goto L60;
    }
  }
  m = lend;
L60:
  if (m < lend) E_(m) = 0.0;
  p = D_(l);
  if (m == l) goto L80;
  if (m == l+1){
    dlaev2_(D_(l), E_(l), D_(l+1), &rt1, &rt2, &c, &s);
    CW_(l) = c; SW_(l) = s;
    { double ct = CW_(l), st = SW_(l);
      if (ct != 1.0 || st != 0.0)
        for (int i = 1; i <= n; ++i){
          double t = Z_(i, l+1);
          Z_(i, l+1) = ct*t - st*Z_(i, l);
          Z_(i, l)   = st*t + ct*Z_(i, l);
        }
    }
    D_(l) = rt1; D_(l+1) = rt2; E_(l) = 0.0;
    l += 2;
    if (l <= lend) goto L40;
    goto L140;
  }
  if (jtot == nmaxit) goto L140;
  jtot++;
  g = (D_(l+1) - p)/(2.0*E_(l));
  r = dlapy2_(g, 1.0);
  g = D_(m) - p + E_(l)/(g + d_sign(r, g));
  s = 1.0; c = 1.0; p = 0.0;
  for (int i = m-1; i >= l; --i){
    f = s*E_(i); b = c*E_(i);
    dlartg_(g, f, &c, &s, &r);
    if (i != m-1) E_(i+1) = r;
    g = D_(i+1) - p;
    r = (D_(i) - g)*s + 2.0*c*b;
    p = s*r;
    D_(i+1) = g + p;
    g = c*r - b;
    CW_(i) = c; SW_(i) = -s;
  }
  { int mm = m - l + 1;
    for (int j = mm-1; j >= 1; --j){
      double ct = CW_(l+j-1), st = SW_(l+j-1);
      if (ct != 1.0 || st != 0.0)
        for (int i = 1; i <= n; ++i){
          double t = Z_(i, l+j);
          Z_(i, l+j)   = ct*t - st*Z_(i, l+j-1);
          Z_(i, l+j-1) = st*t + ct*Z_(i, l+j-1);
        }
    }
  }
  D_(l) = D_(l) - p;
  E_(l) = g;
  goto L40;
L80:
  D_(l) = p;
  l++;
  if (l <= lend) goto L40;
  goto L140;

  // -------- QR iteration --------
L90:
  if (l != lend){
    for (m = l; m >= lend+1; --m){
      tst = fabs(E_(m-1)); tst = tst*tst;
      if (tst <= (eps2*fabs(D_(m)))*fabs(D_(m-1)) + safmin) goto L110;
    }
  }
  m = lend;
L110:
  if (m > lend) E_(m-1) = 0.0;
  p = D_(l);
  if (m == l) goto L130;
  if (m == l-1){
    dlaev2_(D_(l-1), E_(l-1), D_(l), &rt1, &rt2, &c, &s);
    CW_(m) = c; SW_(m) = s;
    { double ct = CW_(m), st = SW_(m);
      if (ct != 1.0 || st != 0.0)
        for (int i = 1; i <= n; ++i){
          double t = Z_(i, l);
          Z_(i, l)   = ct*t - st*Z_(i, l-1);
          Z_(i, l-1) = st*t + ct*Z_(i, l-1);
        }
    }
    D_(l-1) = rt1; D_(l) = rt2; E_(l-1) = 0.0;
    l -= 2;
    if (l >= lend) goto L90;
    goto L140;
  }
  if (jtot == nmaxit) goto L140;
  jtot++;
  g = (D_(l-1) - p)/(2.0*E_(l-1));
  r = dlapy2_(g, 1.0);
  g = D_(m) - p + E_(l-1)/(g + d_sign(r, g));
  s = 1.0; c = 1.0; p = 0.0;
  for (int i = m; i <= l-1; ++i){
    f = s*E_(i); b = c*E_(i);
    dlartg_(g, f, &c, &s, &r);
    if (i != m) E_(i-1) = r;
    g = D_(i) - p;
    r = (D_(i+1) - g)*s + 2.0*c*b;
    p = s*r;
    D_(i) = g + p;
    g = c*r - b;
    CW_(i) = c; SW_(i) = s;
  }
  { int mm = l - m + 1;
    for (int j = 1; j <= mm-1; ++j){
      double ct = CW_(m+j-1), st = SW_(m+j-1);
      if (ct != 1.0 || st != 0.0)
        for (int i = 1; i <= n; ++i){
          double t = Z_(i, m+j);
          Z_(i, m+j)   = ct*t - st*Z_(i, m+j-1);
          Z_(i, m+j-1) = st*t + ct*Z_(i, m+j-1);
        }
    }
  }
  D_(l) = D_(l) - p;
  E_(l-1) = g;
  goto L90;
L130:
  D_(l) = p;
  l--;
  if (l >= lend) goto L90;
  goto L140;

L140:
  if (jtot < nmaxit) goto L10;
  goto L190;

L160:
  for (int ii = 2; ii <= n; ++ii){
    int i = ii-1, k = i;
    p = D_(i);
    for (int j = ii; j <= n; ++j) if (D_(j) < p){ k = j; p = D_(j); }
    if (k != i){
      D_(k) = D_(i); D_(i) = p;
      for (int rr = 1; rr <= n; ++rr){ double t = Z_(rr,i); Z_(rr,i) = Z_(rr,k); Z_(rr,k) = t; }
    }
  }
L190:
  ;
  #undef D_
  #undef E_
  #undef Z_
  #undef CW_
  #undef SW_
}

__device__ void eigh3_(const double C[3][3], double w[3], double v[3][3]){
  double a00=C[0][0], a10=C[1][0], a20=C[2][0], a11=C[1][1], a21=C[2][1], a22=C[2][2];
  double dd[3], ee[2], tau, v2;
  double alpha = a10, x = a20;
  double xnorm = fabs(x);
  if (xnorm == 0.0){ tau = 0.0; v2 = 0.0; ee[0] = alpha; }
  else {
    double beta = -d_sign(dlapy2_(alpha, xnorm), alpha);
    tau = (beta - alpha)/beta;
    v2 = x/(alpha - beta);
    ee[0] = beta;
  }
  if (tau != 0.0){
    double w0 = tau*(a11 + a21*v2);
    double w1 = tau*(a21 + a22*v2);
    double wv = w0 + w1*v2;
    double ac = -0.5*tau*wv;
    w0 += ac; w1 += ac*v2;
    a11 = a11 - 2.0*w0;
    a21 = a21 - (v2*w0 + w1);
    a22 = a22 - 2.0*v2*w1;
  }
  dd[0]=a00; dd[1]=a11; dd[2]=a22; ee[1]=a21;
  double z[3][3] = {{1,0,0},{0,1,0},{0,0,1}};
  dsteqr3_(dd, ee, z);
  for (int j = 0; j < 3; ++j){
    double t = z[1][j] + v2*z[2][j];
    z[1][j] -= tau*t;
    z[2][j] -= tau*t*v2;
  }
  for (int i=0;i<3;++i){ w[i]=dd[i]; for(int j=0;j<3;++j) v[i][j]=z[i][j]; }
}

// ---------------- kernels ----------------
// PD layout (doubles): 0-2 possum, 3 fsum, 4 fsumsq, 5-10 raw pos moments
// (m00,m10,m20,m11,m21,m22), 12-14 mean, 15 scale, 16-24 V, 25 mu1, 26 rstd1,
// 28: int flag + int isf32, 32+2l per-layer LN stats, 40-71 pool,
// 72-74 max(64+p), 75-77 max(64-p)

__global__ void k_dtype(const unsigned short* __restrict__ data, int nus, double* PD){
  int* DF = (int*)(PD + 28);
  int t = threadIdx.x;
  int bad = 0;
  for (int i = t; i < nus; i += 256){
    int e = (data[i] >> 7) & 0xFF;
    if (e > 0x90 || (e && e < 0x60)) bad++;
  }
  #pragma unroll
  for (int o = 32; o > 0; o >>= 1) bad += __shfl_down(bad, o);
  __shared__ int sb[4];
  if ((t & 63) == 0) sb[t >> 6] = bad;
  __syncthreads();
  if (t == 0) DF[1] = ((sb[0]+sb[1]+sb[2]+sb[3]) > nus/16) ? 1 : 0;
}

// single pass: pos sums, raw second moments, min/max (as max(64±p)), feat sums
__global__ void k_red1(const void* __restrict__ data, int N, double* PD){
  int n = blockIdx.x*blockDim.x + threadIdx.x;
  const int* DF = (const int*)(PD + 28);
  int f32 = DF[1];
  double vals[11] = {0,0,0,0,0,0,0,0,0,0,0};
  double mp[3] = {0,0,0}, mn[3] = {0,0,0};
  if (n < N){
    size_t rb = (size_t)n*35;
    double p0 = ldin(data, rb+0, f32);
    double p1 = ldin(data, rb+1, f32);
    double p2 = ldin(data, rb+2, f32);
    vals[0]=p0; vals[1]=p1; vals[2]=p2;
    double fs=0, fss=0;
    for (int k=3;k<35;++k){ double v = ldin(data, rb+k, f32); fs += v; fss += v*v; }
    vals[3]=fs; vals[4]=fss;
    vals[5]=p0*p0; vals[6]=p1*p0; vals[7]=p2*p0; vals[8]=p1*p1; vals[9]=p2*p1; vals[10]=p2*p2;
    mp[0]=64.0+p0; mp[1]=64.0+p1; mp[2]=64.0+p2;
    mn[0]=64.0-p0; mn[1]=64.0-p1; mn[2]=64.0-p2;
  }
  __shared__ double sred[4];
  for (int q=0;q<11;++q){
    double t = wsum_d(vals[q]);
    if ((threadIdx.x&63)==0) sred[threadIdx.x>>6]=t;
    __syncthreads();
    if (threadIdx.x==0) atomicAdd(&PD[q], sred[0]+sred[1]+sred[2]+sred[3]);
    __syncthreads();
  }
  for (int j=0;j<6;++j){
    double t = wmax_d(j<3 ? mp[j] : mn[j-3]);
    if ((threadIdx.x&63)==0) sred[threadIdx.x>>6]=t;
    __syncthreads();
    if (threadIdx.x==0)
      atomicMaxD(&PD[72+j], fmax(fmax(sred[0],sred[1]), fmax(sred[2],sred[3])));
    __syncthreads();
  }
}

__global__ void k_eig(double* PD, int N){
  if (threadIdx.x != 0 || blockIdx.x != 0) return;
  int* DF = (int*)(PD + 28);
  int bad0 = 0;
  for (int i=0;i<11;++i) if (badd(PD[i])) bad0 = 1;
  if (bad0) DF[0] |= 1;
  double dN = (double)N;
  double mu[3] = {PD[0]/dN, PD[1]/dN, PD[2]/dN};
  double amax = 0.0;
  for (int j=0;j<3;++j){
    double mx = (PD[72+j] - 64.0) - mu[j];
    double mnv = mu[j] - (64.0 - PD[75+j]);
    amax = fmax(amax, fmax(mx, mnv));
  }
  double s = 0.999999/amax;
  double s2 = s*s;
  double C[3][3];
  C[0][0]=(PD[5]-dN*mu[0]*mu[0])*s2; C[1][0]=(PD[6]-dN*mu[1]*mu[0])*s2;
  C[2][0]=(PD[7]-dN*mu[2]*mu[0])*s2; C[1][1]=(PD[8]-dN*mu[1]*mu[1])*s2;
  C[2][1]=(PD[9]-dN*mu[2]*mu[1])*s2; C[2][2]=(PD[10]-dN*mu[2]*mu[2])*s2;
  C[0][1]=C[1][0]; C[0][2]=C[2][0]; C[1][2]=C[2][1];
  double w[3], V[3][3];
  eigh3_(C, w, V);
  int bad1 = 0;
  for (int i=0;i<3;++i){ if (badd(w[i])) bad1=1; for (int j=0;j<3;++j) if (badd(V[i][j])) bad1=1; }
  if (bad1){
    DF[0] |= 2;
    for (int i=0;i<3;++i) for (int j=0;j<3;++j) V[i][j] = (i==j) ? 1.0 : 0.0;
  }
  PD[12]=mu[0]; PD[13]=mu[1]; PD[14]=mu[2];
  PD[15]=s;
  for (int i=0;i<3;++i) for (int j=0;j<3;++j) PD[16+i*3+j]=V[i][j];
  double cntf = dN*32.0;
  double mu1 = PD[3]/cntf;
  double var = PD[4]/cntf - mu1*mu1;
  PD[25]=mu1;
  PD[26]=1.0/(sqrt(var>0.0?var:0.0)+1e-5);
}

__global__ void k_buildx(const void* __restrict__ data,
                         const void* __restrict__ ln1w,
                         const void* __restrict__ ln1b,
                         double* __restrict__ PD, float* __restrict__ x, int N){
  int n = blockIdx.x*blockDim.x + threadIdx.x;
  if (n >= N) return;
  int* DF = (int*)(PD + 28);
  int f32 = DF[1];
  size_t rb = (size_t)n*35;
  double s = PD[15];
  double p0 = ((double)ldin(data, rb+0, f32) - PD[12])*s;
  double p1 = ((double)ldin(data, rb+1, f32) - PD[13])*s;
  double p2 = ((double)ldin(data, rb+2, f32) - PD[14])*s;
  float* xr = x + (size_t)n*36;
  int bb = 0;
  for (int j=0;j<3;++j){
    float v = (float)(p0*PD[16+j] + p1*PD[19+j] + p2*PD[22+j]);
    bb |= badf(v);
    xr[j] = v;
  }
  float mu1 = (float)PD[25], rs = (float)PD[26];
  for (int k=0;k<32;++k){
    float v = (ldin(data, rb+3+k, f32) - mu1)*rs*ldin(ln1w, k, f32) + ldin(ln1b, k, f32);
    bb |= badf(v);
    xr[3+k] = v;
  }
  xr[35] = 0.f;
  if (bb) atomicOr(DF, 4);
}

__global__ void k_count(const int* __restrict__ dst, int* __restrict__ cnt, int E){
  int i = blockIdx.x*blockDim.x + threadIdx.x;
  if (i < E) atomicAdd(&cnt[dst[i]], 1);
}

__global__ void k_scan1(const int* __restrict__ cnt, int* __restrict__ bsum, int N){
  int i = blockIdx.x*256 + threadIdx.x;
  int v = (i < N) ? cnt[i] : 0;
  #pragma unroll
  for (int o=32;o>0;o>>=1) v += __shfl_down(v, o);
  __shared__ int s4[4];
  if ((threadIdx.x&63)==0) s4[threadIdx.x>>6]=v;
  __syncthreads();
  if (threadIdx.x==0) bsum[blockIdx.x]=s4[0]+s4[1]+s4[2]+s4[3];
}

__global__ void k_scan2(const int* __restrict__ bsum, int* __restrict__ bpre,
                        int* __restrict__ iptr, int nb, int N){
  if (threadIdx.x != 0 || blockIdx.x != 0) return;
  int run = 0;
  for (int b=0;b<nb;++b){ bpre[b]=run; run += bsum[b]; }
  iptr[N] = run;
}

// iptr[i] per node; bucket heads (i%16==0) also seed the bucket counters bcur.
__global__ void k_scan3(const int* __restrict__ cnt, const int* __restrict__ bpre,
                        int* __restrict__ iptr, int* __restrict__ bcur, int N){
  __shared__ int sc[256];
  int i = blockIdx.x*256 + threadIdx.x;
  int t = threadIdx.x;
  int v = (i < N) ? cnt[i] : 0;
  sc[t] = v;
  __syncthreads();
  for (int o=1;o<256;o<<=1){
    int add = (t >= o) ? sc[t-o] : 0;
    __syncthreads();
    sc[t] += add;
    __syncthreads();
  }
  if (i < N){
    int val = bpre[blockIdx.x] + sc[t] - v;
    iptr[i] = val;
    if ((i & 15) == 0) bcur[i >> 4] = val;
  }
}

// Phase A: bin edges by dst>>4 into bucket segments of stag (append order).
// Entry = src | et<<20 | (dst&15)<<24  (fits 28 bits).
__global__ void k_binA(const int* __restrict__ src, const int* __restrict__ dst,
                       const int* __restrict__ et, int* __restrict__ bcur,
                       int* __restrict__ stag, int E){
  int i = blockIdx.x*blockDim.x + threadIdx.x;
  if (i < E){
    int d = dst[i];
    int p = atomicAdd(&bcur[d >> 4], 1);
    stag[p] = src[i] | (et[i] << 20) | ((d & 15) << 24);
  }
}

// Phase B: per bucket, scatter staged entries to exact CSR positions.
// Final writes land inside the bucket's contiguous 2KB segment (L2-coalesced).
__global__ void k_binB(const int* __restrict__ iptr, const int* __restrict__ stag,
                       int* __restrict__ pack, int N){
  __shared__ int lcnt[16];
  int b = blockIdx.x;
  int n0 = b << 4;
  int t = threadIdx.x;
  if (t < 16) lcnt[t] = (n0 + t < N) ? iptr[n0 + t] : 0;
  __syncthreads();
  int segs = iptr[n0];
  int nend = (n0 + 16 < N) ? (n0 + 16) : N;
  int sege = iptr[nend];
  for (int k = segs + t; k < sege; k += 256){
    int e = stag[k];
    int pos = atomicAdd(&lcnt[(e >> 24) & 15], 1);
    pack[pos] = e & 0xFFFFFF;
  }
}

// Pack B fragments (bf16, MFMA lane layout) for W (per r, kc, tile) and for
// the yq/yk side (u_r = W_r@q, v_r = W_r@k computed inline, hi/lo split).
__global__ void k_fragpack(const void* __restrict__ W, size_t wofs, int F, int KC,
                           const void* __restrict__ qp, const void* __restrict__ kp,
                           size_t qofs,
                           unsigned short* __restrict__ bfr,
                           unsigned short* __restrict__ qkfr,
                           const int* __restrict__ DF){
  int t = blockIdx.x*blockDim.x + threadIdx.x;
  int nB = 15*KC*2*64*8;
  int nQ = 2*2*KC*64*8;
  int f32 = DF[1];
  if (t < nB){
    int j = t & 7; int lane = (t >> 3) & 63; int tile = (t >> 9) & 1; int idx = t >> 10;
    int kc = idx % KC; int r = idx / KC;
    int f = kc*32 + (lane >> 4)*8 + j;
    int o = tile*16 + (lane & 15);
    bfr[t] = (f < F) ? f2bf(ldin(W, wofs + ((size_t)(r*F+f))*32 + o, f32)) : 0;
  } else if (t < nB + nQ){
    int u = t - nB;
    int j = u & 7; int lane = (u >> 3) & 63; int wpk = u >> 9;
    int kc = wpk % KC; int wp = wpk / KC;
    int part = wp & 1; int which = wp >> 1;
    int f = kc*32 + (lane >> 4)*8 + j;
    int rr = lane & 15;
    unsigned short val = 0;
    if (f < F && rr < 15){
      const void* v = which ? kp : qp;
      float acc = 0.f;
      for (int o = 0; o < 32; ++o)
        acc = fmaf(ldin(W, wofs + ((size_t)(rr*F+f))*32 + o, f32), ldin(v, qofs + o, f32), acc);
      unsigned short hi = f2bf(acc);
      val = (part == 0) ? hi : f2bf(acc - bf2f(hi));
    }
    qkfr[u] = val;
  }
}

// MFMA GEMM: per wave, 16 nodes x (15 r x 32 outs + yq/yk). X split hi/lo bf16.
__global__ void __launch_bounds__(256)
k_mf(const float* __restrict__ x, int str, int KC, int N,
     const unsigned short* __restrict__ bfr,
     const unsigned short* __restrict__ qkfr,
     unsigned short* __restrict__ y, float* __restrict__ yq, float* __restrict__ yk){
  int wave = blockIdx.x*(blockDim.x >> 6) + (threadIdx.x >> 6);
  int node0 = wave*16;
  if (node0 >= N) return;
  int lane = threadIdx.x & 63;
  int col = lane & 15, quad = lane >> 4;

  short8 ah[2], al[2];
  #pragma unroll
  for (int kc = 0; kc < 2; ++kc){
    if (kc >= KC) break;
    float xv[8];
    int node = node0 + col;           // A row m = lane&15
    int kbase = kc*32 + quad*8;
    if (node < N && kbase < str){
      const float* xr = x + (size_t)node*str + kbase;
      if (kbase + 8 <= str){
        float4 a = *(const float4*)xr; float4 b = *(const float4*)(xr + 4);
        xv[0]=a.x; xv[1]=a.y; xv[2]=a.z; xv[3]=a.w; xv[4]=b.x; xv[5]=b.y; xv[6]=b.z; xv[7]=b.w;
      } else if (kbase + 4 <= str){
        float4 a = *(const float4*)xr;
        xv[0]=a.x; xv[1]=a.y; xv[2]=a.z; xv[3]=a.w; xv[4]=0.f; xv[5]=0.f; xv[6]=0.f; xv[7]=0.f;
      } else {
        #pragma unroll
        for (int j=0;j<8;++j) xv[j]=0.f;
      }
    } else {
      #pragma unroll
      for (int j=0;j<8;++j) xv[j]=0.f;
    }
    #pragma unroll
    for (int j=0;j<8;++j){
      unsigned short hi = f2bf(xv[j]);
      ah[kc][j] = (short)hi;
      al[kc][j] = (short)f2bf(xv[j] - bf2f(hi));
    }
  }

  const short8* B  = (const short8*)bfr;
  const short8* QK = (const short8*)qkfr;

  // yq / yk tiles (cols = r), B-side hi/lo split too
  f32x4 aq = {0.f,0.f,0.f,0.f}, ak2 = {0.f,0.f,0.f,0.f};
  for (int kc = 0; kc < KC; ++kc){
    short8 qh = QK[((0*KC) + kc)*64 + lane];        // which=0 part=0
    short8 ql = QK[((1*KC) + kc)*64 + lane];        // which=0 part=1
    short8 kh = QK[((2*KC) + kc)*64 + lane];        // which=1 part=0
    short8 kl = QK[((3*KC) + kc)*64 + lane];        // which=1 part=1
    aq = mfma16(ah[kc], qh, aq);
    aq = mfma16(al[kc], qh, aq);
    aq = mfma16(ah[kc], ql, aq);
    ak2 = mfma16(ah[kc], kh, ak2);
    ak2 = mfma16(al[kc], kh, ak2);
    ak2 = mfma16(ah[kc], kl, ak2);
  }
  #pragma unroll
  for (int j = 0; j < 4; ++j){
    int node = node0 + quad*4 + j;
    if (node < N){
      yq[(size_t)node*16 + col] = aq[j];
      yk[(size_t)node*16 + col] = ak2[j];
    }
  }

  // y tiles per relation
  for (int r = 0; r < 15; ++r){
    f32x4 a0 = {0.f,0.f,0.f,0.f}, a1 = {0.f,0.f,0.f,0.f};
    for (int kc = 0; kc < KC; ++kc){
      short8 b0 = B[(((size_t)(r*KC + kc))*2 + 0)*64 + lane];
      short8 b1 = B[(((size_t)(r*KC + kc))*2 + 1)*64 + lane];
      a0 = mfma16(ah[kc], b0, a0);
      a0 = mfma16(al[kc], b0, a0);
      a1 = mfma16(ah[kc], b1, a1);
      a1 = mfma16(al[kc], b1, a1);
    }
    #pragma unroll
    for (int j = 0; j < 4; ++j){
      int node = node0 + quad*4 + j;
      if (node < N){
        unsigned short* yp = &y[(((size_t)r*N + node))*32 + col];
        yp[0]  = f2bf(a0[j]);
        yp[16] = f2bf(a1[j]);
      }
    }
  }
}

// softmax + aggregation. deg<=64 fast path (scalars, no spill), 4x-unrolled
// gather. Per-block stats -> partials[] (plain store); k_stat reduces them.
// NO per-block device fence / same-address atomic (that cost 750us in r6/r7).
__global__ void k_main(const int* __restrict__ iptr, const int* __restrict__ pack,
                       const float* __restrict__ yq, const float* __restrict__ yk,
                       const unsigned short* __restrict__ y,
                       const void* __restrict__ biasp, size_t bofs,
                       const float* __restrict__ xres, float* __restrict__ hpre,
                       double* __restrict__ partials, int* __restrict__ DF, int N){
  __shared__ double sdb[4][2];
  int gt = blockIdx.x*blockDim.x + threadIdx.x;
  int node = gt >> 6, lane = gt & 63;
  int wid = threadIdx.x >> 6;
  int f32 = DF[1];
  int o = lane & 31;
  bool active = (node < N);
  float hp = 0.f;

  if (active){
    int start = iptr[node];
    int deg = iptr[node+1] - start;
    const float* yqn = yq + (size_t)node*16;
    float acc = 0.f;
    float ssum = 0.f;

    if (deg <= 64){
      // ---- fast path: one chunk in scalars ----
      int pe = 0; float a = -INFINITY;
      if (lane < deg){
        pe = pack[start+lane];
        int sr = pe & 0xFFFFF, et = pe >> 20;
        a = yqn[et] + yk[(size_t)sr*16+et];
        a = (a >= 0.f) ? a : 0.2f*a;
      }
      float amax = a;
      #pragma unroll
      for (int o2=32;o2>0;o2>>=1) amax = fmaxf(amax, __shfl_xor(amax, o2));
      float ev = (lane < deg) ? expf(a - amax) : 0.f;
      ssum = ev;
      int sub = lane >> 5;
      for (; sub + 6 < deg; sub += 8){
        float w0 = __shfl(ev, sub),   w1 = __shfl(ev, sub+2);
        float w2 = __shfl(ev, sub+4), w3 = __shfl(ev, sub+6);
        int   p0 = __shfl(pe, sub),   p1 = __shfl(pe, sub+2);
        int   p2 = __shfl(pe, sub+4), p3 = __shfl(pe, sub+6);
        float v0 = bf2f(y[((size_t)(p0 >> 20)*N + (p0 & 0xFFFFF))*32 + o]);
        float v1 = bf2f(y[((size_t)(p1 >> 20)*N + (p1 & 0xFFFFF))*32 + o]);
        float v2 = bf2f(y[((size_t)(p2 >> 20)*N + (p2 & 0xFFFFF))*32 + o]);
        float v3 = bf2f(y[((size_t)(p3 >> 20)*N + (p3 & 0xFFFFF))*32 + o]);
        acc = fmaf(w0, v0, acc);
        acc = fmaf(w1, v1, acc);
        acc = fmaf(w2, v2, acc);
        acc = fmaf(w3, v3, acc);
      }
      for (; sub < deg; sub += 2){
        float wgt = __shfl(ev, sub);
        int pb = __shfl(pe, sub);
        acc = fmaf(wgt, bf2f(y[((size_t)(pb >> 20)*N + (pb & 0xFFFFF))*32 + o]), acc);
      }
    } else {
      // ---- slow path: two-pass recompute (rare: deg>64) ----
      float amax = -INFINITY;
      for (int k = lane; k < deg; k += 64){
        int pe = pack[start+k];
        int sr = pe & 0xFFFFF, et = pe >> 20;
        float a = yqn[et] + yk[(size_t)sr*16+et];
        a = (a >= 0.f) ? a : 0.2f*a;
        amax = fmaxf(amax, a);
      }
      #pragma unroll
      for (int o2=32;o2>0;o2>>=1) amax = fmaxf(amax, __shfl_xor(amax, o2));
      for (int c = 0; c < deg; c += 64){
        int k = c + lane;
        float ev = 0.f; int pe = 0;
        if (k < deg){
          pe = pack[start+k];
          int sr = pe & 0xFFFFF, et = pe >> 20;
          float a = yqn[et] + yk[(size_t)sr*16+et];
          a = (a >= 0.f) ? a : 0.2f*a;
          ev = expf(a - amax);
          ssum += ev;
        }
        int lim = min(64, deg - c);
        int sub = lane >> 5;
        for (; sub + 6 < lim; sub += 8){
          float w0 = __shfl(ev, sub),   w1 = __shfl(ev, sub+2);
          float w2 = __shfl(ev, sub+4), w3 = __shfl(ev, sub+6);
          int   p0 = __shfl(pe, sub),   p1 = __shfl(pe, sub+2);
          int   p2 = __shfl(pe, sub+4), p3 = __shfl(pe, sub+6);
          float v0 = bf2f(y[((size_t)(p0 >> 20)*N + (p0 & 0xFFFFF))*32 + o]);
          float v1 = bf2f(y[((size_t)(p1 >> 20)*N + (p1 & 0xFFFFF))*32 + o]);
          float v2 = bf2f(y[((size_t)(p2 >> 20)*N + (p2 & 0xFFFFF))*32 + o]);
          float v3 = bf2f(y[((size_t)(p3 >> 20)*N + (p3 & 0xFFFFF))*32 + o]);
          acc = fmaf(w0, v0, acc);
          acc = fmaf(w1, v1, acc);
          acc = fmaf(w2, v2, acc);
          acc = fmaf(w3, v3, acc);
        }
        for (; sub < lim; sub += 2){
          float wgt = __shfl(ev, sub);
          int pb = __shfl(pe, sub);
          acc = fmaf(wgt, bf2f(y[((size_t)(pb >> 20)*N + (pb & 0xFFFFF))*32 + o]), acc);
        }
      }
    }
    #pragma unroll
    for (int o2=32;o2>0;o2>>=1) ssum += __shfl_xor(ssum, o2);
    float inv = 1.f/(ssum + 1e-16f);
    acc *= inv;
    acc += __shfl_xor(acc, 32);

    if (lane < 32){
      hp = acc + ldin(biasp, bofs + o, f32);
      if (xres) hp += xres[(size_t)node*32 + o];
      if (badf(hp)) atomicOr(DF, 32);
      hpre[(size_t)node*32 + o] = hp;
    }
  }

  // block-level LN stats -> plain store to partials (no fence, no atomics)
  float s1 = (active && lane < 32) ? hp : 0.f;
  float s2 = s1*s1;
  #pragma unroll
  for (int o2=32;o2>0;o2>>=1){ s1 += __shfl_xor(s1,o2); s2 += __shfl_xor(s2,o2); }
  if (lane == 0){ sdb[wid][0] = (double)s1; sdb[wid][1] = (double)s2; }
  __syncthreads();
  if (threadIdx.x == 0){
    partials[(size_t)blockIdx.x*2]   = sdb[0][0]+sdb[1][0]+sdb[2][0]+sdb[3][0];
    partials[(size_t)blockIdx.x*2+1] = sdb[0][1]+sdb[1][1]+sdb[2][1]+sdb[3][1];
  }
}

__global__ void k_stat(const double* __restrict__ partials, int nb,
                       double* __restrict__ PD, int l){
  double t1 = 0.0, t2 = 0.0;
  for (int i = threadIdx.x; i < nb; i += 256){
    t1 += partials[(size_t)i*2];
    t2 += partials[(size_t)i*2+1];
  }
  t1 = wsum_d(t1); t2 = wsum_d(t2);
  __shared__ double sd[8];
  int w = threadIdx.x >> 6;
  if ((threadIdx.x & 63) == 0){ sd[w*2] = t1; sd[w*2+1] = t2; }
  __syncthreads();
  if (threadIdx.x == 0){
    PD[32+2*l]   = sd[0]+sd[2]+sd[4]+sd[6];
    PD[32+2*l+1] = sd[1]+sd[3]+sd[5]+sd[7];
  }
}

__global__ void k_ln(float* __restrict__ h, const void* __restrict__ lnw,
                     const void* __restrict__ lnb, size_t lofs,
                     double* __restrict__ PD, int l, int N){
  int idx = blockIdx.x*blockDim.x + threadIdx.x;
  if (idx >= N*32) return;
  int* DF = (int*)(PD + 28);
  int f32 = DF[1];
  const double* stats = PD + 32 + 2*l;
  int o = idx & 31;
  double cntf = (double)N*32.0;
  double mu = stats[0]/cntf;
  double var = stats[1]/cntf - mu*mu;
  float rstd = (float)(1.0/(sqrt(var>0.0?var:0.0) + 1e-5));
  float v = (h[idx] - (float)mu)*rstd*ldin(lnw, lofs + o, f32) + ldin(lnb, lofs + o, f32);
  v = v / (1.f + expf(-v));
  if (badf(v)) atomicOr(DF, 64);
  h[idx] = v;
}

__global__ void k_pool(const float* __restrict__ h, double* __restrict__ PD, int N){
  __shared__ float sp[8][33];
  int t = threadIdx.x, o = t & 31, g = t >> 5;
  int r0 = blockIdx.x*256;
  float s = 0.f;
  for (int r = r0 + g; r < N && r < r0 + 256; r += 8) s += h[(size_t)r*32 + o];
  sp[g][o] = s;
  __syncthreads();
  if (t < 32){
    float tot = 0.f;
    #pragma unroll
    for (int g2=0; g2<8; ++g2) tot += sp[g2][t];
    atomicAdd(&PD[40 + t], (double)tot);
  }
}

__global__ void k_out(double* __restrict__ PD, const void* __restrict__ Wl,
                      const void* __restrict__ bl, void* __restrict__ out, int N, int H2){
  int j = blockIdx.x*blockDim.x + threadIdx.x;
  if (j >= H2) return;
  int* DF = (int*)(PD + 28);
  int f32 = DF[1];
  int flag = DF[0];
  const double* pool = PD + 40;
  float acc = ldin(bl, j, f32);
  for (int o=0;o<32;++o)
    acc = fmaf((float)(pool[o]/(double)N), ldin(Wl, (size_t)j*32+o, f32), acc);
  if (badf(acc)) flag |= 128;
  float v = acc / (1.f + expf(-acc));
  if (flag) v = (float)flag;   // diagnostic: absmax == stage bitmask
  if (f32) ((float*)out)[j] = v;
  else     ((unsigned short*)out)[j] = f2bf(v);
}

__global__ void k_diag(unsigned short* out, float val, int H2){
  int j = blockIdx.x*blockDim.x + threadIdx.x;
  if (j < H2) out[j] = f2bf(val);
}

// ---------------- entry ----------------
extern "C" void kernel_launch(void* const* d_in, const int* in_sizes, int n_in,
                              void* d_out, int out_size, void* d_ws, size_t ws_size,
                              hipStream_t stream)
{
  const int N  = in_sizes[0] / 35;
  const int E  = in_sizes[3];
  const int R  = 15;
  const int H2 = in_sizes[19];

  const void* data = d_in[0];
  const int* ei  = (const int*)d_in[2];
  const int* etp = (const int*)d_in[3];
  const void* W0  = d_in[6];
  const void* q0  = d_in[7];
  const void* k0  = d_in[8];
  const void* b0  = d_in[9];
  const void* Wsp = d_in[10];
  const void* qsp = d_in[11];
  const void* ksp = d_in[12];
  const void* bsp = d_in[13];
  const void* lnw = d_in[14];
  const void* lnb = d_in[15];
  const void* ln1w= d_in[16];
  const void* ln1b= d_in[17];
  const void* l1W = d_in[18];
  const void* l1b = d_in[19];

  char* base = (char*)d_ws;
  size_t off = 0;
  auto A = [&](size_t nb)->size_t { size_t c = off; off += (nb + 255) & ~(size_t)255; return c; };
  size_t oPD  = A(1024);
  size_t oCnt = A((size_t)N*4);
  size_t oPtr = A(((size_t)N+1)*4);
  size_t oCur = A((size_t)N*4);
  size_t oBs  = A(4096);
  size_t oBp  = A(4096);
  size_t oPk  = A((size_t)E*4);
  size_t oSt  = A((size_t)E*4);
  size_t oX   = A((size_t)N*36*4);
  size_t oH0  = A((size_t)N*32*4);
  size_t oH1  = A((size_t)N*32*4);
  size_t oYq  = A((size_t)N*16*4);
  size_t oYk  = A((size_t)N*16*4);
  size_t oBf  = A((size_t)15*2*2*64*8*2);
  size_t oQk  = A((size_t)2*2*2*64*8*2);
  int nbMain  = (int)(((size_t)N*64 + 255)/256);
  size_t oPt  = A((size_t)nbMain*2*8);
  size_t oY   = off;
  size_t needB = oY + (size_t)R*N*32*2;

  double* PD  = (double*)(base + oPD);
  int* DF     = (int*)(PD + 28);
  int* cnt    = (int*)(base + oCnt);
  int* iptr   = (int*)(base + oPtr);
  int* bcur   = (int*)(base + oCur);
  int* bsum   = (int*)(base + oBs);
  int* bpre   = (int*)(base + oBp);
  int* pack   = (int*)(base + oPk);
  int* stag   = (int*)(base + oSt);
  float* xb   = (float*)(base + oX);
  float* h0   = (float*)(base + oH0);
  float* h1   = (float*)(base + oH1);
  float* yqb  = (float*)(base + oYq);
  float* ykb  = (float*)(base + oYk);
  unsigned short* bfr  = (unsigned short*)(base + oBf);
  unsigned short* qkfr = (unsigned short*)(base + oQk);
  double* partials = (double*)(base + oPt);
  unsigned short* y = (unsigned short*)(base + oY);

  if (ws_size < needB){
    k_diag<<<1, 256, 0, stream>>>((unsigned short*)d_out, (float)(ws_size >> 20), H2);
    return;
  }

  // zero PD + cnt ( [0, oPtr) covers both exactly )
  hipMemsetAsync(base, 0, oPtr, stream);

  int nbN = (N + 255)/256;
  int nbE = (E + 255)/256;
  int nus = (in_sizes[0] < 1024) ? in_sizes[0] : 1024;

  k_dtype<<<1, 256, 0, stream>>>((const unsigned short*)data, nus, PD);
  k_red1<<<nbN, 256, 0, stream>>>(data, N, PD);
  k_eig<<<1, 1, 0, stream>>>(PD, N);
  k_buildx<<<nbN, 256, 0, stream>>>(data, ln1w, ln1b, PD, xb, N);

  k_count<<<nbE, 256, 0, stream>>>(ei + E, cnt, E);
  k_scan1<<<nbN, 256, 0, stream>>>(cnt, bsum, N);
  k_scan2<<<1, 1, 0, stream>>>(bsum, bpre, iptr, nbN, N);
  k_scan3<<<nbN, 256, 0, stream>>>(cnt, bpre, iptr, bcur, N);
  k_binA<<<nbE, 256, 0, stream>>>(ei, ei + E, etp, bcur, stag, E);
  int nbkt = (N + 15)/16;
  k_binB<<<nbkt, 256, 0, stream>>>(iptr, stag, pack, N);

  int nbMf = (int)(((N + 15)/16 + 3)/4);
  for (int l=0; l<4; ++l){
    const void* W  = (l==0)? W0 : Wsp;  size_t wofs = (l==0)? 0 : (size_t)(l-1)*R*32*32;
    const void* qp = (l==0)? q0 : qsp;  size_t qofs = (l==0)? 0 : (size_t)(l-1)*32;
    const void* kp = (l==0)? k0 : ksp;
    const void* bp = (l==0)? b0 : bsp;  size_t bofs = qofs;
    int str = (l==0)? 36 : 32;
    int KC = (l==0)? 2 : 1;
    int F = (l==0)? 35 : 32;
    const float* xin = (l==0)? xb : ((l%2==0)? h1 : h0);
    float* hout = (l%2==0)? h0 : h1;
    int nFrag = 15*KC*2*64*8 + 2*2*KC*64*8;
    k_fragpack<<<(nFrag+255)/256, 256, 0, stream>>>(W, wofs, F, KC, qp, kp, qofs, bfr, qkfr, DF);
    k_mf<<<nbMf, 256, 0, stream>>>(xin, str, KC, N, bfr, qkfr, y, yqb, ykb);
    k_main<<<nbMain, 256, 0, stream>>>(iptr, pack, yqb, ykb, y, bp, bofs,
                 (l==0)? (const float*)nullptr : xin, hout, partials, DF, N);
    k_stat<<<1, 256, 0, stream>>>(partials, nbMain, PD, l);
    k_ln<<<(N*32+255)/256, 256, 0, stream>>>(hout, lnw, lnb, (size_t)l*32, PD, l, N);
  }

  k_pool<<<nbN, 256, 0, stream>>>(h1, PD, N);
  k_out<<<(H2+255)/256, 256, 0, stream>>>(PD, l1W, l1b, d_out, N, H2);
}

// Round 10
// 1410.455 us; speedup vs baseline: 3.2627x; 1.0698x over previous
//
#include <hip/hip_runtime.h>
#include <math.h>
#include <stdint.h>

#define NBLK 256

// ---------------- helpers ----------------
__device__ inline float bf2f(unsigned short u){
  union { unsigned int i; float f; } x; x.i = ((unsigned int)u) << 16; return x.f;
}
__device__ inline unsigned short f2bf(float f){
  union { float f; unsigned int i; } x; x.f = f;
  unsigned int u = x.i;
  return (unsigned short)((u + 0x7FFFu + ((u >> 16) & 1u)) >> 16);
}
// dtype-dispatched input load: f32 flag comes from device-side probe
__device__ inline float ldin(const void* p, size_t i, int f32){
  return f32 ? ((const float*)p)[i] : bf2f(((const unsigned short*)p)[i]);
}

__device__ inline int badf(float v){ return !(fabsf(v) <= 3.0e38f); }
__device__ inline int badd(double v){ return !(fabs(v) <= 1.0e300); }

__device__ inline double wsum_d(double v){
  #pragma unroll
  for (int o = 32; o > 0; o >>= 1) v += __shfl_down(v, o);
  return v;
}
__device__ inline double wmax_d(double v){
  #pragma unroll
  for (int o = 32; o > 0; o >>= 1) v = fmax(v, __shfl_down(v, o));
  return v;
}
__device__ inline void atomicMaxD(double* addr, double v){ // v >= 0
  atomicMax((unsigned long long*)addr, (unsigned long long)__double_as_longlong(v));
}

// MFMA types
typedef __attribute__((ext_vector_type(8))) short short8;
typedef __attribute__((ext_vector_type(4))) float f32x4;
__device__ inline f32x4 mfma16(short8 a, short8 b, f32x4 c){
  return __builtin_amdgcn_mfma_f32_16x16x32_bf16(a, b, c, 0, 0, 0);
}

// ---------------- LAPACK 3x3 eigh port (dsytd2 + dsteqr + dormtr) ----------------
__device__ inline double d_sign(double a, double b){ return (b >= 0.0) ? fabs(a) : -fabs(a); }
__device__ inline double dlapy2_(double x, double y){ return sqrt(x*x + y*y); }

__device__ void dlartg_(double f, double g, double* cs, double* sn, double* r){
  // LAPACK >= 3.10 convention: c >= 0, r = sign(d, f)
  if (g == 0.0){ *cs = 1.0; *sn = 0.0; *r = f; }
  else if (f == 0.0){ *cs = 0.0; *sn = (g >= 0.0) ? 1.0 : -1.0; *r = fabs(g); }
  else {
    double d = sqrt(f*f + g*g);
    *cs = fabs(f)/d;
    *r  = d_sign(d, f);
    *sn = g / (*r);
  }
}

__device__ void dlaev2_(double a, double b, double c, double* rt1, double* rt2,
                        double* cs1, double* sn1){
  double sm = a + c, df = a - c, adf = fabs(df), tb = b + b, ab = fabs(tb);
  double acmx, acmn;
  if (fabs(a) > fabs(c)){ acmx = a; acmn = c; } else { acmx = c; acmn = a; }
  double rt;
  if (adf > ab) rt = adf*sqrt(1.0 + (ab/adf)*(ab/adf));
  else if (adf < ab) rt = ab*sqrt(1.0 + (adf/ab)*(adf/ab));
  else rt = ab*sqrt(2.0);
  int sgn1;
  if (sm < 0.0){ *rt1 = 0.5*(sm - rt); sgn1 = -1; *rt2 = (acmx/(*rt1))*acmn - (b/(*rt1))*b; }
  else if (sm > 0.0){ *rt1 = 0.5*(sm + rt); sgn1 = 1; *rt2 = (acmx/(*rt1))*acmn - (b/(*rt1))*b; }
  else { *rt1 = 0.5*rt; *rt2 = -0.5*rt; sgn1 = 1; }
  int sgn2; double cs;
  if (df >= 0.0){ cs = df + rt; sgn2 = 1; } else { cs = df - rt; sgn2 = -1; }
  double acs = fabs(cs);
  if (acs > ab){ double ct = -tb/cs; *sn1 = 1.0/sqrt(1.0+ct*ct); *cs1 = ct*(*sn1); }
  else {
    if (ab == 0.0){ *cs1 = 1.0; *sn1 = 0.0; }
    else { double tn = -cs/tb; *cs1 = 1.0/sqrt(1.0+tn*tn); *sn1 = tn*(*cs1); }
  }
  if (sgn1 == sgn2){ double tn = *cs1; *cs1 = -(*sn1); *sn1 = tn; }
}

__device__ void dsteqr3_(double* dd, double* ee, double z[3][3]){
  #define D_(i) dd[(i)-1]
  #define E_(i) ee[(i)-1]
  #define Z_(i,j) z[(i)-1][(j)-1]
  #define CW_(i) cw[(i)-1]
  #define SW_(i) sw[(i)-1]
  const int n = 3;
  const double eps = 1.1102230246251565e-16;
  const double eps2 = eps*eps;
  const double safmin = 2.2250738585072014e-308;
  const int nmaxit = n*30;
  double cw[3], sw[3];
  int jtot = 0;
  int l1 = 1, l, m, lsv, lend, lendsv;
  double p, g, r, c, s, f, b, rt1, rt2, anorm, tst;

L10:
  if (l1 > n) goto L160;
  if (l1 > 1) E_(l1-1) = 0.0;
  if (l1 <= n-1){
    for (m = l1; m <= n-1; ++m){
      tst = fabs(E_(m));
      if (tst == 0.0) goto L30;
      if (tst <= (sqrt(fabs(D_(m)))*sqrt(fabs(D_(m+1))))*eps){ E_(m) = 0.0; goto L30; }
    }
  }
  m = n;
L30:
  l = l1; lsv = l; lend = m; lendsv = lend; l1 = m+1;
  if (lend == l) goto L10;
  anorm = 0.0;
  for (int i = l; i <= lend; ++i) anorm = fmax(anorm, fabs(D_(i)));
  for (int i = l; i <= lend-1; ++i) anorm = fmax(anorm, fabs(E_(i)));
  if (anorm == 0.0) goto L10;
  if (fabs(D_(lend)) < fabs(D_(l))){ lend = lsv; l = lendsv; }
  if (lend > l) goto L40; else goto L90;

  // -------- QL iteration --------
L40:
  if (l != lend){
    for (m = l; m <= lend-1; ++m){
      tst = fabs(E_(m)); tst = tst*tst;
      if (tst <= (eps2*fabs(D_(m)))*fabs(D_(m+1)) + safmin) goto L60;
    }
  }
  m = lend;
L60:
  if (m < lend) E_(m) = 0.0;
  p = D_(l);
  if (m == l) goto L80;
  if (m == l+1){
    dlaev2_(D_(l), E_(l), D_(l+1), &rt1, &rt2, &c, &s);
    CW_(l) = c; SW_(l) = s;
    { double ct = CW_(l), st = SW_(l);
      if (ct != 1.0 || st != 0.0)
        for (int i = 1; i <= n; ++i){
          double t = Z_(i, l+1);
          Z_(i, l+1) = ct*t - st*Z_(i, l);
          Z_(i, l)   = st*t + ct*Z_(i, l);
        }
    }
    D_(l) = rt1; D_(l+1) = rt2; E_(l) = 0.0;
    l += 2;
    if (l <= lend) goto L40;
    goto L140;
  }
  if (jtot == nmaxit) goto L140;
  jtot++;
  g = (D_(l+1) - p)/(2.0*E_(l));
  r = dlapy2_(g, 1.0);
  g = D_(m) - p + E_(l)/(g + d_sign(r, g));
  s = 1.0; c = 1.0; p = 0.0;
  for (int i = m-1; i >= l; --i){
    f = s*E_(i); b = c*E_(i);
    dlartg_(g, f, &c, &s, &r);
    if (i != m-1) E_(i+1) = r;
    g = D_(i+1) - p;
    r = (D_(i) - g)*s + 2.0*c*b;
    p = s*r;
    D_(i+1) = g + p;
    g = c*r - b;
    CW_(i) = c; SW_(i) = -s;
  }
  { int mm = m - l + 1;
    for (int j = mm-1; j >= 1; --j){
      double ct = CW_(l+j-1), st = SW_(l+j-1);
      if (ct != 1.0 || st != 0.0)
        for (int i = 1; i <= n; ++i){
          double t = Z_(i, l+j);
          Z_(i, l+j)   = ct*t - st*Z_(i, l+j-1);
          Z_(i, l+j-1) = st*t + ct*Z_(i, l+j-1);
        }
    }
  }
  D_(l) = D_(l) - p;
  E_(l) = g;
  goto L40;
L80:
  D_(l) = p;
  l++;
  if (l <= lend) goto L40;
  goto L140;

  // -------- QR iteration --------
L90:
  if (l != lend){
    for (m = l; m >= lend+1; --m){
      tst = fabs(E_(m-1)); tst = tst*tst;
      if (tst <= (eps2*fabs(D_(m)))*fabs(D_(m-1)) + safmin) goto L110;
    }
  }
  m = lend;
L110:
  if (m > lend) E_(m-1) = 0.0;
  p = D_(l);
  if (m == l) goto L130;
  if (m == l-1){
    dlaev2_(D_(l-1), E_(l-1), D_(l), &rt1, &rt2, &c, &s);
    CW_(m) = c; SW_(m) = s;
    { double ct = CW_(m), st = SW_(m);
      if (ct != 1.0 || st != 0.0)
        for (int i = 1; i <= n; ++i){
          double t = Z_(i, l);
          Z_(i, l)   = ct*t - st*Z_(i, l-1);
          Z_(i, l-1) = st*t + ct*Z_(i, l-1);
        }
    }
    D_(l-1) = rt1; D_(l) = rt2; E_(l-1) = 0.0;
    l -= 2;
    if (l >= lend) goto L90;
    goto L140;
  }
  if (jtot == nmaxit) goto L140;
  jtot++;
  g = (D_(l-1) - p)/(2.0*E_(l-1));
  r = dlapy2_(g, 1.0);
  g = D_(m) - p + E_(l-1)/(g + d_sign(r, g));
  s = 1.0; c = 1.0; p = 0.0;
  for (int i = m; i <= l-1; ++i){
    f = s*E_(i); b = c*E_(i);
    dlartg_(g, f, &c, &s, &r);
    if (i != m) E_(i-1) = r;
    g = D_(i) - p;
    r = (D_(i+1) - g)*s + 2.0*c*b;
    p = s*r;
    D_(i) = g + p;
    g = c*r - b;
    CW_(i) = c; SW_(i) = s;
  }
  { int mm = l - m + 1;
    for (int j = 1; j <= mm-1; ++j){
      double ct = CW_(m+j-1), st = SW_(m+j-1);
      if (ct != 1.0 || st != 0.0)
        for (int i = 1; i <= n; ++i){
          double t = Z_(i, m+j);
          Z_(i, m+j)   = ct*t - st*Z_(i, m+j-1);
          Z_(i, m+j-1) = st*t + ct*Z_(i, m+j-1);
        }
    }
  }
  D_(l) = D_(l) - p;
  E_(l-1) = g;
  goto L90;
L130:
  D_(l) = p;
  l--;
  if (l >= lend) goto L90;
  goto L140;

L140:
  if (jtot < nmaxit) goto L10;
  goto L190;

L160:
  for (int ii = 2; ii <= n; ++ii){
    int i = ii-1, k = i;
    p = D_(i);
    for (int j = ii; j <= n; ++j) if (D_(j) < p){ k = j; p = D_(j); }
    if (k != i){
      D_(k) = D_(i); D_(i) = p;
      for (int rr = 1; rr <= n; ++rr){ double t = Z_(rr,i); Z_(rr,i) = Z_(rr,k); Z_(rr,k) = t; }
    }
  }
L190:
  ;
  #undef D_
  #undef E_
  #undef Z_
  #undef CW_
  #undef SW_
}

__device__ void eigh3_(const double C[3][3], double w[3], double v[3][3]){
  double a00=C[0][0], a10=C[1][0], a20=C[2][0], a11=C[1][1], a21=C[2][1], a22=C[2][2];
  double dd[3], ee[2], tau, v2;
  double alpha = a10, x = a20;
  double xnorm = fabs(x);
  if (xnorm == 0.0){ tau = 0.0; v2 = 0.0; ee[0] = alpha; }
  else {
    double beta = -d_sign(dlapy2_(alpha, xnorm), alpha);
    tau = (beta - alpha)/beta;
    v2 = x/(alpha - beta);
    ee[0] = beta;
  }
  if (tau != 0.0){
    double w0 = tau*(a11 + a21*v2);
    double w1 = tau*(a21 + a22*v2);
    double wv = w0 + w1*v2;
    double ac = -0.5*tau*wv;
    w0 += ac; w1 += ac*v2;
    a11 = a11 - 2.0*w0;
    a21 = a21 - (v2*w0 + w1);
    a22 = a22 - 2.0*v2*w1;
  }
  dd[0]=a00; dd[1]=a11; dd[2]=a22; ee[1]=a21;
  double z[3][3] = {{1,0,0},{0,1,0},{0,0,1}};
  dsteqr3_(dd, ee, z);
  for (int j = 0; j < 3; ++j){
    double t = z[1][j] + v2*z[2][j];
    z[1][j] -= tau*t;
    z[2][j] -= tau*t*v2;
  }
  for (int i=0;i<3;++i){ w[i]=dd[i]; for(int j=0;j<3;++j) v[i][j]=z[i][j]; }
}

// ---------------- kernels ----------------
// PD layout (doubles): 0-2 possum, 3 fsum, 4 fsumsq, 5-10 raw pos moments
// (m00,m10,m20,m11,m21,m22), 12-14 mean, 15 scale, 16-24 V, 25 mu1, 26 rstd1,
// 28: int flag + int isf32, 32+2l per-layer LN stats, 40-71 pool,
// 72-74 max(64+p), 75-77 max(64-p)

__global__ void k_dtype(const unsigned short* __restrict__ data, int nus, double* PD){
  int* DF = (int*)(PD + 28);
  int t = threadIdx.x;
  int bad = 0;
  for (int i = t; i < nus; i += 256){
    int e = (data[i] >> 7) & 0xFF;
    if (e > 0x90 || (e && e < 0x60)) bad++;
  }
  #pragma unroll
  for (int o = 32; o > 0; o >>= 1) bad += __shfl_down(bad, o);
  __shared__ int sb[4];
  if ((t & 63) == 0) sb[t >> 6] = bad;
  __syncthreads();
  if (t == 0) DF[1] = ((sb[0]+sb[1]+sb[2]+sb[3]) > nus/16) ? 1 : 0;
}

// single pass: pos sums, raw second moments, min/max (as max(64±p)), feat sums
// single __syncthreads: all 17 wave-reductions staged in one LDS round.
__global__ void k_red1(const void* __restrict__ data, int N, double* PD){
  int n = blockIdx.x*blockDim.x + threadIdx.x;
  const int* DF = (const int*)(PD + 28);
  int f32 = DF[1];
  double v11[11] = {0,0,0,0,0,0,0,0,0,0,0};
  double m6[6] = {0,0,0,0,0,0};
  if (n < N){
    size_t rb = (size_t)n*35;
    double p0 = ldin(data, rb+0, f32);
    double p1 = ldin(data, rb+1, f32);
    double p2 = ldin(data, rb+2, f32);
    v11[0]=p0; v11[1]=p1; v11[2]=p2;
    double fs=0, fss=0;
    for (int k=3;k<35;++k){ double v = ldin(data, rb+k, f32); fs += v; fss += v*v; }
    v11[3]=fs; v11[4]=fss;
    v11[5]=p0*p0; v11[6]=p1*p0; v11[7]=p2*p0; v11[8]=p1*p1; v11[9]=p2*p1; v11[10]=p2*p2;
    m6[0]=64.0+p0; m6[1]=64.0+p1; m6[2]=64.0+p2;
    m6[3]=64.0-p0; m6[4]=64.0-p1; m6[5]=64.0-p2;
  }
  __shared__ double sred[17][4];
  int wid = threadIdx.x >> 6;
  int lane0 = ((threadIdx.x & 63) == 0);
  #pragma unroll
  for (int q=0;q<11;++q){
    double t = wsum_d(v11[q]);
    if (lane0) sred[q][wid] = t;
  }
  #pragma unroll
  for (int j=0;j<6;++j){
    double t = wmax_d(m6[j]);
    if (lane0) sred[11+j][wid] = t;
  }
  __syncthreads();
  int t = threadIdx.x;
  if (t < 11) atomicAdd(&PD[t], sred[t][0]+sred[t][1]+sred[t][2]+sred[t][3]);
  else if (t < 17)
    atomicMaxD(&PD[72+(t-11)],
      fmax(fmax(sred[t][0],sred[t][1]), fmax(sred[t][2],sred[t][3])));
}

__global__ void k_eig(double* PD, int N){
  if (threadIdx.x != 0 || blockIdx.x != 0) return;
  int* DF = (int*)(PD + 28);
  int bad0 = 0;
  for (int i=0;i<11;++i) if (badd(PD[i])) bad0 = 1;
  if (bad0) DF[0] |= 1;
  double dN = (double)N;
  double mu[3] = {PD[0]/dN, PD[1]/dN, PD[2]/dN};
  double amax = 0.0;
  for (int j=0;j<3;++j){
    double mx = (PD[72+j] - 64.0) - mu[j];
    double mnv = mu[j] - (64.0 - PD[75+j]);
    amax = fmax(amax, fmax(mx, mnv));
  }
  double s = 0.999999/amax;
  double s2 = s*s;
  double C[3][3];
  C[0][0]=(PD[5]-dN*mu[0]*mu[0])*s2; C[1][0]=(PD[6]-dN*mu[1]*mu[0])*s2;
  C[2][0]=(PD[7]-dN*mu[2]*mu[0])*s2; C[1][1]=(PD[8]-dN*mu[1]*mu[1])*s2;
  C[2][1]=(PD[9]-dN*mu[2]*mu[1])*s2; C[2][2]=(PD[10]-dN*mu[2]*mu[2])*s2;
  C[0][1]=C[1][0]; C[0][2]=C[2][0]; C[1][2]=C[2][1];
  double w[3], V[3][3];
  eigh3_(C, w, V);
  int bad1 = 0;
  for (int i=0;i<3;++i){ if (badd(w[i])) bad1=1; for (int j=0;j<3;++j) if (badd(V[i][j])) bad1=1; }
  if (bad1){
    DF[0] |= 2;
    for (int i=0;i<3;++i) for (int j=0;j<3;++j) V[i][j] = (i==j) ? 1.0 : 0.0;
  }
  PD[12]=mu[0]; PD[13]=mu[1]; PD[14]=mu[2];
  PD[15]=s;
  for (int i=0;i<3;++i) for (int j=0;j<3;++j) PD[16+i*3+j]=V[i][j];
  double cntf = dN*32.0;
  double mu1 = PD[3]/cntf;
  double var = PD[4]/cntf - mu1*mu1;
  PD[25]=mu1;
  PD[26]=1.0/(sqrt(var>0.0?var:0.0)+1e-5);
}

__global__ void k_buildx(const void* __restrict__ data,
                         const void* __restrict__ ln1w,
                         const void* __restrict__ ln1b,
                         double* __restrict__ PD, float* __restrict__ x, int N){
  int n = blockIdx.x*blockDim.x + threadIdx.x;
  if (n >= N) return;
  int* DF = (int*)(PD + 28);
  int f32 = DF[1];
  size_t rb = (size_t)n*35;
  double s = PD[15];
  double p0 = ((double)ldin(data, rb+0, f32) - PD[12])*s;
  double p1 = ((double)ldin(data, rb+1, f32) - PD[13])*s;
  double p2 = ((double)ldin(data, rb+2, f32) - PD[14])*s;
  float* xr = x + (size_t)n*36;
  int bb = 0;
  for (int j=0;j<3;++j){
    float v = (float)(p0*PD[16+j] + p1*PD[19+j] + p2*PD[22+j]);
    bb |= badf(v);
    xr[j] = v;
  }
  float mu1 = (float)PD[25], rs = (float)PD[26];
  for (int k=0;k<32;++k){
    float v = (ldin(data, rb+3+k, f32) - mu1)*rs*ldin(ln1w, k, f32) + ldin(ln1b, k, f32);
    bb |= badf(v);
    xr[3+k] = v;
  }
  xr[35] = 0.f;
  if (bb) atomicOr(DF, 4);
}

__global__ void k_count(const int* __restrict__ dst, int* __restrict__ cnt, int E){
  int i = blockIdx.x*blockDim.x + threadIdx.x;
  if (i < E) atomicAdd(&cnt[dst[i]], 1);
}

__global__ void k_scan1(const int* __restrict__ cnt, int* __restrict__ bsum, int N){
  int i = blockIdx.x*256 + threadIdx.x;
  int v = (i < N) ? cnt[i] : 0;
  #pragma unroll
  for (int o=32;o>0;o>>=1) v += __shfl_down(v, o);
  __shared__ int s4[4];
  if ((threadIdx.x&63)==0) s4[threadIdx.x>>6]=v;
  __syncthreads();
  if (threadIdx.x==0) bsum[blockIdx.x]=s4[0]+s4[1]+s4[2]+s4[3];
}

__global__ void k_scan2(const int* __restrict__ bsum, int* __restrict__ bpre,
                        int* __restrict__ iptr, int nb, int N){
  if (threadIdx.x != 0 || blockIdx.x != 0) return;
  int run = 0;
  for (int b=0;b<nb;++b){ bpre[b]=run; run += bsum[b]; }
  iptr[N] = run;
}

__global__ void k_scan3(const int* __restrict__ cnt, const int* __restrict__ bpre,
                        int* __restrict__ iptr, int* __restrict__ cur, int N){
  __shared__ int sc[256];
  int i = blockIdx.x*256 + threadIdx.x;
  int t = threadIdx.x;
  int v = (i < N) ? cnt[i] : 0;
  sc[t] = v;
  __syncthreads();
  for (int o=1;o<256;o<<=1){
    int add = (t >= o) ? sc[t-o] : 0;
    __syncthreads();
    sc[t] += add;
    __syncthreads();
  }
  if (i < N){
    int val = bpre[blockIdx.x] + sc[t] - v;
    iptr[i] = val;
    cur[i] = val;
  }
}

// ---- deterministic 3-pass partition (buckets of 512 nodes) ----
// Pass 1: per-block histogram of its contiguous edge chunk.
__global__ void k_hist(const int* __restrict__ dst, int* __restrict__ H,
                       int E, int per, int nb){
  __shared__ int lc[256];
  int blk = blockIdx.x, t = threadIdx.x;
  lc[t] = 0;
  __syncthreads();
  int s = blk*per, e = min(E, s+per);
  for (int i = s+t; i < e; i += 256) atomicAdd(&lc[dst[i] >> 9], 1);
  __syncthreads();
  if (t < nb) H[t*NBLK + blk] = lc[t];
}

// Pass 2: per bucket, exclusive scan across blocks; base = iptr[bucket start].
__global__ void k_xscan(const int* __restrict__ H, const int* __restrict__ iptr,
                        int* __restrict__ offs){
  __shared__ int sc[256];
  int b = blockIdx.x, t = threadIdx.x;
  int v = H[b*NBLK + t];
  sc[t] = v;
  __syncthreads();
  for (int o=1;o<256;o<<=1){
    int add = (t >= o) ? sc[t-o] : 0;
    __syncthreads();
    sc[t] += add;
    __syncthreads();
  }
  offs[b*NBLK + t] = iptr[b << 9] + sc[t] - v;
}

// Pass 3: write each edge to its block-private contiguous range (no atomics
// to global; LDS rank counters only). Entry = src | et<<17 | (dst&511)<<21.
__global__ void k_binA2(const int* __restrict__ src, const int* __restrict__ dst,
                        const int* __restrict__ et, const int* __restrict__ offs,
                        int* __restrict__ stag, int E, int per){
  __shared__ int lc[256];
  int blk = blockIdx.x, t = threadIdx.x;
  lc[t] = 0;
  __syncthreads();
  int s = blk*per, e = min(E, s+per);
  for (int i = s+t; i < e; i += 256){
    int d = dst[i];
    int b = d >> 9;
    int r = atomicAdd(&lc[b], 1);
    stag[offs[b*NBLK + blk] + r] = src[i] | (et[i] << 17) | ((d & 511) << 21);
  }
}

// Pass 4: per 512-node bucket, scatter staged entries to exact CSR positions
// (writes land in the bucket's contiguous L2-resident window).
__global__ void k_binB2(const int* __restrict__ iptr, const int* __restrict__ stag,
                        int* __restrict__ pack, int N){
  __shared__ int lcnt[512];
  int b = blockIdx.x;
  int n0 = b << 9;
  int t = threadIdx.x;
  for (int j = t; j < 512; j += 256){
    int n = n0 + j;
    lcnt[j] = (n < N) ? iptr[n] : 0;
  }
  __syncthreads();
  int segs = iptr[n0];
  int nend = (n0 + 512 < N) ? (n0 + 512) : N;
  int sege = iptr[nend];
  for (int k = segs + t; k < sege; k += 256){
    int e2 = stag[k];
    int pos = atomicAdd(&lcnt[(e2 >> 21) & 511], 1);
    pack[pos] = (e2 & 0x1FFFF) | (((e2 >> 17) & 15) << 20);
  }
}

// fallback for N > 2^17 (src wouldn't fit 17 bits): direct scatter
__global__ void k_scatter(const int* __restrict__ src, const int* __restrict__ dst,
                          const int* __restrict__ et, int* __restrict__ cur,
                          int* __restrict__ pack, int E){
  int i = blockIdx.x*blockDim.x + threadIdx.x;
  if (i < E){
    int d = dst[i];
    int p = atomicAdd(&cur[d], 1);
    pack[p] = src[i] | (et[i] << 20);
  }
}

// Pack B fragments (bf16, MFMA lane layout) for W (per r, kc, tile) and for
// the yq/yk side (u_r = W_r@q, v_r = W_r@k computed inline, hi/lo split).
__global__ void k_fragpack(const void* __restrict__ W, size_t wofs, int F, int KC,
                           const void* __restrict__ qp, const void* __restrict__ kp,
                           size_t qofs,
                           unsigned short* __restrict__ bfr,
                           unsigned short* __restrict__ qkfr,
                           const int* __restrict__ DF){
  int t = blockIdx.x*blockDim.x + threadIdx.x;
  int nB = 15*KC*2*64*8;
  int nQ = 2*2*KC*64*8;
  int f32 = DF[1];
  if (t < nB){
    int j = t & 7; int lane = (t >> 3) & 63; int tile = (t >> 9) & 1; int idx = t >> 10;
    int kc = idx % KC; int r = idx / KC;
    int f = kc*32 + (lane >> 4)*8 + j;
    int o = tile*16 + (lane & 15);
    bfr[t] = (f < F) ? f2bf(ldin(W, wofs + ((size_t)(r*F+f))*32 + o, f32)) : 0;
  } else if (t < nB + nQ){
    int u = t - nB;
    int j = u & 7; int lane = (u >> 3) & 63; int wpk = u >> 9;
    int kc = wpk % KC; int wp = wpk / KC;
    int part = wp & 1; int which = wp >> 1;
    int f = kc*32 + (lane >> 4)*8 + j;
    int rr = lane & 15;
    unsigned short val = 0;
    if (f < F && rr < 15){
      const void* v = which ? kp : qp;
      float acc = 0.f;
      for (int o = 0; o < 32; ++o)
        acc = fmaf(ldin(W, wofs + ((size_t)(rr*F+f))*32 + o, f32), ldin(v, qofs + o, f32), acc);
      unsigned short hi = f2bf(acc);
      val = (part == 0) ? hi : f2bf(acc - bf2f(hi));
    }
    qkfr[u] = val;
  }
}

// MFMA GEMM: per wave, 16 nodes x (15 r x 32 outs + yq/yk). X split hi/lo bf16.
__global__ void __launch_bounds__(256)
k_mf(const float* __restrict__ x, int str, int KC, int N,
     const unsigned short* __restrict__ bfr,
     const unsigned short* __restrict__ qkfr,
     unsigned short* __restrict__ y, float* __restrict__ yq, float* __restrict__ yk){
  int wave = blockIdx.x*(blockDim.x >> 6) + (threadIdx.x >> 6);
  int node0 = wave*16;
  if (node0 >= N) return;
  int lane = threadIdx.x & 63;
  int col = lane & 15, quad = lane >> 4;

  short8 ah[2], al[2];
  #pragma unroll
  for (int kc = 0; kc < 2; ++kc){
    if (kc >= KC) break;
    float xv[8];
    int node = node0 + col;           // A row m = lane&15
    int kbase = kc*32 + quad*8;
    if (node < N && kbase < str){
      const float* xr = x + (size_t)node*str + kbase;
      if (kbase + 8 <= str){
        float4 a = *(const float4*)xr; float4 b = *(const float4*)(xr + 4);
        xv[0]=a.x; xv[1]=a.y; xv[2]=a.z; xv[3]=a.w; xv[4]=b.x; xv[5]=b.y; xv[6]=b.z; xv[7]=b.w;
      } else if (kbase + 4 <= str){
        float4 a = *(const float4*)xr;
        xv[0]=a.x; xv[1]=a.y; xv[2]=a.z; xv[3]=a.w; xv[4]=0.f; xv[5]=0.f; xv[6]=0.f; xv[7]=0.f;
      } else {
        #pragma unroll
        for (int j=0;j<8;++j) xv[j]=0.f;
      }
    } else {
      #pragma unroll
      for (int j=0;j<8;++j) xv[j]=0.f;
    }
    #pragma unroll
    for (int j=0;j<8;++j){
      unsigned short hi = f2bf(xv[j]);
      ah[kc][j] = (short)hi;
      al[kc][j] = (short)f2bf(xv[j] - bf2f(hi));
    }
  }

  const short8* B  = (const short8*)bfr;
  const short8* QK = (const short8*)qkfr;

  // yq / yk tiles (cols = r), B-side hi/lo split too
  f32x4 aq = {0.f,0.f,0.f,0.f}, ak2 = {0.f,0.f,0.f,0.f};
  for (int kc = 0; kc < KC; ++kc){
    short8 qh = QK[((0*KC) + kc)*64 + lane];        // which=0 part=0
    short8 ql = QK[((1*KC) + kc)*64 + lane];        // which=0 part=1
    short8 kh = QK[((2*KC) + kc)*64 + lane];        // which=1 part=0
    short8 kl = QK[((3*KC) + kc)*64 + lane];        // which=1 part=1
    aq = mfma16(ah[kc], qh, aq);
    aq = mfma16(al[kc], qh, aq);
    aq = mfma16(ah[kc], ql, aq);
    ak2 = mfma16(ah[kc], kh, ak2);
    ak2 = mfma16(al[kc], kh, ak2);
    ak2 = mfma16(ah[kc], kl, ak2);
  }
  #pragma unroll
  for (int j = 0; j < 4; ++j){
    int node = node0 + quad*4 + j;
    if (node < N){
      yq[(size_t)node*16 + col] = aq[j];
      yk[(size_t)node*16 + col] = ak2[j];
    }
  }

  // y tiles per relation
  for (int r = 0; r < 15; ++r){
    f32x4 a0 = {0.f,0.f,0.f,0.f}, a1 = {0.f,0.f,0.f,0.f};
    for (int kc = 0; kc < KC; ++kc){
      short8 b0 = B[(((size_t)(r*KC + kc))*2 + 0)*64 + lane];
      short8 b1 = B[(((size_t)(r*KC + kc))*2 + 1)*64 + lane];
      a0 = mfma16(ah[kc], b0, a0);
      a0 = mfma16(al[kc], b0, a0);
      a1 = mfma16(ah[kc], b1, a1);
      a1 = mfma16(al[kc], b1, a1);
    }
    #pragma unroll
    for (int j = 0; j < 4; ++j){
      int node = node0 + quad*4 + j;
      if (node < N){
        unsigned short* yp = &y[(((size_t)r*N + node))*32 + col];
        yp[0]  = f2bf(a0[j]);
        yp[16] = f2bf(a1[j]);
      }
    }
  }
}

// softmax + aggregation. deg<=64 fast path (scalars, no spill), 8x-unrolled
// gather. Per-block stats -> partials[] (plain store); k_stat reduces them.
__global__ void k_main(const int* __restrict__ iptr, const int* __restrict__ pack,
                       const float* __restrict__ yq, const float* __restrict__ yk,
                       const unsigned short* __restrict__ y,
                       const void* __restrict__ biasp, size_t bofs,
                       const float* __restrict__ xres, float* __restrict__ hpre,
                       double* __restrict__ partials, int* __restrict__ DF, int N){
  __shared__ double sdb[4][2];
  int gt = blockIdx.x*blockDim.x + threadIdx.x;
  int node = gt >> 6, lane = gt & 63;
  int wid = threadIdx.x >> 6;
  int f32 = DF[1];
  int o = lane & 31;
  bool active = (node < N);
  float hp = 0.f;

  if (active){
    int start = iptr[node];
    int deg = iptr[node+1] - start;
    const float* yqn = yq + (size_t)node*16;
    float acc = 0.f;
    float ssum = 0.f;

    if (deg <= 64){
      // ---- fast path: one chunk in scalars ----
      int pe = 0; float a = -INFINITY;
      if (lane < deg){
        pe = pack[start+lane];
        int sr = pe & 0xFFFFF, et = pe >> 20;
        a = yqn[et] + yk[(size_t)sr*16+et];
        a = (a >= 0.f) ? a : 0.2f*a;
      }
      float amax = a;
      #pragma unroll
      for (int o2=32;o2>0;o2>>=1) amax = fmaxf(amax, __shfl_xor(amax, o2));
      float ev = (lane < deg) ? expf(a - amax) : 0.f;
      ssum = ev;
      int sub = lane >> 5;
      for (; sub + 14 < deg; sub += 16){
        float w0 = __shfl(ev, sub),    w1 = __shfl(ev, sub+2);
        float w2 = __shfl(ev, sub+4),  w3 = __shfl(ev, sub+6);
        float w4 = __shfl(ev, sub+8),  w5 = __shfl(ev, sub+10);
        float w6 = __shfl(ev, sub+12), w7 = __shfl(ev, sub+14);
        int   p0 = __shfl(pe, sub),    p1 = __shfl(pe, sub+2);
        int   p2 = __shfl(pe, sub+4),  p3 = __shfl(pe, sub+6);
        int   p4 = __shfl(pe, sub+8),  p5 = __shfl(pe, sub+10);
        int   p6 = __shfl(pe, sub+12), p7 = __shfl(pe, sub+14);
        float v0 = bf2f(y[((size_t)(p0 >> 20)*N + (p0 & 0xFFFFF))*32 + o]);
        float v1 = bf2f(y[((size_t)(p1 >> 20)*N + (p1 & 0xFFFFF))*32 + o]);
        float v2 = bf2f(y[((size_t)(p2 >> 20)*N + (p2 & 0xFFFFF))*32 + o]);
        float v3 = bf2f(y[((size_t)(p3 >> 20)*N + (p3 & 0xFFFFF))*32 + o]);
        float v4 = bf2f(y[((size_t)(p4 >> 20)*N + (p4 & 0xFFFFF))*32 + o]);
        float v5 = bf2f(y[((size_t)(p5 >> 20)*N + (p5 & 0xFFFFF))*32 + o]);
        float v6 = bf2f(y[((size_t)(p6 >> 20)*N + (p6 & 0xFFFFF))*32 + o]);
        float v7 = bf2f(y[((size_t)(p7 >> 20)*N + (p7 & 0xFFFFF))*32 + o]);
        acc = fmaf(w0, v0, acc); acc = fmaf(w1, v1, acc);
        acc = fmaf(w2, v2, acc); acc = fmaf(w3, v3, acc);
        acc = fmaf(w4, v4, acc); acc = fmaf(w5, v5, acc);
        acc = fmaf(w6, v6, acc); acc = fmaf(w7, v7, acc);
      }
      for (; sub + 6 < deg; sub += 8){
        float w0 = __shfl(ev, sub),   w1 = __shfl(ev, sub+2);
        float w2 = __shfl(ev, sub+4), w3 = __shfl(ev, sub+6);
        int   p0 = __shfl(pe, sub),   p1 = __shfl(pe, sub+2);
        int   p2 = __shfl(pe, sub+4), p3 = __shfl(pe, sub+6);
        float v0 = bf2f(y[((size_t)(p0 >> 20)*N + (p0 & 0xFFFFF))*32 + o]);
        float v1 = bf2f(y[((size_t)(p1 >> 20)*N + (p1 & 0xFFFFF))*32 + o]);
        float v2 = bf2f(y[((size_t)(p2 >> 20)*N + (p2 & 0xFFFFF))*32 + o]);
        float v3 = bf2f(y[((size_t)(p3 >> 20)*N + (p3 & 0xFFFFF))*32 + o]);
        acc = fmaf(w0, v0, acc); acc = fmaf(w1, v1, acc);
        acc = fmaf(w2, v2, acc); acc = fmaf(w3, v3, acc);
      }
      for (; sub < deg; sub += 2){
        float wgt = __shfl(ev, sub);
        int pb = __shfl(pe, sub);
        acc = fmaf(wgt, bf2f(y[((size_t)(pb >> 20)*N + (pb & 0xFFFFF))*32 + o]), acc);
      }
    } else {
      // ---- slow path: two-pass recompute (rare: deg>64) ----
      float amax = -INFINITY;
      for (int k = lane; k < deg; k += 64){
        int pe = pack[start+k];
        int sr = pe & 0xFFFFF, et = pe >> 20;
        float a = yqn[et] + yk[(size_t)sr*16+et];
        a = (a >= 0.f) ? a : 0.2f*a;
        amax = fmaxf(amax, a);
      }
      #pragma unroll
      for (int o2=32;o2>0;o2>>=1) amax = fmaxf(amax, __shfl_xor(amax, o2));
      for (int c = 0; c < deg; c += 64){
        int k = c + lane;
        float ev = 0.f; int pe = 0;
        if (k < deg){
          pe = pack[start+k];
          int sr = pe & 0xFFFFF, et = pe >> 20;
          float a = yqn[et] + yk[(size_t)sr*16+et];
          a = (a >= 0.f) ? a : 0.2f*a;
          ev = expf(a - amax);
          ssum += ev;
        }
        int lim = min(64, deg - c);
        int sub = lane >> 5;
        for (; sub + 6 < lim; sub += 8){
          float w0 = __shfl(ev, sub),   w1 = __shfl(ev, sub+2);
          float w2 = __shfl(ev, sub+4), w3 = __shfl(ev, sub+6);
          int   p0 = __shfl(pe, sub),   p1 = __shfl(pe, sub+2);
          int   p2 = __shfl(pe, sub+4), p3 = __shfl(pe, sub+6);
          float v0 = bf2f(y[((size_t)(p0 >> 20)*N + (p0 & 0xFFFFF))*32 + o]);
          float v1 = bf2f(y[((size_t)(p1 >> 20)*N + (p1 & 0xFFFFF))*32 + o]);
          float v2 = bf2f(y[((size_t)(p2 >> 20)*N + (p2 & 0xFFFFF))*32 + o]);
          float v3 = bf2f(y[((size_t)(p3 >> 20)*N + (p3 & 0xFFFFF))*32 + o]);
          acc = fmaf(w0, v0, acc);
          acc = fmaf(w1, v1, acc);
          acc = fmaf(w2, v2, acc);
          acc = fmaf(w3, v3, acc);
        }
        for (; sub < lim; sub += 2){
          float wgt = __shfl(ev, sub);
          int pb = __shfl(pe, sub);
          acc = fmaf(wgt, bf2f(y[((size_t)(pb >> 20)*N + (pb & 0xFFFFF))*32 + o]), acc);
        }
      }
    }
    #pragma unroll
    for (int o2=32;o2>0;o2>>=1) ssum += __shfl_xor(ssum, o2);
    float inv = 1.f/(ssum + 1e-16f);
    acc *= inv;
    acc += __shfl_xor(acc, 32);

    if (lane < 32){
      hp = acc + ldin(biasp, bofs + o, f32);
      if (xres) hp += xres[(size_t)node*32 + o];
      if (badf(hp)) atomicOr(DF, 32);
      hpre[(size_t)node*32 + o] = hp;
    }
  }

  // block-level LN stats -> plain store to partials (no fence, no atomics)
  float s1 = (active && lane < 32) ? hp : 0.f;
  float s2 = s1*s1;
  #pragma unroll
  for (int o2=32;o2>0;o2>>=1){ s1 += __shfl_xor(s1,o2); s2 += __shfl_xor(s2,o2); }
  if (lane == 0){ sdb[wid][0] = (double)s1; sdb[wid][1] = (double)s2; }
  __syncthreads();
  if (threadIdx.x == 0){
    partials[(size_t)blockIdx.x*2]   = sdb[0][0]+sdb[1][0]+sdb[2][0]+sdb[3][0];
    partials[(size_t)blockIdx.x*2+1] = sdb[0][1]+sdb[1][1]+sdb[2][1]+sdb[3][1];
  }
}

__global__ void k_stat(const double* __restrict__ partials, int nb,
                       double* __restrict__ PD, int l){
  double t1 = 0.0, t2 = 0.0;
  for (int i = threadIdx.x; i < nb; i += 256){
    t1 += partials[(size_t)i*2];
    t2 += partials[(size_t)i*2+1];
  }
  t1 = wsum_d(t1); t2 = wsum_d(t2);
  __shared__ double sd[8];
  int w = threadIdx.x >> 6;
  if ((threadIdx.x & 63) == 0){ sd[w*2] = t1; sd[w*2+1] = t2; }
  __syncthreads();
  if (threadIdx.x == 0){
    PD[32+2*l]   = sd[0]+sd[2]+sd[4]+sd[6];
    PD[32+2*l+1] = sd[1]+sd[3]+sd[5]+sd[7];
  }
}

__global__ void k_ln(float* __restrict__ h, const void* __restrict__ lnw,
                     const void* __restrict__ lnb, size_t lofs,
                     double* __restrict__ PD, int l, int N){
  int idx = blockIdx.x*blockDim.x + threadIdx.x;
  if (idx >= N*32) return;
  int* DF = (int*)(PD + 28);
  int f32 = DF[1];
  const double* stats = PD + 32 + 2*l;
  int o = idx & 31;
  double cntf = (double)N*32.0;
  double mu = stats[0]/cntf;
  double var = stats[1]/cntf - mu*mu;
  float rstd = (float)(1.0/(sqrt(var>0.0?var:0.0) + 1e-5));
  float v = (h[idx] - (float)mu)*rstd*ldin(lnw, lofs + o, f32) + ldin(lnb, lofs + o, f32);
  v = v / (1.f + expf(-v));
  if (badf(v)) atomicOr(DF, 64);
  h[idx] = v;
}

__global__ void k_pool(const float* __restrict__ h, double* __restrict__ PD, int N){
  __shared__ float sp[8][33];
  int t = threadIdx.x, o = t & 31, g = t >> 5;
  int r0 = blockIdx.x*256;
  float s = 0.f;
  for (int r = r0 + g; r < N && r < r0 + 256; r += 8) s += h[(size_t)r*32 + o];
  sp[g][o] = s;
  __syncthreads();
  if (t < 32){
    float tot = 0.f;
    #pragma unroll
    for (int g2=0; g2<8; ++g2) tot += sp[g2][t];
    atomicAdd(&PD[40 + t], (double)tot);
  }
}

__global__ void k_out(double* __restrict__ PD, const void* __restrict__ Wl,
                      const void* __restrict__ bl, void* __restrict__ out, int N, int H2){
  int j = blockIdx.x*blockDim.x + threadIdx.x;
  if (j >= H2) return;
  int* DF = (int*)(PD + 28);
  int f32 = DF[1];
  int flag = DF[0];
  const double* pool = PD + 40;
  float acc = ldin(bl, j, f32);
  for (int o=0;o<32;++o)
    acc = fmaf((float)(pool[o]/(double)N), ldin(Wl, (size_t)j*32+o, f32), acc);
  if (badf(acc)) flag |= 128;
  float v = acc / (1.f + expf(-acc));
  if (flag) v = (float)flag;   // diagnostic: absmax == stage bitmask
  if (f32) ((float*)out)[j] = v;
  else     ((unsigned short*)out)[j] = f2bf(v);
}

__global__ void k_diag(unsigned short* out, float val, int H2){
  int j = blockIdx.x*blockDim.x + threadIdx.x;
  if (j < H2) out[j] = f2bf(val);
}

// ---------------- entry ----------------
extern "C" void kernel_launch(void* const* d_in, const int* in_sizes, int n_in,
                              void* d_out, int out_size, void* d_ws, size_t ws_size,
                              hipStream_t stream)
{
  const int N  = in_sizes[0] / 35;
  const int E  = in_sizes[3];
  const int R  = 15;
  const int H2 = in_sizes[19];

  const void* data = d_in[0];
  const int* ei  = (const int*)d_in[2];
  const int* etp = (const int*)d_in[3];
  const void* W0  = d_in[6];
  const void* q0  = d_in[7];
  const void* k0  = d_in[8];
  const void* b0  = d_in[9];
  const void* Wsp = d_in[10];
  const void* qsp = d_in[11];
  const void* ksp = d_in[12];
  const void* bsp = d_in[13];
  const void* lnw = d_in[14];
  const void* lnb = d_in[15];
  const void* ln1w= d_in[16];
  const void* ln1b= d_in[17];
  const void* l1W = d_in[18];
  const void* l1b = d_in[19];

  char* base = (char*)d_ws;
  size_t off = 0;
  auto A = [&](size_t nb)->size_t { size_t c = off; off += (nb + 255) & ~(size_t)255; return c; };
  size_t oPD  = A(1024);
  size_t oCnt = A((size_t)N*4);
  size_t oPtr = A(((size_t)N+1)*4);
  size_t oCur = A((size_t)N*4);
  size_t oBs  = A(4096);
  size_t oBp  = A(4096);
  size_t oPk  = A((size_t)E*4);
  size_t oSt  = A((size_t)E*4);
  size_t oHh  = A((size_t)256*NBLK*4);
  size_t oOf  = A((size_t)256*NBLK*4);
  size_t oX   = A((size_t)N*36*4);
  size_t oH0  = A((size_t)N*32*4);
  size_t oH1  = A((size_t)N*32*4);
  size_t oYq  = A((size_t)N*16*4);
  size_t oYk  = A((size_t)N*16*4);
  size_t oBf  = A((size_t)15*2*2*64*8*2);
  size_t oQk  = A((size_t)2*2*2*64*8*2);
  int nbMain  = (int)(((size_t)N*64 + 255)/256);
  size_t oPt  = A((size_t)nbMain*2*8);
  size_t oY   = off;
  size_t needB = oY + (size_t)R*N*32*2;

  double* PD  = (double*)(base + oPD);
  int* DF     = (int*)(PD + 28);
  int* cnt    = (int*)(base + oCnt);
  int* iptr   = (int*)(base + oPtr);
  int* cur    = (int*)(base + oCur);
  int* bsum   = (int*)(base + oBs);
  int* bpre   = (int*)(base + oBp);
  int* pack   = (int*)(base + oPk);
  int* stag   = (int*)(base + oSt);
  int* Hh     = (int*)(base + oHh);
  int* offs   = (int*)(base + oOf);
  float* xb   = (float*)(base + oX);
  float* h0   = (float*)(base + oH0);
  float* h1   = (float*)(base + oH1);
  float* yqb  = (float*)(base + oYq);
  float* ykb  = (float*)(base + oYk);
  unsigned short* bfr  = (unsigned short*)(base + oBf);
  unsigned short* qkfr = (unsigned short*)(base + oQk);
  double* partials = (double*)(base + oPt);
  unsigned short* y = (unsigned short*)(base + oY);

  if (ws_size < needB){
    k_diag<<<1, 256, 0, stream>>>((unsigned short*)d_out, (float)(ws_size >> 20), H2);
    return;
  }

  // zero PD + cnt ( [0, oPtr) covers both exactly )
  hipMemsetAsync(base, 0, oPtr, stream);

  int nbN = (N + 255)/256;
  int nbE = (E + 255)/256;
  int nus = (in_sizes[0] < 1024) ? in_sizes[0] : 1024;

  k_dtype<<<1, 256, 0, stream>>>((const unsigned short*)data, nus, PD);
  k_red1<<<nbN, 256, 0, stream>>>(data, N, PD);
  k_eig<<<1, 1, 0, stream>>>(PD, N);
  k_buildx<<<nbN, 256, 0, stream>>>(data, ln1w, ln1b, PD, xb, N);

  k_count<<<nbE, 256, 0, stream>>>(ei + E, cnt, E);
  k_scan1<<<nbN, 256, 0, stream>>>(cnt, bsum, N);
  k_scan2<<<1, 1, 0, stream>>>(bsum, bpre, iptr, nbN, N);
  k_scan3<<<nbN, 256, 0, stream>>>(cnt, bpre, iptr, cur, N);

  if (N <= (1 << 17)){
    int nbkt = (N + 511) >> 9;           // <= 256
    int per  = (E + NBLK - 1) / NBLK;
    k_hist<<<NBLK, 256, 0, stream>>>(ei + E, Hh, E, per, nbkt);
    k_xscan<<<nbkt, 256, 0, stream>>>(Hh, iptr, offs);
    k_binA2<<<NBLK, 256, 0, stream>>>(ei, ei + E, etp, offs, stag, E, per);
    k_binB2<<<nbkt, 256, 0, stream>>>(iptr, stag, pack, N);
  } else {
    k_scatter<<<nbE, 256, 0, stream>>>(ei, ei + E, etp, cur, pack, E);
  }

  int nbMf = (int)(((N + 15)/16 + 3)/4);
  for (int l=0; l<4; ++l){
    const void* W  = (l==0)? W0 : Wsp;  size_t wofs = (l==0)? 0 : (size_t)(l-1)*R*32*32;
    const void* qp = (l==0)? q0 : qsp;  size_t qofs = (l==0)? 0 : (size_t)(l-1)*32;
    const void* kp = (l==0)? k0 : ksp;
    const void* bp = (l==0)? b0 : bsp;  size_t bofs = qofs;
    int str = (l==0)? 36 : 32;
    int KC = (l==0)? 2 : 1;
    int F = (l==0)? 35 : 32;
    const float* xin = (l==0)? xb : ((l%2==0)? h1 : h0);
    float* hout = (l%2==0)? h0 : h1;
    int nFrag = 15*KC*2*64*8 + 2*2*KC*64*8;
    k_fragpack<<<(nFrag+255)/256, 256, 0, stream>>>(W, wofs, F, KC, qp, kp, qofs, bfr, qkfr, DF);
    k_mf<<<nbMf, 256, 0, stream>>>(xin, str, KC, N, bfr, qkfr, y, yqb, ykb);
    k_main<<<nbMain, 256, 0, stream>>>(iptr, pack, yqb, ykb, y, bp, bofs,
                 (l==0)? (const float*)nullptr : xin, hout, partials, DF, N);
    k_stat<<<1, 256, 0, stream>>>(partials, nbMain, PD, l);
    k_ln<<<(N*32+255)/256, 256, 0, stream>>>(hout, lnw, lnb, (size_t)l*32, PD, l, N);
  }

  k_pool<<<nbN, 256, 0, stream>>>(h1, PD, N);
  k_out<<<(H2+255)/256, 256, 0, stream>>>(PD, l1W, l1b, d_out, N, H2);
}

// Round 11
// 1344.583 us; speedup vs baseline: 3.4225x; 1.0490x over previous
//
#include <hip/hip_runtime.h>
#include <math.h>
#include <stdint.h>

#define NBLK 256

// ---------------- helpers ----------------
__device__ inline float bf2f(unsigned short u){
  union { unsigned int i; float f; } x; x.i = ((unsigned int)u) << 16; return x.f;
}
__device__ inline unsigned short f2bf(float f){
  union { float f; unsigned int i; } x; x.f = f;
  unsigned int u = x.i;
  return (unsigned short)((u + 0x7FFFu + ((u >> 16) & 1u)) >> 16);
}
// dtype-dispatched input load: f32 flag comes from device-side probe
__device__ inline float ldin(const void* p, size_t i, int f32){
  return f32 ? ((const float*)p)[i] : bf2f(((const unsigned short*)p)[i]);
}

__device__ inline int badf(float v){ return !(fabsf(v) <= 3.0e38f); }
__device__ inline int badd(double v){ return !(fabs(v) <= 1.0e300); }

__device__ inline double wsum_d(double v){
  #pragma unroll
  for (int o = 32; o > 0; o >>= 1) v += __shfl_down(v, o);
  return v;
}
__device__ inline double wmax_d(double v){
  #pragma unroll
  for (int o = 32; o > 0; o >>= 1) v = fmax(v, __shfl_down(v, o));
  return v;
}
__device__ inline void atomicMaxD(double* addr, double v){ // v >= 0
  atomicMax((unsigned long long*)addr, (unsigned long long)__double_as_longlong(v));
}

// MFMA types
typedef __attribute__((ext_vector_type(8))) short short8;
typedef __attribute__((ext_vector_type(4))) float f32x4;
__device__ inline f32x4 mfma16(short8 a, short8 b, f32x4 c){
  return __builtin_amdgcn_mfma_f32_16x16x32_bf16(a, b, c, 0, 0, 0);
}

// ---------------- LAPACK 3x3 eigh port (dsytd2 + dsteqr + dormtr) ----------------
__device__ inline double d_sign(double a, double b){ return (b >= 0.0) ? fabs(a) : -fabs(a); }
__device__ inline double dlapy2_(double x, double y){ return sqrt(x*x + y*y); }

__device__ void dlartg_(double f, double g, double* cs, double* sn, double* r){
  // LAPACK >= 3.10 convention: c >= 0, r = sign(d, f)
  if (g == 0.0){ *cs = 1.0; *sn = 0.0; *r = f; }
  else if (f == 0.0){ *cs = 0.0; *sn = (g >= 0.0) ? 1.0 : -1.0; *r = fabs(g); }
  else {
    double d = sqrt(f*f + g*g);
    *cs = fabs(f)/d;
    *r  = d_sign(d, f);
    *sn = g / (*r);
  }
}

__device__ void dlaev2_(double a, double b, double c, double* rt1, double* rt2,
                        double* cs1, double* sn1){
  double sm = a + c, df = a - c, adf = fabs(df), tb = b + b, ab = fabs(tb);
  double acmx, acmn;
  if (fabs(a) > fabs(c)){ acmx = a; acmn = c; } else { acmx = c; acmn = a; }
  double rt;
  if (adf > ab) rt = adf*sqrt(1.0 + (ab/adf)*(ab/adf));
  else if (adf < ab) rt = ab*sqrt(1.0 + (adf/ab)*(adf/ab));
  else rt = ab*sqrt(2.0);
  int sgn1;
  if (sm < 0.0){ *rt1 = 0.5*(sm - rt); sgn1 = -1; *rt2 = (acmx/(*rt1))*acmn - (b/(*rt1))*b; }
  else if (sm > 0.0){ *rt1 = 0.5*(sm + rt); sgn1 = 1; *rt2 = (acmx/(*rt1))*acmn - (b/(*rt1))*b; }
  else { *rt1 = 0.5*rt; *rt2 = -0.5*rt; sgn1 = 1; }
  int sgn2; double cs;
  if (df >= 0.0){ cs = df + rt; sgn2 = 1; } else { cs = df - rt; sgn2 = -1; }
  double acs = fabs(cs);
  if (acs > ab){ double ct = -tb/cs; *sn1 = 1.0/sqrt(1.0+ct*ct); *cs1 = ct*(*sn1); }
  else {
    if (ab == 0.0){ *cs1 = 1.0; *sn1 = 0.0; }
    else { double tn = -cs/tb; *cs1 = 1.0/sqrt(1.0+tn*tn); *sn1 = tn*(*cs1); }
  }
  if (sgn1 == sgn2){ double tn = *cs1; *cs1 = -(*sn1); *sn1 = tn; }
}

__device__ void dsteqr3_(double* dd, double* ee, double z[3][3]){
  #define D_(i) dd[(i)-1]
  #define E_(i) ee[(i)-1]
  #define Z_(i,j) z[(i)-1][(j)-1]
  #define CW_(i) cw[(i)-1]
  #define SW_(i) sw[(i)-1]
  const int n = 3;
  const double eps = 1.1102230246251565e-16;
  const double eps2 = eps*eps;
  const double safmin = 2.2250738585072014e-308;
  const int nmaxit = n*30;
  double cw[3], sw[3];
  int jtot = 0;
  int l1 = 1, l, m, lsv, lend, lendsv;
  double p, g, r, c, s, f, b, rt1, rt2, anorm, tst;

L10:
  if (l1 > n) goto L160;
  if (l1 > 1) E_(l1-1) = 0.0;
  if (l1 <= n-1){
    for (m = l1; m <= n-1; ++m){
      tst = fabs(E_(m));
      if (tst == 0.0) goto L30;
      if (tst <= (sqrt(fabs(D_(m)))*sqrt(fabs(D_(m+1))))*eps){ E_(m) = 0.0; goto L30; }
    }
  }
  m = n;
L30:
  l = l1; lsv = l; lend = m; lendsv = lend; l1 = m+1;
  if (lend == l) goto L10;
  anorm = 0.0;
  for (int i = l; i <= lend; ++i) anorm = fmax(anorm, fabs(D_(i)));
  for (int i = l; i <= lend-1; ++i) anorm = fmax(anorm, fabs(E_(i)));
  if (anorm == 0.0) goto L10;
  if (fabs(D_(lend)) < fabs(D_(l))){ lend = lsv; l = lendsv; }
  if (lend > l) goto L40; else goto L90;

  // -------- QL iteration --------
L40:
  if (l != lend){
    for (m = l; m <= lend-1; ++m){
      tst = fabs(E_(m)); tst = tst*tst;
      if (tst <= (eps2*fabs(D_(m)))*fabs(D_(m+1)) + safmin) goto L60;
    }
  }
  m = lend;
L60:
  if (m < lend) E_(m) = 0.0;
  p = D_(l);
  if (m == l) goto L80;
  if (m == l+1){
    dlaev2_(D_(l), E_(l), D_(l+1), &rt1, &rt2, &c, &s);
    CW_(l) = c; SW_(l) = s;
    { double ct = CW_(l), st = SW_(l);
      if (ct != 1.0 || st != 0.0)
        for (int i = 1; i <= n; ++i){
          double t = Z_(i, l+1);
          Z_(i, l+1) = ct*t - st*Z_(i, l);
          Z_(i, l)   = st*t + ct*Z_(i, l);
        }
    }
    D_(l) = rt1; D_(l+1) = rt2; E_(l) = 0.0;
    l += 2;
    if (l <= lend) goto L40;
    goto L140;
  }
  if (jtot == nmaxit) goto L140;
  jtot++;
  g = (D_(l+1) - p)/(2.0*E_(l));
  r = dlapy2_(g, 1.0);
  g = D_(m) - p + E_(l)/(g + d_sign(r, g));
  s = 1.0; c = 1.0; p = 0.0;
  for (int i = m-1; i >= l; --i){
    f = s*E_(i); b = c*E_(i);
    dlartg_(g, f, &c, &s, &r);
    if (i != m-1) E_(i+1) = r;
    g = D_(i+1) - p;
    r = (D_(i) - g)*s + 2.0*c*b;
    p = s*r;
    D_(i+1) = g + p;
    g = c*r - b;
    CW_(i) = c; SW_(i) = -s;
  }
  { int mm = m - l + 1;
    for (int j = mm-1; j >= 1; --j){
      double ct = CW_(l+j-1), st = SW_(l+j-1);
      if (ct != 1.0 || st != 0.0)
        for (int i = 1; i <= n; ++i){
          double t = Z_(i, l+j);
          Z_(i, l+j)   = ct*t - st*Z_(i, l+j-1);
          Z_(i, l+j-1) = st*t + ct*Z_(i, l+j-1);
        }
    }
  }
  D_(l) = D_(l) - p;
  E_(l) = g;
  goto L40;
L80:
  D_(l) = p;
  l++;
  if (l <= lend) goto L40;
  goto L140;

  // -------- QR iteration --------
L90:
  if (l != lend){
    for (m = l; m >= lend+1; --m){
      tst = fabs(E_(m-1)); tst = tst*tst;
      if (tst <= (eps2*fabs(D_(m)))*fabs(D_(m-1)) + safmin) goto L110;
    }
  }
  m = lend;
L110:
  if (m > lend) E_(m-1) = 0.0;
  p = D_(l);
  if (m == l) goto L130;
  if (m == l-1){
    dlaev2_(D_(l-1), E_(l-1), D_(l), &rt1, &rt2, &c, &s);
    CW_(m) = c; SW_(m) = s;
    { double ct = CW_(m), st = SW_(m);
      if (ct != 1.0 || st != 0.0)
        for (int i = 1; i <= n; ++i){
          double t = Z_(i, l);
          Z_(i, l)   = ct*t - st*Z_(i, l-1);
          Z_(i, l-1) = st*t + ct*Z_(i, l-1);
        }
    }
    D_(l-1) = rt1; D_(l) = rt2; E_(l-1) = 0.0;
    l -= 2;
    if (l >= lend) goto L90;
    goto L140;
  }
  if (jtot == nmaxit) goto L140;
  jtot++;
  g = (D_(l-1) - p)/(2.0*E_(l-1));
  r = dlapy2_(g, 1.0);
  g = D_(m) - p + E_(l-1)/(g + d_sign(r, g));
  s = 1.0; c = 1.0; p = 0.0;
  for (int i = m; i <= l-1; ++i){
    f = s*E_(i); b = c*E_(i);
    dlartg_(g, f, &c, &s, &r);
    if (i != m) E_(i-1) = r;
    g = D_(i) - p;
    r = (D_(i+1) - g)*s + 2.0*c*b;
    p = s*r;
    D_(i) = g + p;
    g = c*r - b;
    CW_(i) = c; SW_(i) = s;
  }
  { int mm = l - m + 1;
    for (int j = 1; j <= mm-1; ++j){
      double ct = CW_(m+j-1), st = SW_(m+j-1);
      if (ct != 1.0 || st != 0.0)
        for (int i = 1; i <= n; ++i){
          double t = Z_(i, m+j);
          Z_(i, m+j)   = ct*t - st*Z_(i, m+j-1);
          Z_(i, m+j-1) = st*t + ct*Z_(i, m+j-1);
        }
    }
  }
  D_(l) = D_(l) - p;
  E_(l-1) = g;
  goto L90;
L130:
  D_(l) = p;
  l--;
  if (l >= lend) goto L90;
  goto L140;

L140:
  if (jtot < nmaxit) goto L10;
  goto L190;

L160:
  for (int ii = 2; ii <= n; ++ii){
    int i = ii-1, k = i;
    p = D_(i);
    for (int j = ii; j <= n; ++j) if (D_(j) < p){ k = j; p = D_(j); }
    if (k != i){
      D_(k) = D_(i); D_(i) = p;
      for (int rr = 1; rr <= n; ++rr){ double t = Z_(rr,i); Z_(rr,i) = Z_(rr,k); Z_(rr,k) = t; }
    }
  }
L190:
  ;
  #undef D_
  #undef E_
  #undef Z_
  #undef CW_
  #undef SW_
}

__device__ void eigh3_(const double C[3][3], double w[3], double v[3][3]){
  double a00=C[0][0], a10=C[1][0], a20=C[2][0], a11=C[1][1], a21=C[2][1], a22=C[2][2];
  double dd[3], ee[2], tau, v2;
  double alpha = a10, x = a20;
  double xnorm = fabs(x);
  if (xnorm == 0.0){ tau = 0.0; v2 = 0.0; ee[0] = alpha; }
  else {
    double beta = -d_sign(dlapy2_(alpha, xnorm), alpha);
    tau = (beta - alpha)/beta;
    v2 = x/(alpha - beta);
    ee[0] = beta;
  }
  if (tau != 0.0){
    double w0 = tau*(a11 + a21*v2);
    double w1 = tau*(a21 + a22*v2);
    double wv = w0 + w1*v2;
    double ac = -0.5*tau*wv;
    w0 += ac; w1 += ac*v2;
    a11 = a11 - 2.0*w0;
    a21 = a21 - (v2*w0 + w1);
    a22 = a22 - 2.0*v2*w1;
  }
  dd[0]=a00; dd[1]=a11; dd[2]=a22; ee[1]=a21;
  double z[3][3] = {{1,0,0},{0,1,0},{0,0,1}};
  dsteqr3_(dd, ee, z);
  for (int j = 0; j < 3; ++j){
    double t = z[1][j] + v2*z[2][j];
    z[1][j] -= tau*t;
    z[2][j] -= tau*t*v2;
  }
  for (int i=0;i<3;++i){ w[i]=dd[i]; for(int j=0;j<3;++j) v[i][j]=z[i][j]; }
}

// ---------------- kernels ----------------
// PD layout (doubles): 0-2 possum, 3 fsum, 4 fsumsq, 5-10 raw pos moments
// (m00,m10,m20,m11,m21,m22), 12-14 mean, 15 scale, 16-24 V, 25 mu1, 26 rstd1,
// 28: int flag + int isf32, 32+2l per-layer LN stats, 40-71 pool,
// 72-74 max(64+p), 75-77 max(64-p)

__global__ void k_dtype(const unsigned short* __restrict__ data, int nus, double* PD){
  int* DF = (int*)(PD + 28);
  int t = threadIdx.x;
  int bad = 0;
  for (int i = t; i < nus; i += 256){
    int e = (data[i] >> 7) & 0xFF;
    if (e > 0x90 || (e && e < 0x60)) bad++;
  }
  #pragma unroll
  for (int o = 32; o > 0; o >>= 1) bad += __shfl_down(bad, o);
  __shared__ int sb[4];
  if ((t & 63) == 0) sb[t >> 6] = bad;
  __syncthreads();
  if (t == 0) DF[1] = ((sb[0]+sb[1]+sb[2]+sb[3]) > nus/16) ? 1 : 0;
}

// single pass: pos sums, raw second moments, min/max (as max(64±p)), feat sums
// single __syncthreads: all 17 wave-reductions staged in one LDS round.
__global__ void k_red1(const void* __restrict__ data, int N, double* PD){
  int n = blockIdx.x*blockDim.x + threadIdx.x;
  const int* DF = (const int*)(PD + 28);
  int f32 = DF[1];
  double v11[11] = {0,0,0,0,0,0,0,0,0,0,0};
  double m6[6] = {0,0,0,0,0,0};
  if (n < N){
    size_t rb = (size_t)n*35;
    double p0 = ldin(data, rb+0, f32);
    double p1 = ldin(data, rb+1, f32);
    double p2 = ldin(data, rb+2, f32);
    v11[0]=p0; v11[1]=p1; v11[2]=p2;
    double fs=0, fss=0;
    for (int k=3;k<35;++k){ double v = ldin(data, rb+k, f32); fs += v; fss += v*v; }
    v11[3]=fs; v11[4]=fss;
    v11[5]=p0*p0; v11[6]=p1*p0; v11[7]=p2*p0; v11[8]=p1*p1; v11[9]=p2*p1; v11[10]=p2*p2;
    m6[0]=64.0+p0; m6[1]=64.0+p1; m6[2]=64.0+p2;
    m6[3]=64.0-p0; m6[4]=64.0-p1; m6[5]=64.0-p2;
  }
  __shared__ double sred[17][4];
  int wid = threadIdx.x >> 6;
  int lane0 = ((threadIdx.x & 63) == 0);
  #pragma unroll
  for (int q=0;q<11;++q){
    double t = wsum_d(v11[q]);
    if (lane0) sred[q][wid] = t;
  }
  #pragma unroll
  for (int j=0;j<6;++j){
    double t = wmax_d(m6[j]);
    if (lane0) sred[11+j][wid] = t;
  }
  __syncthreads();
  int t = threadIdx.x;
  if (t < 11) atomicAdd(&PD[t], sred[t][0]+sred[t][1]+sred[t][2]+sred[t][3]);
  else if (t < 17)
    atomicMaxD(&PD[72+(t-11)],
      fmax(fmax(sred[t][0],sred[t][1]), fmax(sred[t][2],sred[t][3])));
}

__global__ void k_eig(double* PD, int N){
  if (threadIdx.x != 0 || blockIdx.x != 0) return;
  int* DF = (int*)(PD + 28);
  int bad0 = 0;
  for (int i=0;i<11;++i) if (badd(PD[i])) bad0 = 1;
  if (bad0) DF[0] |= 1;
  double dN = (double)N;
  double mu[3] = {PD[0]/dN, PD[1]/dN, PD[2]/dN};
  double amax = 0.0;
  for (int j=0;j<3;++j){
    double mx = (PD[72+j] - 64.0) - mu[j];
    double mnv = mu[j] - (64.0 - PD[75+j]);
    amax = fmax(amax, fmax(mx, mnv));
  }
  double s = 0.999999/amax;
  double s2 = s*s;
  double C[3][3];
  C[0][0]=(PD[5]-dN*mu[0]*mu[0])*s2; C[1][0]=(PD[6]-dN*mu[1]*mu[0])*s2;
  C[2][0]=(PD[7]-dN*mu[2]*mu[0])*s2; C[1][1]=(PD[8]-dN*mu[1]*mu[1])*s2;
  C[2][1]=(PD[9]-dN*mu[2]*mu[1])*s2; C[2][2]=(PD[10]-dN*mu[2]*mu[2])*s2;
  C[0][1]=C[1][0]; C[0][2]=C[2][0]; C[1][2]=C[2][1];
  double w[3], V[3][3];
  eigh3_(C, w, V);
  int bad1 = 0;
  for (int i=0;i<3;++i){ if (badd(w[i])) bad1=1; for (int j=0;j<3;++j) if (badd(V[i][j])) bad1=1; }
  if (bad1){
    DF[0] |= 2;
    for (int i=0;i<3;++i) for (int j=0;j<3;++j) V[i][j] = (i==j) ? 1.0 : 0.0;
  }
  PD[12]=mu[0]; PD[13]=mu[1]; PD[14]=mu[2];
  PD[15]=s;
  for (int i=0;i<3;++i) for (int j=0;j<3;++j) PD[16+i*3+j]=V[i][j];
  double cntf = dN*32.0;
  double mu1 = PD[3]/cntf;
  double var = PD[4]/cntf - mu1*mu1;
  PD[25]=mu1;
  PD[26]=1.0/(sqrt(var>0.0?var:0.0)+1e-5);
}

__global__ void k_buildx(const void* __restrict__ data,
                         const void* __restrict__ ln1w,
                         const void* __restrict__ ln1b,
                         double* __restrict__ PD, float* __restrict__ x, int N){
  int n = blockIdx.x*blockDim.x + threadIdx.x;
  if (n >= N) return;
  int* DF = (int*)(PD + 28);
  int f32 = DF[1];
  size_t rb = (size_t)n*35;
  double s = PD[15];
  double p0 = ((double)ldin(data, rb+0, f32) - PD[12])*s;
  double p1 = ((double)ldin(data, rb+1, f32) - PD[13])*s;
  double p2 = ((double)ldin(data, rb+2, f32) - PD[14])*s;
  float* xr = x + (size_t)n*36;
  int bb = 0;
  for (int j=0;j<3;++j){
    float v = (float)(p0*PD[16+j] + p1*PD[19+j] + p2*PD[22+j]);
    bb |= badf(v);
    xr[j] = v;
  }
  float mu1 = (float)PD[25], rs = (float)PD[26];
  for (int k=0;k<32;++k){
    float v = (ldin(data, rb+3+k, f32) - mu1)*rs*ldin(ln1w, k, f32) + ldin(ln1b, k, f32);
    bb |= badf(v);
    xr[3+k] = v;
  }
  xr[35] = 0.f;
  if (bb) atomicOr(DF, 4);
}

__global__ void k_count(const int* __restrict__ dst, int* __restrict__ cnt, int E){
  int i = blockIdx.x*blockDim.x + threadIdx.x;
  if (i < E) atomicAdd(&cnt[dst[i]], 1);
}

__global__ void k_scan1(const int* __restrict__ cnt, int* __restrict__ bsum, int N){
  int i = blockIdx.x*256 + threadIdx.x;
  int v = (i < N) ? cnt[i] : 0;
  #pragma unroll
  for (int o=32;o>0;o>>=1) v += __shfl_down(v, o);
  __shared__ int s4[4];
  if ((threadIdx.x&63)==0) s4[threadIdx.x>>6]=v;
  __syncthreads();
  if (threadIdx.x==0) bsum[blockIdx.x]=s4[0]+s4[1]+s4[2]+s4[3];
}

__global__ void k_scan2(const int* __restrict__ bsum, int* __restrict__ bpre,
                        int* __restrict__ iptr, int nb, int N){
  if (threadIdx.x != 0 || blockIdx.x != 0) return;
  int run = 0;
  for (int b=0;b<nb;++b){ bpre[b]=run; run += bsum[b]; }
  iptr[N] = run;
}

__global__ void k_scan3(const int* __restrict__ cnt, const int* __restrict__ bpre,
                        int* __restrict__ iptr, int* __restrict__ cur, int N){
  __shared__ int sc[256];
  int i = blockIdx.x*256 + threadIdx.x;
  int t = threadIdx.x;
  int v = (i < N) ? cnt[i] : 0;
  sc[t] = v;
  __syncthreads();
  for (int o=1;o<256;o<<=1){
    int add = (t >= o) ? sc[t-o] : 0;
    __syncthreads();
    sc[t] += add;
    __syncthreads();
  }
  if (i < N){
    int val = bpre[blockIdx.x] + sc[t] - v;
    iptr[i] = val;
    cur[i] = val;
  }
}

// ---- deterministic 3-pass partition (buckets of 512 nodes) ----
// Pass 1: per-block histogram of its contiguous edge chunk.
__global__ void k_hist(const int* __restrict__ dst, int* __restrict__ H,
                       int E, int per, int nb){
  __shared__ int lc[256];
  int blk = blockIdx.x, t = threadIdx.x;
  lc[t] = 0;
  __syncthreads();
  int s = blk*per, e = min(E, s+per);
  for (int i = s+t; i < e; i += 256) atomicAdd(&lc[dst[i] >> 9], 1);
  __syncthreads();
  if (t < nb) H[t*NBLK + blk] = lc[t];
}

// Pass 2: per bucket, exclusive scan across blocks; base = iptr[bucket start].
__global__ void k_xscan(const int* __restrict__ H, const int* __restrict__ iptr,
                        int* __restrict__ offs){
  __shared__ int sc[256];
  int b = blockIdx.x, t = threadIdx.x;
  int v = H[b*NBLK + t];
  sc[t] = v;
  __syncthreads();
  for (int o=1;o<256;o<<=1){
    int add = (t >= o) ? sc[t-o] : 0;
    __syncthreads();
    sc[t] += add;
    __syncthreads();
  }
  offs[b*NBLK + t] = iptr[b << 9] + sc[t] - v;
}

// Pass 3: write each edge to its block-private contiguous range (no atomics
// to global; LDS rank counters only). Entry = src | et<<17 | (dst&511)<<21.
__global__ void k_binA2(const int* __restrict__ src, const int* __restrict__ dst,
                        const int* __restrict__ et, const int* __restrict__ offs,
                        int* __restrict__ stag, int E, int per){
  __shared__ int lc[256];
  int blk = blockIdx.x, t = threadIdx.x;
  lc[t] = 0;
  __syncthreads();
  int s = blk*per, e = min(E, s+per);
  for (int i = s+t; i < e; i += 256){
    int d = dst[i];
    int b = d >> 9;
    int r = atomicAdd(&lc[b], 1);
    stag[offs[b*NBLK + blk] + r] = src[i] | (et[i] << 17) | ((d & 511) << 21);
  }
}

// Pass 4: per 512-node bucket, scatter staged entries to exact CSR positions
// (writes land in the bucket's contiguous L2-resident window).
__global__ void k_binB2(const int* __restrict__ iptr, const int* __restrict__ stag,
                        int* __restrict__ pack, int N){
  __shared__ int lcnt[512];
  int b = blockIdx.x;
  int n0 = b << 9;
  int t = threadIdx.x;
  for (int j = t; j < 512; j += 256){
    int n = n0 + j;
    lcnt[j] = (n < N) ? iptr[n] : 0;
  }
  __syncthreads();
  int segs = iptr[n0];
  int nend = (n0 + 512 < N) ? (n0 + 512) : N;
  int sege = iptr[nend];
  for (int k = segs + t; k < sege; k += 256){
    int e2 = stag[k];
    int pos = atomicAdd(&lcnt[(e2 >> 21) & 511], 1);
    pack[pos] = (e2 & 0x1FFFF) | (((e2 >> 17) & 15) << 20);
  }
}

// fallback for N > 2^17 (src wouldn't fit 17 bits): direct scatter
__global__ void k_scatter(const int* __restrict__ src, const int* __restrict__ dst,
                          const int* __restrict__ et, int* __restrict__ cur,
                          int* __restrict__ pack, int E){
  int i = blockIdx.x*blockDim.x + threadIdx.x;
  if (i < E){
    int d = dst[i];
    int p = atomicAdd(&cur[d], 1);
    pack[p] = src[i] | (et[i] << 20);
  }
}

// Pack B fragments (bf16, MFMA lane layout) for W (per r, kc, tile) and for
// the yq/yk side (u_r = W_r@q, v_r = W_r@k computed inline, hi/lo split).
__global__ void k_fragpack(const void* __restrict__ W, size_t wofs, int F, int KC,
                           const void* __restrict__ qp, const void* __restrict__ kp,
                           size_t qofs,
                           unsigned short* __restrict__ bfr,
                           unsigned short* __restrict__ qkfr,
                           const int* __restrict__ DF){
  int t = blockIdx.x*blockDim.x + threadIdx.x;
  int nB = 15*KC*2*64*8;
  int nQ = 2*2*KC*64*8;
  int f32 = DF[1];
  if (t < nB){
    int j = t & 7; int lane = (t >> 3) & 63; int tile = (t >> 9) & 1; int idx = t >> 10;
    int kc = idx % KC; int r = idx / KC;
    int f = kc*32 + (lane >> 4)*8 + j;
    int o = tile*16 + (lane & 15);
    bfr[t] = (f < F) ? f2bf(ldin(W, wofs + ((size_t)(r*F+f))*32 + o, f32)) : 0;
  } else if (t < nB + nQ){
    int u = t - nB;
    int j = u & 7; int lane = (u >> 3) & 63; int wpk = u >> 9;
    int kc = wpk % KC; int wp = wpk / KC;
    int part = wp & 1; int which = wp >> 1;
    int f = kc*32 + (lane >> 4)*8 + j;
    int rr = lane & 15;
    unsigned short val = 0;
    if (f < F && rr < 15){
      const void* v = which ? kp : qp;
      float acc = 0.f;
      for (int o = 0; o < 32; ++o)
        acc = fmaf(ldin(W, wofs + ((size_t)(rr*F+f))*32 + o, f32), ldin(v, qofs + o, f32), acc);
      unsigned short hi = f2bf(acc);
      val = (part == 0) ? hi : f2bf(acc - bf2f(hi));
    }
    qkfr[u] = val;
  }
}

// MFMA GEMM, r-sliced for occupancy: blockIdx.y in [0,5), 3 relations each.
// y stored SWIZZLED: row position 2*col holds col (tile0), 2*col+1 holds
// col+16 (tile1) -> one aligned dword store per lane per (r,j).
__global__ void __launch_bounds__(256)
k_mf(const float* __restrict__ x, int str, int KC, int N,
     const unsigned short* __restrict__ bfr,
     const unsigned short* __restrict__ qkfr,
     unsigned short* __restrict__ y, float* __restrict__ yq, float* __restrict__ yk){
  int wave = blockIdx.x*(blockDim.x >> 6) + (threadIdx.x >> 6);
  int node0 = wave*16;
  if (node0 >= N) return;
  int lane = threadIdx.x & 63;
  int col = lane & 15, quad = lane >> 4;
  int r0 = blockIdx.y*3;

  short8 ah[2], al[2];
  #pragma unroll
  for (int kc = 0; kc < 2; ++kc){
    if (kc >= KC) break;
    float xv[8];
    int node = node0 + col;           // A row m = lane&15
    int kbase = kc*32 + quad*8;
    if (node < N && kbase < str){
      const float* xr = x + (size_t)node*str + kbase;
      if (kbase + 8 <= str){
        float4 a = *(const float4*)xr; float4 b = *(const float4*)(xr + 4);
        xv[0]=a.x; xv[1]=a.y; xv[2]=a.z; xv[3]=a.w; xv[4]=b.x; xv[5]=b.y; xv[6]=b.z; xv[7]=b.w;
      } else if (kbase + 4 <= str){
        float4 a = *(const float4*)xr;
        xv[0]=a.x; xv[1]=a.y; xv[2]=a.z; xv[3]=a.w; xv[4]=0.f; xv[5]=0.f; xv[6]=0.f; xv[7]=0.f;
      } else {
        #pragma unroll
        for (int j=0;j<8;++j) xv[j]=0.f;
      }
    } else {
      #pragma unroll
      for (int j=0;j<8;++j) xv[j]=0.f;
    }
    #pragma unroll
    for (int j=0;j<8;++j){
      unsigned short hi = f2bf(xv[j]);
      ah[kc][j] = (short)hi;
      al[kc][j] = (short)f2bf(xv[j] - bf2f(hi));
    }
  }

  const short8* B  = (const short8*)bfr;
  const short8* QK = (const short8*)qkfr;

  if (blockIdx.y == 0){
    // yq / yk tiles (cols = r), B-side hi/lo split too
    f32x4 aq = {0.f,0.f,0.f,0.f}, ak2 = {0.f,0.f,0.f,0.f};
    for (int kc = 0; kc < KC; ++kc){
      short8 qh = QK[((0*KC) + kc)*64 + lane];        // which=0 part=0
      short8 ql = QK[((1*KC) + kc)*64 + lane];        // which=0 part=1
      short8 kh = QK[((2*KC) + kc)*64 + lane];        // which=1 part=0
      short8 kl = QK[((3*KC) + kc)*64 + lane];        // which=1 part=1
      aq = mfma16(ah[kc], qh, aq);
      aq = mfma16(al[kc], qh, aq);
      aq = mfma16(ah[kc], ql, aq);
      ak2 = mfma16(ah[kc], kh, ak2);
      ak2 = mfma16(al[kc], kh, ak2);
      ak2 = mfma16(ah[kc], kl, ak2);
    }
    #pragma unroll
    for (int j = 0; j < 4; ++j){
      int node = node0 + quad*4 + j;
      if (node < N){
        yq[(size_t)node*16 + col] = aq[j];
        yk[(size_t)node*16 + col] = ak2[j];
      }
    }
  }

  // y tiles for this slice's 3 relations
  for (int r = r0; r < r0+3; ++r){
    f32x4 a0 = {0.f,0.f,0.f,0.f}, a1 = {0.f,0.f,0.f,0.f};
    for (int kc = 0; kc < KC; ++kc){
      short8 b0 = B[(((size_t)(r*KC + kc))*2 + 0)*64 + lane];
      short8 b1 = B[(((size_t)(r*KC + kc))*2 + 1)*64 + lane];
      a0 = mfma16(ah[kc], b0, a0);
      a0 = mfma16(al[kc], b0, a0);
      a1 = mfma16(ah[kc], b1, a1);
      a1 = mfma16(al[kc], b1, a1);
    }
    #pragma unroll
    for (int j = 0; j < 4; ++j){
      int node = node0 + quad*4 + j;
      if (node < N){
        unsigned int pk = (unsigned int)f2bf(a0[j]) | ((unsigned int)f2bf(a1[j]) << 16);
        *(unsigned int*)&y[(((size_t)r*N + node))*32 + col*2] = pk;
      }
    }
  }
}

// softmax + aggregation. deg<=64 fast path (scalars, no spill), 8x-unrolled
// gather. y rows are SWIZZLED (see k_mf): os = 2*(o&15) + (o>>4).
__global__ void k_main(const int* __restrict__ iptr, const int* __restrict__ pack,
                       const float* __restrict__ yq, const float* __restrict__ yk,
                       const unsigned short* __restrict__ y,
                       const void* __restrict__ biasp, size_t bofs,
                       const float* __restrict__ xres, float* __restrict__ hpre,
                       double* __restrict__ partials, int* __restrict__ DF, int N){
  __shared__ double sdb[4][2];
  int gt = blockIdx.x*blockDim.x + threadIdx.x;
  int node = gt >> 6, lane = gt & 63;
  int wid = threadIdx.x >> 6;
  int f32 = DF[1];
  int o = lane & 31;
  int os = ((o & 15) << 1) | (o >> 4);   // swizzled position within y row
  bool active = (node < N);
  float hp = 0.f;

  if (active){
    int start = iptr[node];
    int deg = iptr[node+1] - start;
    const float* yqn = yq + (size_t)node*16;
    float acc = 0.f;
    float ssum = 0.f;

    if (deg <= 64){
      // ---- fast path: one chunk in scalars ----
      int pe = 0; float a = -INFINITY;
      if (lane < deg){
        pe = pack[start+lane];
        int sr = pe & 0xFFFFF, et = pe >> 20;
        a = yqn[et] + yk[(size_t)sr*16+et];
        a = (a >= 0.f) ? a : 0.2f*a;
      }
      float amax = a;
      #pragma unroll
      for (int o2=32;o2>0;o2>>=1) amax = fmaxf(amax, __shfl_xor(amax, o2));
      float ev = (lane < deg) ? expf(a - amax) : 0.f;
      ssum = ev;
      int sub = lane >> 5;
      for (; sub + 14 < deg; sub += 16){
        float w0 = __shfl(ev, sub),    w1 = __shfl(ev, sub+2);
        float w2 = __shfl(ev, sub+4),  w3 = __shfl(ev, sub+6);
        float w4 = __shfl(ev, sub+8),  w5 = __shfl(ev, sub+10);
        float w6 = __shfl(ev, sub+12), w7 = __shfl(ev, sub+14);
        int   p0 = __shfl(pe, sub),    p1 = __shfl(pe, sub+2);
        int   p2 = __shfl(pe, sub+4),  p3 = __shfl(pe, sub+6);
        int   p4 = __shfl(pe, sub+8),  p5 = __shfl(pe, sub+10);
        int   p6 = __shfl(pe, sub+12), p7 = __shfl(pe, sub+14);
        float v0 = bf2f(y[((size_t)(p0 >> 20)*N + (p0 & 0xFFFFF))*32 + os]);
        float v1 = bf2f(y[((size_t)(p1 >> 20)*N + (p1 & 0xFFFFF))*32 + os]);
        float v2 = bf2f(y[((size_t)(p2 >> 20)*N + (p2 & 0xFFFFF))*32 + os]);
        float v3 = bf2f(y[((size_t)(p3 >> 20)*N + (p3 & 0xFFFFF))*32 + os]);
        float v4 = bf2f(y[((size_t)(p4 >> 20)*N + (p4 & 0xFFFFF))*32 + os]);
        float v5 = bf2f(y[((size_t)(p5 >> 20)*N + (p5 & 0xFFFFF))*32 + os]);
        float v6 = bf2f(y[((size_t)(p6 >> 20)*N + (p6 & 0xFFFFF))*32 + os]);
        float v7 = bf2f(y[((size_t)(p7 >> 20)*N + (p7 & 0xFFFFF))*32 + os]);
        acc = fmaf(w0, v0, acc); acc = fmaf(w1, v1, acc);
        acc = fmaf(w2, v2, acc); acc = fmaf(w3, v3, acc);
        acc = fmaf(w4, v4, acc); acc = fmaf(w5, v5, acc);
        acc = fmaf(w6, v6, acc); acc = fmaf(w7, v7, acc);
      }
      for (; sub + 6 < deg; sub += 8){
        float w0 = __shfl(ev, sub),   w1 = __shfl(ev, sub+2);
        float w2 = __shfl(ev, sub+4), w3 = __shfl(ev, sub+6);
        int   p0 = __shfl(pe, sub),   p1 = __shfl(pe, sub+2);
        int   p2 = __shfl(pe, sub+4), p3 = __shfl(pe, sub+6);
        float v0 = bf2f(y[((size_t)(p0 >> 20)*N + (p0 & 0xFFFFF))*32 + os]);
        float v1 = bf2f(y[((size_t)(p1 >> 20)*N + (p1 & 0xFFFFF))*32 + os]);
        float v2 = bf2f(y[((size_t)(p2 >> 20)*N + (p2 & 0xFFFFF))*32 + os]);
        float v3 = bf2f(y[((size_t)(p3 >> 20)*N + (p3 & 0xFFFFF))*32 + os]);
        acc = fmaf(w0, v0, acc); acc = fmaf(w1, v1, acc);
        acc = fmaf(w2, v2, acc); acc = fmaf(w3, v3, acc);
      }
      for (; sub < deg; sub += 2){
        float wgt = __shfl(ev, sub);
        int pb = __shfl(pe, sub);
        acc = fmaf(wgt, bf2f(y[((size_t)(pb >> 20)*N + (pb & 0xFFFFF))*32 + os]), acc);
      }
    } else {
      // ---- slow path: two-pass recompute (rare: deg>64) ----
      float amax = -INFINITY;
      for (int k = lane; k < deg; k += 64){
        int pe = pack[start+k];
        int sr = pe & 0xFFFFF, et = pe >> 20;
        float a = yqn[et] + yk[(size_t)sr*16+et];
        a = (a >= 0.f) ? a : 0.2f*a;
        amax = fmaxf(amax, a);
      }
      #pragma unroll
      for (int o2=32;o2>0;o2>>=1) amax = fmaxf(amax, __shfl_xor(amax, o2));
      for (int c = 0; c < deg; c += 64){
        int k = c + lane;
        float ev = 0.f; int pe = 0;
        if (k < deg){
          pe = pack[start+k];
          int sr = pe & 0xFFFFF, et = pe >> 20;
          float a = yqn[et] + yk[(size_t)sr*16+et];
          a = (a >= 0.f) ? a : 0.2f*a;
          ev = expf(a - amax);
          ssum += ev;
        }
        int lim = min(64, deg - c);
        int sub = lane >> 5;
        for (; sub + 6 < lim; sub += 8){
          float w0 = __shfl(ev, sub),   w1 = __shfl(ev, sub+2);
          float w2 = __shfl(ev, sub+4), w3 = __shfl(ev, sub+6);
          int   p0 = __shfl(pe, sub),   p1 = __shfl(pe, sub+2);
          int   p2 = __shfl(pe, sub+4), p3 = __shfl(pe, sub+6);
          float v0 = bf2f(y[((size_t)(p0 >> 20)*N + (p0 & 0xFFFFF))*32 + os]);
          float v1 = bf2f(y[((size_t)(p1 >> 20)*N + (p1 & 0xFFFFF))*32 + os]);
          float v2 = bf2f(y[((size_t)(p2 >> 20)*N + (p2 & 0xFFFFF))*32 + os]);
          float v3 = bf2f(y[((size_t)(p3 >> 20)*N + (p3 & 0xFFFFF))*32 + os]);
          acc = fmaf(w0, v0, acc);
          acc = fmaf(w1, v1, acc);
          acc = fmaf(w2, v2, acc);
          acc = fmaf(w3, v3, acc);
        }
        for (; sub < lim; sub += 2){
          float wgt = __shfl(ev, sub);
          int pb = __shfl(pe, sub);
          acc = fmaf(wgt, bf2f(y[((size_t)(pb >> 20)*N + (pb & 0xFFFFF))*32 + os]), acc);
        }
      }
    }
    #pragma unroll
    for (int o2=32;o2>0;o2>>=1) ssum += __shfl_xor(ssum, o2);
    float inv = 1.f/(ssum + 1e-16f);
    acc *= inv;
    acc += __shfl_xor(acc, 32);

    if (lane < 32){
      hp = acc + ldin(biasp, bofs + o, f32);
      if (xres) hp += xres[(size_t)node*32 + o];
      if (badf(hp)) atomicOr(DF, 32);
      hpre[(size_t)node*32 + o] = hp;
    }
  }

  // block-level LN stats -> plain store to partials (no fence, no atomics)
  float s1 = (active && lane < 32) ? hp : 0.f;
  float s2 = s1*s1;
  #pragma unroll
  for (int o2=32;o2>0;o2>>=1){ s1 += __shfl_xor(s1,o2); s2 += __shfl_xor(s2,o2); }
  if (lane == 0){ sdb[wid][0] = (double)s1; sdb[wid][1] = (double)s2; }
  __syncthreads();
  if (threadIdx.x == 0){
    partials[(size_t)blockIdx.x*2]   = sdb[0][0]+sdb[1][0]+sdb[2][0]+sdb[3][0];
    partials[(size_t)blockIdx.x*2+1] = sdb[0][1]+sdb[1][1]+sdb[2][1]+sdb[3][1];
  }
}

__global__ void k_stat(const double* __restrict__ partials, int nb,
                       double* __restrict__ PD, int l){
  double t1 = 0.0, t2 = 0.0;
  for (int i = threadIdx.x; i < nb; i += 256){
    t1 += partials[(size_t)i*2];
    t2 += partials[(size_t)i*2+1];
  }
  t1 = wsum_d(t1); t2 = wsum_d(t2);
  __shared__ double sd[8];
  int w = threadIdx.x >> 6;
  if ((threadIdx.x & 63) == 0){ sd[w*2] = t1; sd[w*2+1] = t2; }
  __syncthreads();
  if (threadIdx.x == 0){
    PD[32+2*l]   = sd[0]+sd[2]+sd[4]+sd[6];
    PD[32+2*l+1] = sd[1]+sd[3]+sd[5]+sd[7];
  }
}

__global__ void k_ln(float* __restrict__ h, const void* __restrict__ lnw,
                     const void* __restrict__ lnb, size_t lofs,
                     double* __restrict__ PD, int l, int N){
  int idx = blockIdx.x*blockDim.x + threadIdx.x;
  if (idx >= N*32) return;
  int* DF = (int*)(PD + 28);
  int f32 = DF[1];
  const double* stats = PD + 32 + 2*l;
  int o = idx & 31;
  double cntf = (double)N*32.0;
  double mu = stats[0]/cntf;
  double var = stats[1]/cntf - mu*mu;
  float rstd = (float)(1.0/(sqrt(var>0.0?var:0.0) + 1e-5));
  float v = (h[idx] - (float)mu)*rstd*ldin(lnw, lofs + o, f32) + ldin(lnb, lofs + o, f32);
  v = v / (1.f + expf(-v));
  if (badf(v)) atomicOr(DF, 64);
  h[idx] = v;
}

__global__ void k_pool(const float* __restrict__ h, double* __restrict__ PD, int N){
  __shared__ float sp[8][33];
  int t = threadIdx.x, o = t & 31, g = t >> 5;
  int r0 = blockIdx.x*256;
  float s = 0.f;
  for (int r = r0 + g; r < N && r < r0 + 256; r += 8) s += h[(size_t)r*32 + o];
  sp[g][o] = s;
  __syncthreads();
  if (t < 32){
    float tot = 0.f;
    #pragma unroll
    for (int g2=0; g2<8; ++g2) tot += sp[g2][t];
    atomicAdd(&PD[40 + t], (double)tot);
  }
}

__global__ void k_out(double* __restrict__ PD, const void* __restrict__ Wl,
                      const void* __restrict__ bl, void* __restrict__ out, int N, int H2){
  int j = blockIdx.x*blockDim.x + threadIdx.x;
  if (j >= H2) return;
  int* DF = (int*)(PD + 28);
  int f32 = DF[1];
  int flag = DF[0];
  const double* pool = PD + 40;
  float acc = ldin(bl, j, f32);
  for (int o=0;o<32;++o)
    acc = fmaf((float)(pool[o]/(double)N), ldin(Wl, (size_t)j*32+o, f32), acc);
  if (badf(acc)) flag |= 128;
  float v = acc / (1.f + expf(-acc));
  if (flag) v = (float)flag;   // diagnostic: absmax == stage bitmask
  if (f32) ((float*)out)[j] = v;
  else     ((unsigned short*)out)[j] = f2bf(v);
}

__global__ void k_diag(unsigned short* out, float val, int H2){
  int j = blockIdx.x*blockDim.x + threadIdx.x;
  if (j < H2) out[j] = f2bf(val);
}

// ---------------- entry ----------------
extern "C" void kernel_launch(void* const* d_in, const int* in_sizes, int n_in,
                              void* d_out, int out_size, void* d_ws, size_t ws_size,
                              hipStream_t stream)
{
  const int N  = in_sizes[0] / 35;
  const int E  = in_sizes[3];
  const int R  = 15;
  const int H2 = in_sizes[19];

  const void* data = d_in[0];
  const int* ei  = (const int*)d_in[2];
  const int* etp = (const int*)d_in[3];
  const void* W0  = d_in[6];
  const void* q0  = d_in[7];
  const void* k0  = d_in[8];
  const void* b0  = d_in[9];
  const void* Wsp = d_in[10];
  const void* qsp = d_in[11];
  const void* ksp = d_in[12];
  const void* bsp = d_in[13];
  const void* lnw = d_in[14];
  const void* lnb = d_in[15];
  const void* ln1w= d_in[16];
  const void* ln1b= d_in[17];
  const void* l1W = d_in[18];
  const void* l1b = d_in[19];

  char* base = (char*)d_ws;
  size_t off = 0;
  auto A = [&](size_t nb)->size_t { size_t c = off; off += (nb + 255) & ~(size_t)255; return c; };
  size_t oPD  = A(1024);
  size_t oCnt = A((size_t)N*4);
  size_t oPtr = A(((size_t)N+1)*4);
  size_t oCur = A((size_t)N*4);
  size_t oBs  = A(4096);
  size_t oBp  = A(4096);
  size_t oPk  = A((size_t)E*4);
  size_t oSt  = A((size_t)E*4);
  size_t oHh  = A((size_t)256*NBLK*4);
  size_t oOf  = A((size_t)256*NBLK*4);
  size_t oX   = A((size_t)N*36*4);
  size_t oH0  = A((size_t)N*32*4);
  size_t oH1  = A((size_t)N*32*4);
  size_t oYq  = A((size_t)N*16*4);
  size_t oYk  = A((size_t)N*16*4);
  size_t oBf  = A((size_t)15*2*2*64*8*2);
  size_t oQk  = A((size_t)2*2*2*64*8*2);
  int nbMain  = (int)(((size_t)N*64 + 255)/256);
  size_t oPt  = A((size_t)nbMain*2*8);
  size_t oY   = off;
  size_t needB = oY + (size_t)R*N*32*2;

  double* PD  = (double*)(base + oPD);
  int* DF     = (int*)(PD + 28);
  int* cnt    = (int*)(base + oCnt);
  int* iptr   = (int*)(base + oPtr);
  int* cur    = (int*)(base + oCur);
  int* bsum   = (int*)(base + oBs);
  int* bpre   = (int*)(base + oBp);
  int* pack   = (int*)(base + oPk);
  int* stag   = (int*)(base + oSt);
  int* Hh     = (int*)(base + oHh);
  int* offs   = (int*)(base + oOf);
  float* xb   = (float*)(base + oX);
  float* h0   = (float*)(base + oH0);
  float* h1   = (float*)(base + oH1);
  float* yqb  = (float*)(base + oYq);
  float* ykb  = (float*)(base + oYk);
  unsigned short* bfr  = (unsigned short*)(base + oBf);
  unsigned short* qkfr = (unsigned short*)(base + oQk);
  double* partials = (double*)(base + oPt);
  unsigned short* y = (unsigned short*)(base + oY);

  if (ws_size < needB){
    k_diag<<<1, 256, 0, stream>>>((unsigned short*)d_out, (float)(ws_size >> 20), H2);
    return;
  }

  // zero PD + cnt ( [0, oPtr) covers both exactly )
  hipMemsetAsync(base, 0, oPtr, stream);

  int nbN = (N + 255)/256;
  int nbE = (E + 255)/256;
  int nus = (in_sizes[0] < 1024) ? in_sizes[0] : 1024;

  k_dtype<<<1, 256, 0, stream>>>((const unsigned short*)data, nus, PD);
  k_red1<<<nbN, 256, 0, stream>>>(data, N, PD);
  k_eig<<<1, 1, 0, stream>>>(PD, N);
  k_buildx<<<nbN, 256, 0, stream>>>(data, ln1w, ln1b, PD, xb, N);

  k_count<<<nbE, 256, 0, stream>>>(ei + E, cnt, E);
  k_scan1<<<nbN, 256, 0, stream>>>(cnt, bsum, N);
  k_scan2<<<1, 1, 0, stream>>>(bsum, bpre, iptr, nbN, N);
  k_scan3<<<nbN, 256, 0, stream>>>(cnt, bpre, iptr, cur, N);

  if (N <= (1 << 17)){
    int nbkt = (N + 511) >> 9;           // <= 256
    int per  = (E + NBLK - 1) / NBLK;
    k_hist<<<NBLK, 256, 0, stream>>>(ei + E, Hh, E, per, nbkt);
    k_xscan<<<nbkt, 256, 0, stream>>>(Hh, iptr, offs);
    k_binA2<<<NBLK, 256, 0, stream>>>(ei, ei + E, etp, offs, stag, E, per);
    k_binB2<<<nbkt, 256, 0, stream>>>(iptr, stag, pack, N);
  } else {
    k_scatter<<<nbE, 256, 0, stream>>>(ei, ei + E, etp, cur, pack, E);
  }

  int nbMf = (int)(((N + 15)/16 + 3)/4);
  for (int l=0; l<4; ++l){
    const void* W  = (l==0)? W0 : Wsp;  size_t wofs = (l==0)? 0 : (size_t)(l-1)*R*32*32;
    const void* qp = (l==0)? q0 : qsp;  size_t qofs = (l==0)? 0 : (size_t)(l-1)*32;
    const void* kp = (l==0)? k0 : ksp;
    const void* bp = (l==0)? b0 : bsp;  size_t bofs = qofs;
    int str = (l==0)? 36 : 32;
    int KC = (l==0)? 2 : 1;
    int F = (l==0)? 35 : 32;
    const float* xin = (l==0)? xb : ((l%2==0)? h1 : h0);
    float* hout = (l%2==0)? h0 : h1;
    int nFrag = 15*KC*2*64*8 + 2*2*KC*64*8;
    k_fragpack<<<(nFrag+255)/256, 256, 0, stream>>>(W, wofs, F, KC, qp, kp, qofs, bfr, qkfr, DF);
    dim3 gmf((unsigned)nbMf, 5);
    k_mf<<<gmf, 256, 0, stream>>>(xin, str, KC, N, bfr, qkfr, y, yqb, ykb);
    k_main<<<nbMain, 256, 0, stream>>>(iptr, pack, yqb, ykb, y, bp, bofs,
                 (l==0)? (const float*)nullptr : xin, hout, partials, DF, N);
    k_stat<<<1, 256, 0, stream>>>(partials, nbMain, PD, l);
    k_ln<<<(N*32+255)/256, 256, 0, stream>>>(hout, lnw, lnb, (size_t)l*32, PD, l, N);
  }

  k_pool<<<nbN, 256, 0, stream>>>(h1, PD, N);
  k_out<<<(H2+255)/256, 256, 0, stream>>>(PD, l1W, l1b, d_out, N, H2);
}

// Round 12
// 1217.442 us; speedup vs baseline: 3.7800x; 1.1044x over previous
//
#include <hip/hip_runtime.h>
#include <math.h>
#include <stdint.h>

#define NBLK 256

// ---------------- helpers ----------------
__device__ inline float bf2f(unsigned short u){
  union { unsigned int i; float f; } x; x.i = ((unsigned int)u) << 16; return x.f;
}
__device__ inline unsigned short f2bf(float f){
  union { float f; unsigned int i; } x; x.f = f;
  unsigned int u = x.i;
  return (unsigned short)((u + 0x7FFFu + ((u >> 16) & 1u)) >> 16);
}
// dtype-dispatched input load: f32 flag comes from device-side probe
__device__ inline float ldin(const void* p, size_t i, int f32){
  return f32 ? ((const float*)p)[i] : bf2f(((const unsigned short*)p)[i]);
}

__device__ inline int badf(float v){ return !(fabsf(v) <= 3.0e38f); }
__device__ inline int badd(double v){ return !(fabs(v) <= 1.0e300); }

__device__ inline double wsum_d(double v){
  #pragma unroll
  for (int o = 32; o > 0; o >>= 1) v += __shfl_down(v, o);
  return v;
}
__device__ inline double wmax_d(double v){
  #pragma unroll
  for (int o = 32; o > 0; o >>= 1) v = fmax(v, __shfl_down(v, o));
  return v;
}
__device__ inline void atomicMaxD(double* addr, double v){ // v >= 0
  atomicMax((unsigned long long*)addr, (unsigned long long)__double_as_longlong(v));
}

// MFMA types
typedef __attribute__((ext_vector_type(8))) short short8;
typedef __attribute__((ext_vector_type(4))) float f32x4;
__device__ inline f32x4 mfma16(short8 a, short8 b, f32x4 c){
  return __builtin_amdgcn_mfma_f32_16x16x32_bf16(a, b, c, 0, 0, 0);
}

// ---------------- LAPACK 3x3 eigh port (dsytd2 + dsteqr + dormtr) ----------------
__device__ inline double d_sign(double a, double b){ return (b >= 0.0) ? fabs(a) : -fabs(a); }
__device__ inline double dlapy2_(double x, double y){ return sqrt(x*x + y*y); }

__device__ void dlartg_(double f, double g, double* cs, double* sn, double* r){
  // LAPACK >= 3.10 convention: c >= 0, r = sign(d, f)
  if (g == 0.0){ *cs = 1.0; *sn = 0.0; *r = f; }
  else if (f == 0.0){ *cs = 0.0; *sn = (g >= 0.0) ? 1.0 : -1.0; *r = fabs(g); }
  else {
    double d = sqrt(f*f + g*g);
    *cs = fabs(f)/d;
    *r  = d_sign(d, f);
    *sn = g / (*r);
  }
}

__device__ void dlaev2_(double a, double b, double c, double* rt1, double* rt2,
                        double* cs1, double* sn1){
  double sm = a + c, df = a - c, adf = fabs(df), tb = b + b, ab = fabs(tb);
  double acmx, acmn;
  if (fabs(a) > fabs(c)){ acmx = a; acmn = c; } else { acmx = c; acmn = a; }
  double rt;
  if (adf > ab) rt = adf*sqrt(1.0 + (ab/adf)*(ab/adf));
  else if (adf < ab) rt = ab*sqrt(1.0 + (adf/ab)*(adf/ab));
  else rt = ab*sqrt(2.0);
  int sgn1;
  if (sm < 0.0){ *rt1 = 0.5*(sm - rt); sgn1 = -1; *rt2 = (acmx/(*rt1))*acmn - (b/(*rt1))*b; }
  else if (sm > 0.0){ *rt1 = 0.5*(sm + rt); sgn1 = 1; *rt2 = (acmx/(*rt1))*acmn - (b/(*rt1))*b; }
  else { *rt1 = 0.5*rt; *rt2 = -0.5*rt; sgn1 = 1; }
  int sgn2; double cs;
  if (df >= 0.0){ cs = df + rt; sgn2 = 1; } else { cs = df - rt; sgn2 = -1; }
  double acs = fabs(cs);
  if (acs > ab){ double ct = -tb/cs; *sn1 = 1.0/sqrt(1.0+ct*ct); *cs1 = ct*(*sn1); }
  else {
    if (ab == 0.0){ *cs1 = 1.0; *sn1 = 0.0; }
    else { double tn = -cs/tb; *cs1 = 1.0/sqrt(1.0+tn*tn); *sn1 = tn*(*cs1); }
  }
  if (sgn1 == sgn2){ double tn = *cs1; *cs1 = -(*sn1); *sn1 = tn; }
}

__device__ void dsteqr3_(double* dd, double* ee, double z[3][3]){
  #define D_(i) dd[(i)-1]
  #define E_(i) ee[(i)-1]
  #define Z_(i,j) z[(i)-1][(j)-1]
  #define CW_(i) cw[(i)-1]
  #define SW_(i) sw[(i)-1]
  const int n = 3;
  const double eps = 1.1102230246251565e-16;
  const double eps2 = eps*eps;
  const double safmin = 2.2250738585072014e-308;
  const int nmaxit = n*30;
  double cw[3], sw[3];
  int jtot = 0;
  int l1 = 1, l, m, lsv, lend, lendsv;
  double p, g, r, c, s, f, b, rt1, rt2, anorm, tst;

L10:
  if (l1 > n) goto L160;
  if (l1 > 1) E_(l1-1) = 0.0;
  if (l1 <= n-1){
    for (m = l1; m <= n-1; ++m){
      tst = fabs(E_(m));
      if (tst == 0.0) goto L30;
      if (tst <= (sqrt(fabs(D_(m)))*sqrt(fabs(D_(m+1))))*eps){ E_(m) = 0.0; goto L30; }
    }
  }
  m = n;
L30:
  l = l1; lsv = l; lend = m; lendsv = lend; l1 = m+1;
  if (lend == l) goto L10;
  anorm = 0.0;
  for (int i = l; i <= lend; ++i) anorm = fmax(anorm, fabs(D_(i)));
  for (int i = l; i <= lend-1; ++i) anorm = fmax(anorm, fabs(E_(i)));
  if (anorm == 0.0) goto L10;
  if (fabs(D_(lend)) < fabs(D_(l))){ lend = lsv; l = lendsv; }
  if (lend > l) goto L40; else goto L90;

  // -------- QL iteration --------
L40:
  if (l != lend){
    for (m = l; m <= lend-1; ++m){
      tst = fabs(E_(m)); tst = tst*tst;
      if (tst <= (eps2*fabs(D_(m)))*fabs(D_(m+1)) + safmin) goto L60;
    }
  }
  m = lend;
L60:
  if (m < lend) E_(m) = 0.0;
  p = D_(l);
  if (m == l) goto L80;
  if (m == l+1){
    dlaev2_(D_(l), E_(l), D_(l+1), &rt1, &rt2, &c, &s);
    CW_(l) = c; SW_(l) = s;
    { double ct = CW_(l), st = SW_(l);
      if (ct != 1.0 || st != 0.0)
        for (int i = 1; i <= n; ++i){
          double t = Z_(i, l+1);
          Z_(i, l+1) = ct*t - st*Z_(i, l);
          Z_(i, l)   = st*t + ct*Z_(i, l);
        }
    }
    D_(l) = rt1; D_(l+1) = rt2; E_(l) = 0.0;
    l += 2;
    if (l <= lend) goto L40;
    goto L140;
  }
  if (jtot == nmaxit) goto L140;
  jtot++;
  g = (D_(l+1) - p)/(2.0*E_(l));
  r = dlapy2_(g, 1.0);
  g = D_(m) - p + E_(l)/(g + d_sign(r, g));
  s = 1.0; c = 1.0; p = 0.0;
  for (int i = m-1; i >= l; --i){
    f = s*E_(i); b = c*E_(i);
    dlartg_(g, f, &c, &s, &r);
    if (i != m-1) E_(i+1) = r;
    g = D_(i+1) - p;
    r = (D_(i) - g)*s + 2.0*c*b;
    p = s*r;
    D_(i+1) = g + p;
    g = c*r - b;
    CW_(i) = c; SW_(i) = -s;
  }
  { int mm = m - l + 1;
    for (int j = mm-1; j >= 1; --j){
      double ct = CW_(l+j-1), st = SW_(l+j-1);
      if (ct != 1.0 || st != 0.0)
        for (int i = 1; i <= n; ++i){
          double t = Z_(i, l+j);
          Z_(i, l+j)   = ct*t - st*Z_(i, l+j-1);
          Z_(i, l+j-1) = st*t + ct*Z_(i, l+j-1);
        }
    }
  }
  D_(l) = D_(l) - p;
  E_(l) = g;
  goto L40;
L80:
  D_(l) = p;
  l++;
  if (l <= lend) goto L40;
  goto L140;

  // -------- QR iteration --------
L90:
  if (l != lend){
    for (m = l; m >= lend+1; --m){
      tst = fabs(E_(m-1)); tst = tst*tst;
      if (tst <= (eps2*fabs(D_(m)))*fabs(D_(m-1)) + safmin) goto L110;
    }
  }
  m = lend;
L110:
  if (m > lend) E_(m-1) = 0.0;
  p = D_(l);
  if (m == l) goto L130;
  if (m == l-1){
    dlaev2_(D_(l-1), E_(l-1), D_(l), &rt1, &rt2, &c, &s);
    CW_(m) = c; SW_(m) = s;
    { double ct = CW_(m), st = SW_(m);
      if (ct != 1.0 || st != 0.0)
        for (int i = 1; i <= n; ++i){
          double t = Z_(i, l);
          Z_(i, l)   = ct*t - st*Z_(i, l-1);
          Z_(i, l-1) = st*t + ct*Z_(i, l-1);
        }
    }
    D_(l-1) = rt1; D_(l) = rt2; E_(l-1) = 0.0;
    l -= 2;
    if (l >= lend) goto L90;
    goto L140;
  }
  if (jtot == nmaxit) goto L140;
  jtot++;
  g = (D_(l-1) - p)/(2.0*E_(l-1));
  r = dlapy2_(g, 1.0);
  g = D_(m) - p + E_(l-1)/(g + d_sign(r, g));
  s = 1.0; c = 1.0; p = 0.0;
  for (int i = m; i <= l-1; ++i){
    f = s*E_(i); b = c*E_(i);
    dlartg_(g, f, &c, &s, &r);
    if (i != m) E_(i-1) = r;
    g = D_(i) - p;
    r = (D_(i+1) - g)*s + 2.0*c*b;
    p = s*r;
    D_(i) = g + p;
    g = c*r - b;
    CW_(i) = c; SW_(i) = s;
  }
  { int mm = l - m + 1;
    for (int j = 1; j <= mm-1; ++j){
      double ct = CW_(m+j-1), st = SW_(m+j-1);
      if (ct != 1.0 || st != 0.0)
        for (int i = 1; i <= n; ++i){
          double t = Z_(i, m+j);
          Z_(i, m+j)   = ct*t - st*Z_(i, m+j-1);
          Z_(i, m+j-1) = st*t + ct*Z_(i, m+j-1);
        }
    }
  }
  D_(l) = D_(l) - p;
  E_(l-1) = g;
  goto L90;
L130:
  D_(l) = p;
  l--;
  if (l >= lend) goto L90;
  goto L140;

L140:
  if (jtot < nmaxit) goto L10;
  goto L190;

L160:
  for (int ii = 2; ii <= n; ++ii){
    int i = ii-1, k = i;
    p = D_(i);
    for (int j = ii; j <= n; ++j) if (D_(j) < p){ k = j; p = D_(j); }
    if (k != i){
      D_(k) = D_(i); D_(i) = p;
      for (int rr = 1; rr <= n; ++rr){ double t = Z_(rr,i); Z_(rr,i) = Z_(rr,k); Z_(rr,k) = t; }
    }
  }
L190:
  ;
  #undef D_
  #undef E_
  #undef Z_
  #undef CW_
  #undef SW_
}

__device__ void eigh3_(const double C[3][3], double w[3], double v[3][3]){
  double a00=C[0][0], a10=C[1][0], a20=C[2][0], a11=C[1][1], a21=C[2][1], a22=C[2][2];
  double dd[3], ee[2], tau, v2;
  double alpha = a10, x = a20;
  double xnorm = fabs(x);
  if (xnorm == 0.0){ tau = 0.0; v2 = 0.0; ee[0] = alpha; }
  else {
    double beta = -d_sign(dlapy2_(alpha, xnorm), alpha);
    tau = (beta - alpha)/beta;
    v2 = x/(alpha - beta);
    ee[0] = beta;
  }
  if (tau != 0.0){
    double w0 = tau*(a11 + a21*v2);
    double w1 = tau*(a21 + a22*v2);
    double wv = w0 + w1*v2;
    double ac = -0.5*tau*wv;
    w0 += ac; w1 += ac*v2;
    a11 = a11 - 2.0*w0;
    a21 = a21 - (v2*w0 + w1);
    a22 = a22 - 2.0*v2*w1;
  }
  dd[0]=a00; dd[1]=a11; dd[2]=a22; ee[1]=a21;
  double z[3][3] = {{1,0,0},{0,1,0},{0,0,1}};
  dsteqr3_(dd, ee, z);
  for (int j = 0; j < 3; ++j){
    double t = z[1][j] + v2*z[2][j];
    z[1][j] -= tau*t;
    z[2][j] -= tau*t*v2;
  }
  for (int i=0;i<3;++i){ w[i]=dd[i]; for(int j=0;j<3;++j) v[i][j]=z[i][j]; }
}

// ---------------- kernels ----------------
// PD layout (doubles): 0-2 possum, 3 fsum, 4 fsumsq, 5-10 raw pos moments
// (m00,m10,m20,m11,m21,m22), 12-14 mean, 15 scale, 16-24 V, 25 mu1, 26 rstd1,
// 28: int flag + int isf32, 32+2l per-layer LN stats, 40-71 pool,
// 72-74 max(64+p), 75-77 max(64-p)

__global__ void k_dtype(const unsigned short* __restrict__ data, int nus, double* PD){
  int* DF = (int*)(PD + 28);
  int t = threadIdx.x;
  int bad = 0;
  for (int i = t; i < nus; i += 256){
    int e = (data[i] >> 7) & 0xFF;
    if (e > 0x90 || (e && e < 0x60)) bad++;
  }
  #pragma unroll
  for (int o = 32; o > 0; o >>= 1) bad += __shfl_down(bad, o);
  __shared__ int sb[4];
  if ((t & 63) == 0) sb[t >> 6] = bad;
  __syncthreads();
  if (t == 0) DF[1] = ((sb[0]+sb[1]+sb[2]+sb[3]) > nus/16) ? 1 : 0;
}

// single pass: pos sums, raw second moments, min/max (as max(64±p)), feat sums
// single __syncthreads: all 17 wave-reductions staged in one LDS round.
__global__ void k_red1(const void* __restrict__ data, int N, double* PD){
  int n = blockIdx.x*blockDim.x + threadIdx.x;
  const int* DF = (const int*)(PD + 28);
  int f32 = DF[1];
  double v11[11] = {0,0,0,0,0,0,0,0,0,0,0};
  double m6[6] = {0,0,0,0,0,0};
  if (n < N){
    size_t rb = (size_t)n*35;
    double p0 = ldin(data, rb+0, f32);
    double p1 = ldin(data, rb+1, f32);
    double p2 = ldin(data, rb+2, f32);
    v11[0]=p0; v11[1]=p1; v11[2]=p2;
    double fs=0, fss=0;
    for (int k=3;k<35;++k){ double v = ldin(data, rb+k, f32); fs += v; fss += v*v; }
    v11[3]=fs; v11[4]=fss;
    v11[5]=p0*p0; v11[6]=p1*p0; v11[7]=p2*p0; v11[8]=p1*p1; v11[9]=p2*p1; v11[10]=p2*p2;
    m6[0]=64.0+p0; m6[1]=64.0+p1; m6[2]=64.0+p2;
    m6[3]=64.0-p0; m6[4]=64.0-p1; m6[5]=64.0-p2;
  }
  __shared__ double sred[17][4];
  int wid = threadIdx.x >> 6;
  int lane0 = ((threadIdx.x & 63) == 0);
  #pragma unroll
  for (int q=0;q<11;++q){
    double t = wsum_d(v11[q]);
    if (lane0) sred[q][wid] = t;
  }
  #pragma unroll
  for (int j=0;j<6;++j){
    double t = wmax_d(m6[j]);
    if (lane0) sred[11+j][wid] = t;
  }
  __syncthreads();
  int t = threadIdx.x;
  if (t < 11) atomicAdd(&PD[t], sred[t][0]+sred[t][1]+sred[t][2]+sred[t][3]);
  else if (t < 17)
    atomicMaxD(&PD[72+(t-11)],
      fmax(fmax(sred[t][0],sred[t][1]), fmax(sred[t][2],sred[t][3])));
}

__global__ void k_eig(double* PD, int N){
  if (threadIdx.x != 0 || blockIdx.x != 0) return;
  int* DF = (int*)(PD + 28);
  int bad0 = 0;
  for (int i=0;i<11;++i) if (badd(PD[i])) bad0 = 1;
  if (bad0) DF[0] |= 1;
  double dN = (double)N;
  double mu[3] = {PD[0]/dN, PD[1]/dN, PD[2]/dN};
  double amax = 0.0;
  for (int j=0;j<3;++j){
    double mx = (PD[72+j] - 64.0) - mu[j];
    double mnv = mu[j] - (64.0 - PD[75+j]);
    amax = fmax(amax, fmax(mx, mnv));
  }
  double s = 0.999999/amax;
  double s2 = s*s;
  double C[3][3];
  C[0][0]=(PD[5]-dN*mu[0]*mu[0])*s2; C[1][0]=(PD[6]-dN*mu[1]*mu[0])*s2;
  C[2][0]=(PD[7]-dN*mu[2]*mu[0])*s2; C[1][1]=(PD[8]-dN*mu[1]*mu[1])*s2;
  C[2][1]=(PD[9]-dN*mu[2]*mu[1])*s2; C[2][2]=(PD[10]-dN*mu[2]*mu[2])*s2;
  C[0][1]=C[1][0]; C[0][2]=C[2][0]; C[1][2]=C[2][1];
  double w[3], V[3][3];
  eigh3_(C, w, V);
  int bad1 = 0;
  for (int i=0;i<3;++i){ if (badd(w[i])) bad1=1; for (int j=0;j<3;++j) if (badd(V[i][j])) bad1=1; }
  if (bad1){
    DF[0] |= 2;
    for (int i=0;i<3;++i) for (int j=0;j<3;++j) V[i][j] = (i==j) ? 1.0 : 0.0;
  }
  PD[12]=mu[0]; PD[13]=mu[1]; PD[14]=mu[2];
  PD[15]=s;
  for (int i=0;i<3;++i) for (int j=0;j<3;++j) PD[16+i*3+j]=V[i][j];
  double cntf = dN*32.0;
  double mu1 = PD[3]/cntf;
  double var = PD[4]/cntf - mu1*mu1;
  PD[25]=mu1;
  PD[26]=1.0/(sqrt(var>0.0?var:0.0)+1e-5);
}

__global__ void k_buildx(const void* __restrict__ data,
                         const void* __restrict__ ln1w,
                         const void* __restrict__ ln1b,
                         double* __restrict__ PD, float* __restrict__ x, int N){
  int n = blockIdx.x*blockDim.x + threadIdx.x;
  if (n >= N) return;
  int* DF = (int*)(PD + 28);
  int f32 = DF[1];
  size_t rb = (size_t)n*35;
  double s = PD[15];
  double p0 = ((double)ldin(data, rb+0, f32) - PD[12])*s;
  double p1 = ((double)ldin(data, rb+1, f32) - PD[13])*s;
  double p2 = ((double)ldin(data, rb+2, f32) - PD[14])*s;
  float* xr = x + (size_t)n*36;
  int bb = 0;
  for (int j=0;j<3;++j){
    float v = (float)(p0*PD[16+j] + p1*PD[19+j] + p2*PD[22+j]);
    bb |= badf(v);
    xr[j] = v;
  }
  float mu1 = (float)PD[25], rs = (float)PD[26];
  for (int k=0;k<32;++k){
    float v = (ldin(data, rb+3+k, f32) - mu1)*rs*ldin(ln1w, k, f32) + ldin(ln1b, k, f32);
    bb |= badf(v);
    xr[3+k] = v;
  }
  xr[35] = 0.f;
  if (bb) atomicOr(DF, 4);
}

// ---- fallback-path kernels (N > 2^17): per-node count + scan + scatter ----
__global__ void k_count(const int* __restrict__ dst, int* __restrict__ cnt, int E){
  int i = blockIdx.x*blockDim.x + threadIdx.x;
  if (i < E) atomicAdd(&cnt[dst[i]], 1);
}

__global__ void k_scan1(const int* __restrict__ cnt, int* __restrict__ bsum, int N){
  int i = blockIdx.x*256 + threadIdx.x;
  int v = (i < N) ? cnt[i] : 0;
  #pragma unroll
  for (int o=32;o>0;o>>=1) v += __shfl_down(v, o);
  __shared__ int s4[4];
  if ((threadIdx.x&63)==0) s4[threadIdx.x>>6]=v;
  __syncthreads();
  if (threadIdx.x==0) bsum[blockIdx.x]=s4[0]+s4[1]+s4[2]+s4[3];
}

__global__ void k_scan2(const int* __restrict__ bsum, int* __restrict__ bpre,
                        int* __restrict__ iptr, int nb, int N){
  if (threadIdx.x != 0 || blockIdx.x != 0) return;
  int run = 0;
  for (int b=0;b<nb;++b){ bpre[b]=run; run += bsum[b]; }
  iptr[N] = run;
}

__global__ void k_scan3(const int* __restrict__ cnt, const int* __restrict__ bpre,
                        int* __restrict__ iptr, int* __restrict__ cur, int N){
  __shared__ int sc[256];
  int i = blockIdx.x*256 + threadIdx.x;
  int t = threadIdx.x;
  int v = (i < N) ? cnt[i] : 0;
  sc[t] = v;
  __syncthreads();
  for (int o=1;o<256;o<<=1){
    int add = (t >= o) ? sc[t-o] : 0;
    __syncthreads();
    sc[t] += add;
    __syncthreads();
  }
  if (i < N){
    int val = bpre[blockIdx.x] + sc[t] - v;
    iptr[i] = val;
    cur[i] = val;
  }
}

__global__ void k_scatter(const int* __restrict__ src, const int* __restrict__ dst,
                          const int* __restrict__ et, int* __restrict__ cur,
                          int* __restrict__ pack, int E){
  int i = blockIdx.x*blockDim.x + threadIdx.x;
  if (i < E){
    int d = dst[i];
    int p = atomicAdd(&cur[d], 1);
    pack[p] = src[i] | (et[i] << 20);
  }
}

// ---- fast path: deterministic partition, no per-node global atomics ----
// Pass 1: per-block histogram of its contiguous edge chunk (512-node buckets).
__global__ void k_hist(const int* __restrict__ dst, int* __restrict__ H,
                       int E, int per, int nb){
  __shared__ int lc[256];
  int blk = blockIdx.x, t = threadIdx.x;
  lc[t] = 0;
  __syncthreads();
  int s = blk*per, e = min(E, s+per);
  for (int i = s+t; i < e; i += 256) atomicAdd(&lc[dst[i] >> 9], 1);
  __syncthreads();
  if (t < nb) H[t*NBLK + blk] = lc[t];
}

// Pass 1b: bucket totals (one block per bucket, NBLK==256 columns).
__global__ void k_bsum1(const int* __restrict__ H, int* __restrict__ btot){
  int b = blockIdx.x;
  int v = H[b*NBLK + threadIdx.x];
  #pragma unroll
  for (int o=32;o>0;o>>=1) v += __shfl_down(v, o);
  __shared__ int s4[4];
  if ((threadIdx.x&63)==0) s4[threadIdx.x>>6]=v;
  __syncthreads();
  if (threadIdx.x==0) btot[b]=s4[0]+s4[1]+s4[2]+s4[3];
}

// Pass 1c: exclusive prefix over bucket totals -> bbase[nbkt+1].
__global__ void k_bpre(const int* __restrict__ btot, int* __restrict__ bbase, int nbkt){
  __shared__ int sc[256];
  int t = threadIdx.x;
  int v = (t < nbkt) ? btot[t] : 0;
  sc[t] = v;
  __syncthreads();
  for (int o=1;o<256;o<<=1){
    int add = (t >= o) ? sc[t-o] : 0;
    __syncthreads();
    sc[t] += add;
    __syncthreads();
  }
  if (t <= nbkt && t < 256) bbase[t] = (t == 0) ? 0 : sc[t-1];
  if (t == 0 && nbkt == 256) bbase[256] = sc[255];
}

// Pass 2: per bucket, exclusive scan across blocks; base = bbase[b].
__global__ void k_xscan(const int* __restrict__ H, const int* __restrict__ bbase,
                        int* __restrict__ offs){
  __shared__ int sc[256];
  int b = blockIdx.x, t = threadIdx.x;
  int v = H[b*NBLK + t];
  sc[t] = v;
  __syncthreads();
  for (int o=1;o<256;o<<=1){
    int add = (t >= o) ? sc[t-o] : 0;
    __syncthreads();
    sc[t] += add;
    __syncthreads();
  }
  offs[b*NBLK + t] = bbase[b] + sc[t] - v;
}

// Pass 3: write each edge to its block-private contiguous range (no atomics
// to global; LDS rank counters only). Entry = src | et<<17 | (dst&511)<<21.
__global__ void k_binA2(const int* __restrict__ src, const int* __restrict__ dst,
                        const int* __restrict__ et, const int* __restrict__ offs,
                        int* __restrict__ stag, int E, int per){
  __shared__ int lc[256];
  int blk = blockIdx.x, t = threadIdx.x;
  lc[t] = 0;
  __syncthreads();
  int s = blk*per, e = min(E, s+per);
  for (int i = s+t; i < e; i += 256){
    int d = dst[i];
    int b = d >> 9;
    int r = atomicAdd(&lc[b], 1);
    stag[offs[b*NBLK + blk] + r] = src[i] | (et[i] << 17) | ((d & 511) << 21);
  }
}

// Pass 4: per bucket: LDS per-node count + scan -> iptr, then scatter pack.
// Replaces the global-atomic k_count/k_scan*/k_binB2 entirely.
__global__ void k_binB3(const int* __restrict__ bbase, const int* __restrict__ stag,
                        int* __restrict__ pack, int* __restrict__ iptr,
                        int N, int E, int nbkt){
  __shared__ int lcnt[512];
  __shared__ int ssum[256];
  int b = blockIdx.x;
  int n0 = b << 9;
  int t = threadIdx.x;
  lcnt[t] = 0; lcnt[t+256] = 0;
  __syncthreads();
  int segs = bbase[b], sege = bbase[b+1];
  for (int k = segs + t; k < sege; k += 256)
    atomicAdd(&lcnt[(stag[k] >> 21) & 511], 1);
  __syncthreads();
  int c0 = lcnt[2*t], c1 = lcnt[2*t+1];
  int s = c0 + c1;
  ssum[t] = s;
  __syncthreads();
  for (int o=1;o<256;o<<=1){
    int add = (t >= o) ? ssum[t-o] : 0;
    __syncthreads();
    ssum[t] += add;
    __syncthreads();
  }
  int p0 = segs + ssum[t] - s;
  int p1 = p0 + c0;
  lcnt[2*t] = p0; lcnt[2*t+1] = p1;
  if (n0 + 2*t < N)     iptr[n0 + 2*t]     = p0;
  if (n0 + 2*t+1 < N)   iptr[n0 + 2*t+1]   = p1;
  if (b == nbkt-1 && t == 0) iptr[N] = E;
  __syncthreads();
  for (int k = segs + t; k < sege; k += 256){
    int e2 = stag[k];
    int pos = atomicAdd(&lcnt[(e2 >> 21) & 511], 1);
    pack[pos] = (e2 & 0x1FFFF) | (((e2 >> 17) & 15) << 20);
  }
}

// Pack B fragments (bf16, MFMA lane layout) for W (per r, kc, tile) and for
// the yq/yk side (u_r = W_r@q, v_r = W_r@k computed inline, hi/lo split).
__global__ void k_fragpack(const void* __restrict__ W, size_t wofs, int F, int KC,
                           const void* __restrict__ qp, const void* __restrict__ kp,
                           size_t qofs,
                           unsigned short* __restrict__ bfr,
                           unsigned short* __restrict__ qkfr,
                           const int* __restrict__ DF){
  int t = blockIdx.x*blockDim.x + threadIdx.x;
  int nB = 15*KC*2*64*8;
  int nQ = 2*2*KC*64*8;
  int f32 = DF[1];
  if (t < nB){
    int j = t & 7; int lane = (t >> 3) & 63; int tile = (t >> 9) & 1; int idx = t >> 10;
    int kc = idx % KC; int r = idx / KC;
    int f = kc*32 + (lane >> 4)*8 + j;
    int o = tile*16 + (lane & 15);
    bfr[t] = (f < F) ? f2bf(ldin(W, wofs + ((size_t)(r*F+f))*32 + o, f32)) : 0;
  } else if (t < nB + nQ){
    int u = t - nB;
    int j = u & 7; int lane = (u >> 3) & 63; int wpk = u >> 9;
    int kc = wpk % KC; int wp = wpk / KC;
    int part = wp & 1; int which = wp >> 1;
    int f = kc*32 + (lane >> 4)*8 + j;
    int rr = lane & 15;
    unsigned short val = 0;
    if (f < F && rr < 15){
      const void* v = which ? kp : qp;
      float acc = 0.f;
      for (int o = 0; o < 32; ++o)
        acc = fmaf(ldin(W, wofs + ((size_t)(rr*F+f))*32 + o, f32), ldin(v, qofs + o, f32), acc);
      unsigned short hi = f2bf(acc);
      val = (part == 0) ? hi : f2bf(acc - bf2f(hi));
    }
    qkfr[u] = val;
  }
}

// MFMA GEMM, r-sliced for occupancy: blockIdx.y in [0,5), 3 relations each.
// y stored SWIZZLED: row position 2*col holds col (tile0), 2*col+1 holds
// col+16 (tile1) -> one aligned dword store per lane per (r,j).
__global__ void __launch_bounds__(256)
k_mf(const float* __restrict__ x, int str, int KC, int N,
     const unsigned short* __restrict__ bfr,
     const unsigned short* __restrict__ qkfr,
     unsigned short* __restrict__ y, float* __restrict__ yq, float* __restrict__ yk){
  int wave = blockIdx.x*(blockDim.x >> 6) + (threadIdx.x >> 6);
  int node0 = wave*16;
  if (node0 >= N) return;
  int lane = threadIdx.x & 63;
  int col = lane & 15, quad = lane >> 4;
  int r0 = blockIdx.y*3;

  short8 ah[2], al[2];
  #pragma unroll
  for (int kc = 0; kc < 2; ++kc){
    if (kc >= KC) break;
    float xv[8];
    int node = node0 + col;           // A row m = lane&15
    int kbase = kc*32 + quad*8;
    if (node < N && kbase < str){
      const float* xr = x + (size_t)node*str + kbase;
      if (kbase + 8 <= str){
        float4 a = *(const float4*)xr; float4 b = *(const float4*)(xr + 4);
        xv[0]=a.x; xv[1]=a.y; xv[2]=a.z; xv[3]=a.w; xv[4]=b.x; xv[5]=b.y; xv[6]=b.z; xv[7]=b.w;
      } else if (kbase + 4 <= str){
        float4 a = *(const float4*)xr;
        xv[0]=a.x; xv[1]=a.y; xv[2]=a.z; xv[3]=a.w; xv[4]=0.f; xv[5]=0.f; xv[6]=0.f; xv[7]=0.f;
      } else {
        #pragma unroll
        for (int j=0;j<8;++j) xv[j]=0.f;
      }
    } else {
      #pragma unroll
      for (int j=0;j<8;++j) xv[j]=0.f;
    }
    #pragma unroll
    for (int j=0;j<8;++j){
      unsigned short hi = f2bf(xv[j]);
      ah[kc][j] = (short)hi;
      al[kc][j] = (short)f2bf(xv[j] - bf2f(hi));
    }
  }

  const short8* B  = (const short8*)bfr;
  const short8* QK = (const short8*)qkfr;

  if (blockIdx.y == 0){
    // yq / yk tiles (cols = r), B-side hi/lo split too
    f32x4 aq = {0.f,0.f,0.f,0.f}, ak2 = {0.f,0.f,0.f,0.f};
    for (int kc = 0; kc < KC; ++kc){
      short8 qh = QK[((0*KC) + kc)*64 + lane];        // which=0 part=0
      short8 ql = QK[((1*KC) + kc)*64 + lane];        // which=0 part=1
      short8 kh = QK[((2*KC) + kc)*64 + lane];        // which=1 part=0
      short8 kl = QK[((3*KC) + kc)*64 + lane];        // which=1 part=1
      aq = mfma16(ah[kc], qh, aq);
      aq = mfma16(al[kc], qh, aq);
      aq = mfma16(ah[kc], ql, aq);
      ak2 = mfma16(ah[kc], kh, ak2);
      ak2 = mfma16(al[kc], kh, ak2);
      ak2 = mfma16(ah[kc], kl, ak2);
    }
    #pragma unroll
    for (int j = 0; j < 4; ++j){
      int node = node0 + quad*4 + j;
      if (node < N){
        yq[(size_t)node*16 + col] = aq[j];
        yk[(size_t)node*16 + col] = ak2[j];
      }
    }
  }

  // y tiles for this slice's 3 relations
  for (int r = r0; r < r0+3; ++r){
    f32x4 a0 = {0.f,0.f,0.f,0.f}, a1 = {0.f,0.f,0.f,0.f};
    for (int kc = 0; kc < KC; ++kc){
      short8 b0 = B[(((size_t)(r*KC + kc))*2 + 0)*64 + lane];
      short8 b1 = B[(((size_t)(r*KC + kc))*2 + 1)*64 + lane];
      a0 = mfma16(ah[kc], b0, a0);
      a0 = mfma16(al[kc], b0, a0);
      a1 = mfma16(ah[kc], b1, a1);
      a1 = mfma16(al[kc], b1, a1);
    }
    #pragma unroll
    for (int j = 0; j < 4; ++j){
      int node = node0 + quad*4 + j;
      if (node < N){
        unsigned int pk = (unsigned int)f2bf(a0[j]) | ((unsigned int)f2bf(a1[j]) << 16);
        *(unsigned int*)&y[(((size_t)r*N + node))*32 + col*2] = pk;
      }
    }
  }
}

// softmax + aggregation. deg<=64 fast path (scalars, no spill), 8x-unrolled
// gather. y rows are SWIZZLED (see k_mf): os = 2*(o&15) + (o>>4).
__global__ void k_main(const int* __restrict__ iptr, const int* __restrict__ pack,
                       const float* __restrict__ yq, const float* __restrict__ yk,
                       const unsigned short* __restrict__ y,
                       const void* __restrict__ biasp, size_t bofs,
                       const float* __restrict__ xres, float* __restrict__ hpre,
                       double* __restrict__ partials, int* __restrict__ DF, int N){
  __shared__ double sdb[4][2];
  int gt = blockIdx.x*blockDim.x + threadIdx.x;
  int node = gt >> 6, lane = gt & 63;
  int wid = threadIdx.x >> 6;
  int f32 = DF[1];
  int o = lane & 31;
  int os = ((o & 15) << 1) | (o >> 4);   // swizzled position within y row
  bool active = (node < N);
  float hp = 0.f;

  if (active){
    int start = iptr[node];
    int deg = iptr[node+1] - start;
    const float* yqn = yq + (size_t)node*16;
    float acc = 0.f;
    float ssum = 0.f;

    if (deg <= 64){
      // ---- fast path: one chunk in scalars ----
      int pe = 0; float a = -INFINITY;
      if (lane < deg){
        pe = pack[start+lane];
        int sr = pe & 0xFFFFF, et = pe >> 20;
        a = yqn[et] + yk[(size_t)sr*16+et];
        a = (a >= 0.f) ? a : 0.2f*a;
      }
      float amax = a;
      #pragma unroll
      for (int o2=32;o2>0;o2>>=1) amax = fmaxf(amax, __shfl_xor(amax, o2));
      float ev = (lane < deg) ? expf(a - amax) : 0.f;
      ssum = ev;
      int sub = lane >> 5;
      for (; sub + 14 < deg; sub += 16){
        float w0 = __shfl(ev, sub),    w1 = __shfl(ev, sub+2);
        float w2 = __shfl(ev, sub+4),  w3 = __shfl(ev, sub+6);
        float w4 = __shfl(ev, sub+8),  w5 = __shfl(ev, sub+10);
        float w6 = __shfl(ev, sub+12), w7 = __shfl(ev, sub+14);
        int   p0 = __shfl(pe, sub),    p1 = __shfl(pe, sub+2);
        int   p2 = __shfl(pe, sub+4),  p3 = __shfl(pe, sub+6);
        int   p4 = __shfl(pe, sub+8),  p5 = __shfl(pe, sub+10);
        int   p6 = __shfl(pe, sub+12), p7 = __shfl(pe, sub+14);
        float v0 = bf2f(y[((size_t)(p0 >> 20)*N + (p0 & 0xFFFFF))*32 + os]);
        float v1 = bf2f(y[((size_t)(p1 >> 20)*N + (p1 & 0xFFFFF))*32 + os]);
        float v2 = bf2f(y[((size_t)(p2 >> 20)*N + (p2 & 0xFFFFF))*32 + os]);
        float v3 = bf2f(y[((size_t)(p3 >> 20)*N + (p3 & 0xFFFFF))*32 + os]);
        float v4 = bf2f(y[((size_t)(p4 >> 20)*N + (p4 & 0xFFFFF))*32 + os]);
        float v5 = bf2f(y[((size_t)(p5 >> 20)*N + (p5 & 0xFFFFF))*32 + os]);
        float v6 = bf2f(y[((size_t)(p6 >> 20)*N + (p6 & 0xFFFFF))*32 + os]);
        float v7 = bf2f(y[((size_t)(p7 >> 20)*N + (p7 & 0xFFFFF))*32 + os]);
        acc = fmaf(w0, v0, acc); acc = fmaf(w1, v1, acc);
        acc = fmaf(w2, v2, acc); acc = fmaf(w3, v3, acc);
        acc = fmaf(w4, v4, acc); acc = fmaf(w5, v5, acc);
        acc = fmaf(w6, v6, acc); acc = fmaf(w7, v7, acc);
      }
      for (; sub + 6 < deg; sub += 8){
        float w0 = __shfl(ev, sub),   w1 = __shfl(ev, sub+2);
        float w2 = __shfl(ev, sub+4), w3 = __shfl(ev, sub+6);
        int   p0 = __shfl(pe, sub),   p1 = __shfl(pe, sub+2);
        int   p2 = __shfl(pe, sub+4), p3 = __shfl(pe, sub+6);
        float v0 = bf2f(y[((size_t)(p0 >> 20)*N + (p0 & 0xFFFFF))*32 + os]);
        float v1 = bf2f(y[((size_t)(p1 >> 20)*N + (p1 & 0xFFFFF))*32 + os]);
        float v2 = bf2f(y[((size_t)(p2 >> 20)*N + (p2 & 0xFFFFF))*32 + os]);
        float v3 = bf2f(y[((size_t)(p3 >> 20)*N + (p3 & 0xFFFFF))*32 + os]);
        acc = fmaf(w0, v0, acc); acc = fmaf(w1, v1, acc);
        acc = fmaf(w2, v2, acc); acc = fmaf(w3, v3, acc);
      }
      for (; sub < deg; sub += 2){
        float wgt = __shfl(ev, sub);
        int pb = __shfl(pe, sub);
        acc = fmaf(wgt, bf2f(y[((size_t)(pb >> 20)*N + (pb & 0xFFFFF))*32 + os]), acc);
      }
    } else {
      // ---- slow path: two-pass recompute (rare: deg>64) ----
      float amax = -INFINITY;
      for (int k = lane; k < deg; k += 64){
        int pe = pack[start+k];
        int sr = pe & 0xFFFFF, et = pe >> 20;
        float a = yqn[et] + yk[(size_t)sr*16+et];
        a = (a >= 0.f) ? a : 0.2f*a;
        amax = fmaxf(amax, a);
      }
      #pragma unroll
      for (int o2=32;o2>0;o2>>=1) amax = fmaxf(amax, __shfl_xor(amax, o2));
      for (int c = 0; c < deg; c += 64){
        int k = c + lane;
        float ev = 0.f; int pe = 0;
        if (k < deg){
          pe = pack[start+k];
          int sr = pe & 0xFFFFF, et = pe >> 20;
          float a = yqn[et] + yk[(size_t)sr*16+et];
          a = (a >= 0.f) ? a : 0.2f*a;
          ev = expf(a - amax);
          ssum += ev;
        }
        int lim = min(64, deg - c);
        int sub = lane >> 5;
        for (; sub + 6 < lim; sub += 8){
          float w0 = __shfl(ev, sub),   w1 = __shfl(ev, sub+2);
          float w2 = __shfl(ev, sub+4), w3 = __shfl(ev, sub+6);
          int   p0 = __shfl(pe, sub),   p1 = __shfl(pe, sub+2);
          int   p2 = __shfl(pe, sub+4), p3 = __shfl(pe, sub+6);
          float v0 = bf2f(y[((size_t)(p0 >> 20)*N + (p0 & 0xFFFFF))*32 + os]);
          float v1 = bf2f(y[((size_t)(p1 >> 20)*N + (p1 & 0xFFFFF))*32 + os]);
          float v2 = bf2f(y[((size_t)(p2 >> 20)*N + (p2 & 0xFFFFF))*32 + os]);
          float v3 = bf2f(y[((size_t)(p3 >> 20)*N + (p3 & 0xFFFFF))*32 + os]);
          acc = fmaf(w0, v0, acc);
          acc = fmaf(w1, v1, acc);
          acc = fmaf(w2, v2, acc);
          acc = fmaf(w3, v3, acc);
        }
        for (; sub < lim; sub += 2){
          float wgt = __shfl(ev, sub);
          int pb = __shfl(pe, sub);
          acc = fmaf(wgt, bf2f(y[((size_t)(pb >> 20)*N + (pb & 0xFFFFF))*32 + os]), acc);
        }
      }
    }
    #pragma unroll
    for (int o2=32;o2>0;o2>>=1) ssum += __shfl_xor(ssum, o2);
    float inv = 1.f/(ssum + 1e-16f);
    acc *= inv;
    acc += __shfl_xor(acc, 32);

    if (lane < 32){
      hp = acc + ldin(biasp, bofs + o, f32);
      if (xres) hp += xres[(size_t)node*32 + o];
      if (badf(hp)) atomicOr(DF, 32);
      hpre[(size_t)node*32 + o] = hp;
    }
  }

  // block-level LN stats -> plain store to partials (no fence, no atomics)
  float s1 = (active && lane < 32) ? hp : 0.f;
  float s2 = s1*s1;
  #pragma unroll
  for (int o2=32;o2>0;o2>>=1){ s1 += __shfl_xor(s1,o2); s2 += __shfl_xor(s2,o2); }
  if (lane == 0){ sdb[wid][0] = (double)s1; sdb[wid][1] = (double)s2; }
  __syncthreads();
  if (threadIdx.x == 0){
    partials[(size_t)blockIdx.x*2]   = sdb[0][0]+sdb[1][0]+sdb[2][0]+sdb[3][0];
    partials[(size_t)blockIdx.x*2+1] = sdb[0][1]+sdb[1][1]+sdb[2][1]+sdb[3][1];
  }
}

__global__ void k_stat(const double* __restrict__ partials, int nb,
                       double* __restrict__ PD, int l){
  double t1 = 0.0, t2 = 0.0;
  for (int i = threadIdx.x; i < nb; i += 256){
    t1 += partials[(size_t)i*2];
    t2 += partials[(size_t)i*2+1];
  }
  t1 = wsum_d(t1); t2 = wsum_d(t2);
  __shared__ double sd[8];
  int w = threadIdx.x >> 6;
  if ((threadIdx.x & 63) == 0){ sd[w*2] = t1; sd[w*2+1] = t2; }
  __syncthreads();
  if (threadIdx.x == 0){
    PD[32+2*l]   = sd[0]+sd[2]+sd[4]+sd[6];
    PD[32+2*l+1] = sd[1]+sd[3]+sd[5]+sd[7];
  }
}

__global__ void k_ln(float* __restrict__ h, const void* __restrict__ lnw,
                     const void* __restrict__ lnb, size_t lofs,
                     double* __restrict__ PD, int l, int N){
  int idx = blockIdx.x*blockDim.x + threadIdx.x;
  if (idx >= N*32) return;
  int* DF = (int*)(PD + 28);
  int f32 = DF[1];
  const double* stats = PD + 32 + 2*l;
  int o = idx & 31;
  double cntf = (double)N*32.0;
  double mu = stats[0]/cntf;
  double var = stats[1]/cntf - mu*mu;
  float rstd = (float)(1.0/(sqrt(var>0.0?var:0.0) + 1e-5));
  float v = (h[idx] - (float)mu)*rstd*ldin(lnw, lofs + o, f32) + ldin(lnb, lofs + o, f32);
  v = v / (1.f + expf(-v));
  if (badf(v)) atomicOr(DF, 64);
  h[idx] = v;
}

__global__ void k_pool(const float* __restrict__ h, double* __restrict__ PD, int N){
  __shared__ float sp[8][33];
  int t = threadIdx.x, o = t & 31, g = t >> 5;
  int r0 = blockIdx.x*256;
  float s = 0.f;
  for (int r = r0 + g; r < N && r < r0 + 256; r += 8) s += h[(size_t)r*32 + o];
  sp[g][o] = s;
  __syncthreads();
  if (t < 32){
    float tot = 0.f;
    #pragma unroll
    for (int g2=0; g2<8; ++g2) tot += sp[g2][t];
    atomicAdd(&PD[40 + t], (double)tot);
  }
}

__global__ void k_out(double* __restrict__ PD, const void* __restrict__ Wl,
                      const void* __restrict__ bl, void* __restrict__ out, int N, int H2){
  int j = blockIdx.x*blockDim.x + threadIdx.x;
  if (j >= H2) return;
  int* DF = (int*)(PD + 28);
  int f32 = DF[1];
  int flag = DF[0];
  const double* pool = PD + 40;
  float acc = ldin(bl, j, f32);
  for (int o=0;o<32;++o)
    acc = fmaf((float)(pool[o]/(double)N), ldin(Wl, (size_t)j*32+o, f32), acc);
  if (badf(acc)) flag |= 128;
  float v = acc / (1.f + expf(-acc));
  if (flag) v = (float)flag;   // diagnostic: absmax == stage bitmask
  if (f32) ((float*)out)[j] = v;
  else     ((unsigned short*)out)[j] = f2bf(v);
}

__global__ void k_diag(unsigned short* out, float val, int H2){
  int j = blockIdx.x*blockDim.x + threadIdx.x;
  if (j < H2) out[j] = f2bf(val);
}

// ---------------- entry ----------------
extern "C" void kernel_launch(void* const* d_in, const int* in_sizes, int n_in,
                              void* d_out, int out_size, void* d_ws, size_t ws_size,
                              hipStream_t stream)
{
  const int N  = in_sizes[0] / 35;
  const int E  = in_sizes[3];
  const int R  = 15;
  const int H2 = in_sizes[19];

  const void* data = d_in[0];
  const int* ei  = (const int*)d_in[2];
  const int* etp = (const int*)d_in[3];
  const void* W0  = d_in[6];
  const void* q0  = d_in[7];
  const void* k0  = d_in[8];
  const void* b0  = d_in[9];
  const void* Wsp = d_in[10];
  const void* qsp = d_in[11];
  const void* ksp = d_in[12];
  const void* bsp = d_in[13];
  const void* lnw = d_in[14];
  const void* lnb = d_in[15];
  const void* ln1w= d_in[16];
  const void* ln1b= d_in[17];
  const void* l1W = d_in[18];
  const void* l1b = d_in[19];

  char* base = (char*)d_ws;
  size_t off = 0;
  auto A = [&](size_t nb)->size_t { size_t c = off; off += (nb + 255) & ~(size_t)255; return c; };
  size_t oPD  = A(1024);
  size_t oCnt = A((size_t)N*4);
  size_t oPtr = A(((size_t)N+1)*4);
  size_t oCur = A((size_t)N*4);
  size_t oBs  = A(4096);
  size_t oBp  = A(4096);
  size_t oBb  = A(2048);
  size_t oBt  = A(2048);
  size_t oPk  = A((size_t)E*4);
  size_t oSt  = A((size_t)E*4);
  size_t oHh  = A((size_t)256*NBLK*4);
  size_t oOf  = A((size_t)256*NBLK*4);
  size_t oX   = A((size_t)N*36*4);
  size_t oH0  = A((size_t)N*32*4);
  size_t oH1  = A((size_t)N*32*4);
  size_t oYq  = A((size_t)N*16*4);
  size_t oYk  = A((size_t)N*16*4);
  size_t oBf  = A((size_t)15*2*2*64*8*2);
  size_t oQk  = A((size_t)2*2*2*64*8*2);
  int nbMain  = (int)(((size_t)N*64 + 255)/256);
  size_t oPt  = A((size_t)nbMain*2*8);
  size_t oY   = off;
  size_t needB = oY + (size_t)R*N*32*2;

  double* PD  = (double*)(base + oPD);
  int* DF     = (int*)(PD + 28);
  int* cnt    = (int*)(base + oCnt);
  int* iptr   = (int*)(base + oPtr);
  int* cur    = (int*)(base + oCur);
  int* bsum   = (int*)(base + oBs);
  int* bpre   = (int*)(base + oBp);
  int* bbase  = (int*)(base + oBb);
  int* btot   = (int*)(base + oBt);
  int* pack   = (int*)(base + oPk);
  int* stag   = (int*)(base + oSt);
  int* Hh     = (int*)(base + oHh);
  int* offs   = (int*)(base + oOf);
  float* xb   = (float*)(base + oX);
  float* h0   = (float*)(base + oH0);
  float* h1   = (float*)(base + oH1);
  float* yqb  = (float*)(base + oYq);
  float* ykb  = (float*)(base + oYk);
  unsigned short* bfr  = (unsigned short*)(base + oBf);
  unsigned short* qkfr = (unsigned short*)(base + oQk);
  double* partials = (double*)(base + oPt);
  unsigned short* y = (unsigned short*)(base + oY);

  if (ws_size < needB){
    k_diag<<<1, 256, 0, stream>>>((unsigned short*)d_out, (float)(ws_size >> 20), H2);
    return;
  }

  // zero PD + cnt ( [0, oPtr) covers both exactly )
  hipMemsetAsync(base, 0, oPtr, stream);

  int nbN = (N + 255)/256;
  int nbE = (E + 255)/256;
  int nus = (in_sizes[0] < 1024) ? in_sizes[0] : 1024;

  k_dtype<<<1, 256, 0, stream>>>((const unsigned short*)data, nus, PD);
  k_red1<<<nbN, 256, 0, stream>>>(data, N, PD);
  k_eig<<<1, 1, 0, stream>>>(PD, N);
  k_buildx<<<nbN, 256, 0, stream>>>(data, ln1w, ln1b, PD, xb, N);

  if (N <= (1 << 17)){
    int nbkt = (N + 511) >> 9;           // <= 256
    int per  = (E + NBLK - 1) / NBLK;
    k_hist<<<NBLK, 256, 0, stream>>>(ei + E, Hh, E, per, nbkt);
    k_bsum1<<<nbkt, 256, 0, stream>>>(Hh, btot);
    k_bpre<<<1, 256, 0, stream>>>(btot, bbase, nbkt);
    k_xscan<<<nbkt, 256, 0, stream>>>(Hh, bbase, offs);
    k_binA2<<<NBLK, 256, 0, stream>>>(ei, ei + E, etp, offs, stag, E, per);
    k_binB3<<<nbkt, 256, 0, stream>>>(bbase, stag, pack, iptr, N, E, nbkt);
  } else {
    k_count<<<nbE, 256, 0, stream>>>(ei + E, cnt, E);
    k_scan1<<<nbN, 256, 0, stream>>>(cnt, bsum, N);
    k_scan2<<<1, 1, 0, stream>>>(bsum, bpre, iptr, nbN, N);
    k_scan3<<<nbN, 256, 0, stream>>>(cnt, bpre, iptr, cur, N);
    k_scatter<<<nbE, 256, 0, stream>>>(ei, ei + E, etp, cur, pack, E);
  }

  int nbMf = (int)(((N + 15)/16 + 3)/4);
  for (int l=0; l<4; ++l){
    const void* W  = (l==0)? W0 : Wsp;  size_t wofs = (l==0)? 0 : (size_t)(l-1)*R*32*32;
    const void* qp = (l==0)? q0 : qsp;  size_t qofs = (l==0)? 0 : (size_t)(l-1)*32;
    const void* kp = (l==0)? k0 : ksp;
    const void* bp = (l==0)? b0 : bsp;  size_t bofs = qofs;
    int str = (l==0)? 36 : 32;
    int KC = (l==0)? 2 : 1;
    int F = (l==0)? 35 : 32;
    const float* xin = (l==0)? xb : ((l%2==0)? h1 : h0);
    float* hout = (l%2==0)? h0 : h1;
    int nFrag = 15*KC*2*64*8 + 2*2*KC*64*8;
    k_fragpack<<<(nFrag+255)/256, 256, 0, stream>>>(W, wofs, F, KC, qp, kp, qofs, bfr, qkfr, DF);
    dim3 gmf((unsigned)nbMf, 5);
    k_mf<<<gmf, 256, 0, stream>>>(xin, str, KC, N, bfr, qkfr, y, yqb, ykb);
    k_main<<<nbMain, 256, 0, stream>>>(iptr, pack, yqb, ykb, y, bp, bofs,
                 (l==0)? (const float*)nullptr : xin, hout, partials, DF, N);
    k_stat<<<1, 256, 0, stream>>>(partials, nbMain, PD, l);
    k_ln<<<(N*32+255)/256, 256, 0, stream>>>(hout, lnw, lnb, (size_t)l*32, PD, l, N);
  }

  k_pool<<<nbN, 256, 0, stream>>>(h1, PD, N);
  k_out<<<(H2+255)/256, 256, 0, stream>>>(PD, l1W, l1b, d_out, N, H2);
}